// Round 6
// baseline (293.333 us; speedup 1.0000x reference)
//
#include <hip/hip_runtime.h>
#include <hip/hip_bf16.h>
#include <stdint.h>

#define DEV __device__ __forceinline__

typedef short     s16x8  __attribute__((ext_vector_type(8)));
typedef __bf16    bf16v8 __attribute__((ext_vector_type(8)));
typedef float     f32x4  __attribute__((ext_vector_type(4)));
typedef float     f32x16 __attribute__((ext_vector_type(16)));

// ---------- helpers ----------
DEV unsigned short f2bf(float x) {
    uint32_t u = __float_as_uint(x);
    uint32_t r = (u + 0x7FFFu + ((u >> 16) & 1u)) >> 16;
    return (unsigned short)r;
}

DEV void gload_lds16(const void* g, void* l) {
    __builtin_amdgcn_global_load_lds((const __attribute__((address_space(1))) void*)g,
                                     (__attribute__((address_space(3))) void*)l,
                                     16, 0, 0);
}

DEV f32x4 mfma16(s16x8 a, s16x8 b, f32x4 c) {
    return __builtin_amdgcn_mfma_f32_16x16x32_bf16(
        __builtin_bit_cast(bf16v8, a), __builtin_bit_cast(bf16v8, b), c, 0, 0, 0);
}
DEV f32x16 mfma32(s16x8 a, s16x8 b, f32x16 c) {
    return __builtin_amdgcn_mfma_f32_32x32x16_bf16(
        __builtin_bit_cast(bf16v8, a), __builtin_bit_cast(bf16v8, b), c, 0, 0, 0);
}

DEV uint32_t cvtpk_bf16(float lo, float hi) {
    uint32_t r;
    asm volatile("v_cvt_pk_bf16_f32 %0, %1, %2" : "=v"(r) : "v"(lo), "v"(hi));
    return r;
}

// ---------- elementwise f32 -> bf16 (8 elems / thread) ----------
__global__ void f32_to_bf16_k(const float* __restrict__ in, short* __restrict__ out, int n8) {
    int i = blockIdx.x * blockDim.x + threadIdx.x;
    if (i >= n8) return;
    const float4 a = *(const float4*)(in + (size_t)i * 8);
    const float4 b = *(const float4*)(in + (size_t)i * 8 + 4);
    uint4 w;
    w.x = (uint32_t)f2bf(a.x) | ((uint32_t)f2bf(a.y) << 16);
    w.y = (uint32_t)f2bf(a.z) | ((uint32_t)f2bf(a.w) << 16);
    w.z = (uint32_t)f2bf(b.x) | ((uint32_t)f2bf(b.y) << 16);
    w.w = (uint32_t)f2bf(b.z) | ((uint32_t)f2bf(b.w) << 16);
    *(uint4*)(out + (size_t)i * 8) = w;
}

// ---------- tiled transpose f32 (R x C) -> bf16 (C x R) ----------
__global__ __launch_bounds__(256) void transpose_f32_bf16_k(
    const float* __restrict__ in, size_t in_batch, int ld_in,
    short* __restrict__ out, size_t out_batch, int ld_out) {
    __shared__ float tile[64][65];
    const float* ip = in + (size_t)blockIdx.z * in_batch;
    short* op = out + (size_t)blockIdx.z * out_batch;
    const int c0 = blockIdx.x * 64, r0 = blockIdx.y * 64;
    const int t = threadIdx.x;
    const int cc4 = (t & 15) * 4;
    const int rr  = t >> 4;
#pragma unroll
    for (int p = 0; p < 4; ++p) {
        int r = rr + p * 16;
        float4 v = *(const float4*)(ip + (size_t)(r0 + r) * ld_in + c0 + cc4);
        tile[r][cc4 + 0] = v.x; tile[r][cc4 + 1] = v.y;
        tile[r][cc4 + 2] = v.z; tile[r][cc4 + 3] = v.w;
    }
    __syncthreads();
#pragma unroll
    for (int p = 0; p < 4; ++p) {
        int oc  = (t >> 4) + p * 16;
        int rr4 = (t & 15) * 4;
        ushort4 w;
        w.x = f2bf(tile[rr4 + 0][oc]);
        w.y = f2bf(tile[rr4 + 1][oc]);
        w.z = f2bf(tile[rr4 + 2][oc]);
        w.w = f2bf(tile[rr4 + 3][oc]);
        *(ushort4*)(op + (size_t)(c0 + oc) * ld_out + r0 + rr4) = w;
    }
}

// ---------- bias concat ----------
__global__ void concat_bias_k(const float* __restrict__ bq, const float* __restrict__ bk,
                              const float* __restrict__ bv, float* __restrict__ o) {
    int i = blockIdx.x * 256 + threadIdx.x;
    if (i < 2048)       o[i] = bq[i];
    else if (i < 2560)  o[i] = bk[i - 2048];
    else if (i < 3072)  o[i] = bv[i - 2560];
}

// ---------- GEMM v2: C[M,N] = A[M,K](bf16) * Bt[N,K]^T + bias ----------
// 128x128 tile, BK=64, 8 waves (4x2, wave out = 32x64), 3-buffer LDS ring with
// 2-tiles-ahead staging: counted s_waitcnt vmcnt(4) + raw s_barrier per K-step
// (never drains the load queue), T2 XOR-swizzle (pre-swizzled global source +
// swizzled ds_read), T5 setprio, XCD-bijective block swizzle.
__global__ __launch_bounds__(512, 2) void gemm_bt_k(
    const short* __restrict__ A, const short* __restrict__ Bt,
    const float* __restrict__ bias, float* __restrict__ C,
    int M, int N, int K) {
    __shared__ short As[3][128 * 64];
    __shared__ short Bs[3][128 * 64];
    const int tid = threadIdx.x;
    const int gx = gridDim.x;
    const int nwg = gx * gridDim.y;
    const int flat = blockIdx.y * gx + blockIdx.x;
    const int cpx = nwg >> 3;
    const int swz = (flat & 7) * cpx + (flat >> 3);
    const int m0 = (swz / gx) * 128, n0 = (swz % gx) * 128;
    const int lane = tid & 63;
    const int wid = tid >> 6;
    const int wm = wid >> 1, wn = wid & 1;   // wave out: rows [wm*32,+32), cols [wn*64,+64)
    const int lr = lane & 15, lg = lane >> 4;

    // staging: thread t writes LDS linear slot (row = i*64 + t/8, chunk = t&7);
    // swizzled read means slot (row,chunk) must hold logical chunk^(row&7).
    const int trow = tid >> 3;                               // 0..63
    const int scol = ((tid & 7) ^ (trow & 7)) << 3;          // shorts
    const short* agp = A  + (size_t)(m0 + trow) * K + scol;
    const short* bgp = Bt + (size_t)(n0 + trow) * K + scol;
    const size_t rowK64 = (size_t)64 * K;
    const int lwb = (tid & ~63) * 8;                         // wave-uniform LDS base (shorts)

    f32x4 acc[2][4];
#pragma unroll
    for (int mi = 0; mi < 2; ++mi)
#pragma unroll
        for (int ni = 0; ni < 4; ++ni)
#pragma unroll
            for (int r = 0; r < 4; ++r) acc[mi][ni][r] = 0.f;

    const int nk = K >> 6;

#define STAGE(tt, bb) do {                                        \
        const int ko_ = (tt) * 64;                                \
        gload_lds16(agp + ko_,          &As[bb][lwb]);            \
        gload_lds16(agp + rowK64 + ko_, &As[bb][4096 + lwb]);     \
        gload_lds16(bgp + ko_,          &Bs[bb][lwb]);            \
        gload_lds16(bgp + rowK64 + ko_, &Bs[bb][4096 + lwb]);     \
    } while (0)

    // prologue: stage tiles 0,1 into bufs 0,1; wait tile0 (allow tile1 in flight)
    STAGE(0, 0);
    STAGE(1, 1);
    asm volatile("s_waitcnt vmcnt(4)" ::: "memory");
    __builtin_amdgcn_s_barrier();
    asm volatile("" ::: "memory");

    int c = 0;                                  // buffer holding tile t
    for (int t = 0; t < nk; ++t) {
        const int s = (c == 0) ? 2 : c - 1;     // (c+2)%3 : buffer for tile t+2
        if (t + 2 < nk) STAGE(t + 2, s);
        const short* ab = &As[c][0];
        const short* bbp = &Bs[c][0];
#pragma unroll
        for (int kk = 0; kk < 2; ++kk) {
            const int cswz = (((kk * 4) + lg) ^ (lr & 7)) << 3;
            s16x8 a0 = *(const s16x8*)&ab[(wm * 32 + lr) * 64 + cswz];
            s16x8 a1 = *(const s16x8*)&ab[(wm * 32 + 16 + lr) * 64 + cswz];
            s16x8 b0 = *(const s16x8*)&bbp[(wn * 64 + lr) * 64 + cswz];
            s16x8 b1 = *(const s16x8*)&bbp[(wn * 64 + 16 + lr) * 64 + cswz];
            s16x8 b2 = *(const s16x8*)&bbp[(wn * 64 + 32 + lr) * 64 + cswz];
            s16x8 b3 = *(const s16x8*)&bbp[(wn * 64 + 48 + lr) * 64 + cswz];
            __builtin_amdgcn_s_setprio(1);
            acc[0][0] = mfma16(a0, b0, acc[0][0]);
            acc[0][1] = mfma16(a0, b1, acc[0][1]);
            acc[0][2] = mfma16(a0, b2, acc[0][2]);
            acc[0][3] = mfma16(a0, b3, acc[0][3]);
            acc[1][0] = mfma16(a1, b0, acc[1][0]);
            acc[1][1] = mfma16(a1, b1, acc[1][1]);
            acc[1][2] = mfma16(a1, b2, acc[1][2]);
            acc[1][3] = mfma16(a1, b3, acc[1][3]);
            __builtin_amdgcn_s_setprio(0);
        }
        if (t + 1 < nk) {
            // before reading buf (t+1): this wave's tile t+1 loads must be done.
            // outstanding = t+1's 4 (oldest) + t+2's 4 (if staged) -> vmcnt(4)/(0).
            if (t + 2 < nk) asm volatile("s_waitcnt vmcnt(4)" ::: "memory");
            else            asm volatile("s_waitcnt vmcnt(0)" ::: "memory");
            __builtin_amdgcn_s_barrier();
            asm volatile("" ::: "memory");
        }
        c = (c == 2) ? 0 : c + 1;
    }
#undef STAGE

#pragma unroll
    for (int ni = 0; ni < 4; ++ni) {
        const int col = n0 + wn * 64 + ni * 16 + lr;
        const float bb = bias[col];
#pragma unroll
        for (int mi = 0; mi < 2; ++mi) {
            const int rbase = m0 + wm * 32 + mi * 16 + lg * 4;
#pragma unroll
            for (int r = 0; r < 4; ++r)
                C[(size_t)(rbase + r) * N + col] = acc[mi][ni][r] + bb;
        }
    }
}

// ---------- rmsnorm + rope + head layout for Q,K ----------
__global__ __launch_bounds__(256) void qkv_post_k(
    const float* __restrict__ Y, const float* __restrict__ qn_w,
    const float* __restrict__ kn_w, const int* __restrict__ start_pos,
    short* __restrict__ Qb, short* __restrict__ Kb) {
    const int m = blockIdx.x;
    const int b = m >> 11, s = m & 2047;
    const float* y = Y + (size_t)m * 3072;
    const int tid = threadIdx.x;

    const float4 q1 = *(const float4*)(y + tid * 8);
    const float4 q2 = *(const float4*)(y + tid * 8 + 4);
    const float2 kv = *(const float2*)(y + 2048 + tid * 2);
    float ssq = q1.x * q1.x + q1.y * q1.y + q1.z * q1.z + q1.w * q1.w
              + q2.x * q2.x + q2.y * q2.y + q2.z * q2.z + q2.w * q2.w;
    float ssk = kv.x * kv.x + kv.y * kv.y;
#pragma unroll
    for (int off = 1; off < 64; off <<= 1) {
        ssq += __shfl_xor(ssq, off);
        ssk += __shfl_xor(ssk, off);
    }
    __shared__ float red[8];
    if ((tid & 63) == 0) { red[tid >> 6] = ssq; red[4 + (tid >> 6)] = ssk; }
    __syncthreads();
    const float tq = red[0] + red[1] + red[2] + red[3];
    const float tk = red[4] + red[5] + red[6] + red[7];
    const float rq = rsqrtf(tq * (1.f / 2048.f) + 1.1920929e-07f);
    const float rk = rsqrtf(tk * (1.f / 512.f) + 1.1920929e-07f);
    const int pos = start_pos[0] + s;

    float qn[8];
    qn[0] = q1.x; qn[1] = q1.y; qn[2] = q1.z; qn[3] = q1.w;
    qn[4] = q2.x; qn[5] = q2.y; qn[6] = q2.z; qn[7] = q2.w;
#pragma unroll
    for (int j = 0; j < 8; ++j) qn[j] *= rq * qn_w[tid * 8 + j];
    const int hq = tid >> 4;
    const int din = (tid * 8) & 127;
    unsigned short ob[8];
#pragma unroll
    for (int j = 0; j < 4; ++j) {
        int tt = (din >> 1) + j;
        float inv = __builtin_exp2f(-0.20762050f * (float)tt);
        float ang = (float)pos * inv;
        float sn, cn;
        __sincosf(ang, &sn, &cn);
        float x1 = qn[2 * j], x2 = qn[2 * j + 1];
        ob[2 * j]     = f2bf(x1 * cn - x2 * sn);
        ob[2 * j + 1] = f2bf(x1 * sn + x2 * cn);
    }
    short* qdst = Qb + (((size_t)(b * 16 + hq) * 2048 + s) * 128 + din);
    uint4 w;
    w.x = (uint32_t)ob[0] | ((uint32_t)ob[1] << 16);
    w.y = (uint32_t)ob[2] | ((uint32_t)ob[3] << 16);
    w.z = (uint32_t)ob[4] | ((uint32_t)ob[5] << 16);
    w.w = (uint32_t)ob[6] | ((uint32_t)ob[7] << 16);
    *(uint4*)qdst = w;

    const int colk = tid * 2;
    const int hk = colk >> 7, dk = colk & 127;
    float k1 = kv.x * rk * kn_w[colk], k2 = kv.y * rk * kn_w[colk + 1];
    {
        int tt = dk >> 1;
        float inv = __builtin_exp2f(-0.20762050f * (float)tt);
        float ang = (float)pos * inv;
        float sn, cn;
        __sincosf(ang, &sn, &cn);
        float r1 = k1 * cn - k2 * sn, r2 = k1 * sn + k2 * cn;
        short* kdst = Kb + (((size_t)(b * 4 + hk) * 2048 + s) * 128 + dk);
        *(uint32_t*)kdst = (uint32_t)f2bf(r1) | ((uint32_t)f2bf(r2) << 16);
    }
}

// ---------- flash attention v4: LPT dispatch + setprio ----------
__global__ __launch_bounds__(256, 2) void attn_fwd_k(
    const short* __restrict__ Qb, const short* __restrict__ Kb,
    const short* __restrict__ Vtb, const float* __restrict__ gate_logits,
    short* __restrict__ attnb) {
    const int S = 2048;
    __shared__ short Ks[2][64 * 128];
    __shared__ short Vs[2][128 * 64];
    const int tid = threadIdx.x, lane = tid & 63;
    const int wid = tid >> 6;                 // head within group
    const int qt = 63 - (int)blockIdx.y;      // LPT: longest first
    const int bhk = blockIdx.x;               // b*4+hk
    const int b = bhk >> 2, hk = bhk & 3;
    const int h = hk * 4 + wid;
    const int q0 = qt * 32;
    const int ql = lane & 31, hi = lane >> 5;
    const int qg = q0 + ql;

    s16x8 qf[8];
    {
        const short* qrow = Qb + (((size_t)(b * 16 + h) * S + qg) * 128 + hi * 8);
#pragma unroll
        for (int kc = 0; kc < 8; ++kc) qf[kc] = *(const s16x8*)(qrow + kc * 16);
    }
    f32x16 ov[4];
#pragma unroll
    for (int dc = 0; dc < 4; ++dc)
#pragma unroll
        for (int r = 0; r < 16; ++r) ov[dc][r] = 0.f;
    float mrun = -3.0e38f, lrun = 0.f;
    const float cs = 0.12751745f;     // (1/sqrt(128)) * log2(e)
    const float THR = 90.509668f;     // 8*sqrt(128)

    const short* kg[4]; const short* vg[4]; int lb[4];
#pragma unroll
    for (int i = 0; i < 4; ++i) {
        int oo = (i * 256 + tid) * 8;
        lb[i] = (i * 256 + (tid & ~63)) * 8;
        {
            int row = oo >> 7, col = oo & 127, ch = col >> 3;
            kg[i] = Kb + ((size_t)bhk * S + row) * 128 + ((ch ^ (row & 7)) << 3);
        }
        {
            int row = oo >> 6, col = oo & 63, ch = col >> 3;
            vg[i] = Vtb + ((size_t)bhk * 128 + row) * S + ((ch ^ (row & 7)) << 3);
        }
    }
    const int ntiles = ((q0 + 31) >> 6) + 1;
#pragma unroll
    for (int i = 0; i < 4; ++i) gload_lds16(kg[i], &Ks[0][lb[i]]);
#pragma unroll
    for (int i = 0; i < 4; ++i) gload_lds16(vg[i], &Vs[0][lb[i]]);
    asm volatile("s_waitcnt vmcnt(0)");
    __syncthreads();

    int cur = 0;
    for (int jt = 0; jt < ntiles; ++jt) {
        const int j0 = jt * 64;
        if (jt + 1 < ntiles) {
            const int jn = j0 + 64;
#pragma unroll
            for (int i = 0; i < 4; ++i) gload_lds16(kg[i] + (size_t)jn * 128, &Ks[cur ^ 1][lb[i]]);
#pragma unroll
            for (int i = 0; i < 4; ++i) gload_lds16(vg[i] + jn, &Vs[cur ^ 1][lb[i]]);
        }
#pragma unroll
        for (int t = 0; t < 2; ++t) {
            const int jb = j0 + t * 32;
            if (jb > q0 + 31) continue;             // subtile fully masked
            const bool fsub = (jb + 31 <= q0);      // fully unmasked (wave-uniform)
            f32x16 sacc;
#pragma unroll
            for (int r = 0; r < 16; ++r) sacc[r] = 0.f;
            const int krl = t * 32 + ql;
            __builtin_amdgcn_s_setprio(1);
#pragma unroll
            for (int kc = 0; kc < 8; ++kc) {
                int ch = kc * 2 + hi;
                s16x8 kf = *(const s16x8*)&Ks[cur][krl * 128 + ((ch ^ (krl & 7)) << 3)];
                sacc = mfma32(kf, qf[kc], sacc);
            }
            __builtin_amdgcn_s_setprio(0);
            float p[16];
            if (fsub) {
#pragma unroll
                for (int r = 0; r < 16; ++r) p[r] = sacc[r];
            } else {
#pragma unroll
                for (int r = 0; r < 16; ++r) {
                    int kvg = jb + ((r & 3) + 8 * (r >> 2) + 4 * hi);
                    p[r] = (kvg <= qg) ? sacc[r] : -3.0e38f;
                }
            }
            float m0a = fmaxf(p[0], p[1]),  m1a = fmaxf(p[2], p[3]);
            float m2a = fmaxf(p[4], p[5]),  m3a = fmaxf(p[6], p[7]);
            float m4a = fmaxf(p[8], p[9]),  m5a = fmaxf(p[10], p[11]);
            float m6a = fmaxf(p[12], p[13]), m7a = fmaxf(p[14], p[15]);
            float mb0 = fmaxf(m0a, m1a), mb1 = fmaxf(m2a, m3a);
            float mb2 = fmaxf(m4a, m5a), mb3 = fmaxf(m6a, m7a);
            float pmax = fmaxf(fmaxf(mb0, mb1), fmaxf(mb2, mb3));
            pmax = fmaxf(pmax, __shfl_xor(pmax, 32));
            if (__any(pmax - mrun > THR)) {
                float mnew = fmaxf(mrun, pmax);
                float alpha = __builtin_exp2f((mrun - mnew) * cs);
                lrun *= alpha;
#pragma unroll
                for (int r = 0; r < 16; ++r) {
                    int cr = (r & 3) + 8 * (r >> 2) + 4 * hi;
                    float ar = __uint_as_float(
                        (uint32_t)__builtin_amdgcn_ds_bpermute(cr << 2, (int)__float_as_uint(alpha)));
                    ov[0][r] *= ar; ov[1][r] *= ar; ov[2][r] *= ar; ov[3][r] *= ar;
                }
                mrun = mnew;
            }
#pragma unroll
            for (int r = 0; r < 16; ++r) p[r] = __builtin_exp2f((p[r] - mrun) * cs);
            float s0a = p[0] + p[1],  s1a = p[2] + p[3];
            float s2a = p[4] + p[5],  s3a = p[6] + p[7];
            float s4a = p[8] + p[9],  s5a = p[10] + p[11];
            float s6a = p[12] + p[13], s7a = p[14] + p[15];
            float ps = ((s0a + s1a) + (s2a + s3a)) + ((s4a + s5a) + (s6a + s7a));
            ps += __shfl_xor(ps, 32);
            lrun += ps;
            uint32_t w0 = cvtpk_bf16(p[0], p[1]),   w1 = cvtpk_bf16(p[2], p[3]);
            uint32_t w2 = cvtpk_bf16(p[4], p[5]),   w3 = cvtpk_bf16(p[6], p[7]);
            uint32_t w4 = cvtpk_bf16(p[8], p[9]),   w5 = cvtpk_bf16(p[10], p[11]);
            uint32_t w6 = cvtpk_bf16(p[12], p[13]), w7 = cvtpk_bf16(p[14], p[15]);
            uint32_t w0s = (uint32_t)__shfl_xor((int)w0, 32);
            uint32_t w1s = (uint32_t)__shfl_xor((int)w1, 32);
            uint32_t w2s = (uint32_t)__shfl_xor((int)w2, 32);
            uint32_t w3s = (uint32_t)__shfl_xor((int)w3, 32);
            uint32_t w4s = (uint32_t)__shfl_xor((int)w4, 32);
            uint32_t w5s = (uint32_t)__shfl_xor((int)w5, 32);
            uint32_t w6s = (uint32_t)__shfl_xor((int)w6, 32);
            uint32_t w7s = (uint32_t)__shfl_xor((int)w7, 32);
            union { uint32_t u[4]; s16x8 v; } pa0, pa1;
            pa0.u[0] = hi ? w2s : w0;  pa0.u[1] = hi ? w3s : w1;
            pa0.u[2] = hi ? w2  : w0s; pa0.u[3] = hi ? w3  : w1s;
            pa1.u[0] = hi ? w6s : w4;  pa1.u[1] = hi ? w7s : w5;
            pa1.u[2] = hi ? w6  : w4s; pa1.u[3] = hi ? w7  : w5s;
            __builtin_amdgcn_s_setprio(1);
#pragma unroll
            for (int dc = 0; dc < 4; ++dc) {
                int d = dc * 32 + ql;
                int c0i = t * 4 + hi;
                s16x8 vf0 = *(const s16x8*)&Vs[cur][d * 64 + ((c0i ^ (d & 7)) << 3)];
                ov[dc] = mfma32(pa0.v, vf0, ov[dc]);
                int c1i = t * 4 + 2 + hi;
                s16x8 vf1 = *(const s16x8*)&Vs[cur][d * 64 + ((c1i ^ (d & 7)) << 3)];
                ov[dc] = mfma32(pa1.v, vf1, ov[dc]);
            }
            __builtin_amdgcn_s_setprio(0);
        }
        asm volatile("s_waitcnt vmcnt(0)");
        __syncthreads();
        cur ^= 1;
    }
    const float gl = gate_logits[h];
    const float gate = 1.f / (1.f + __expf(-gl));
    const float linv = gate / lrun;
#pragma unroll
    for (int r = 0; r < 16; ++r) {
        int cr = (r & 3) + 8 * (r >> 2) + 4 * hi;
        float sc = __uint_as_float(
            (uint32_t)__builtin_amdgcn_ds_bpermute(cr << 2, (int)__float_as_uint(linv)));
        int qrow = q0 + cr;
        short* orow = attnb + ((size_t)(b * S) + qrow) * 2048 + h * 128 + ql;
#pragma unroll
        for (int dc = 0; dc < 4; ++dc)
            orow[dc * 32] = (short)f2bf(ov[dc][r] * sc);
    }
}

// ---------- launch ----------
extern "C" void kernel_launch(void* const* d_in, const int* in_sizes, int n_in,
                              void* d_out, int out_size, void* d_ws, size_t ws_size,
                              hipStream_t stream) {
    const float* x  = (const float*)d_in[0];
    const float* Wq = (const float*)d_in[1];
    const float* bq = (const float*)d_in[2];
    const float* Wk = (const float*)d_in[3];
    const float* bk = (const float*)d_in[4];
    const float* Wv = (const float*)d_in[5];
    const float* bv = (const float*)d_in[6];
    const float* Wo = (const float*)d_in[7];
    const float* bo = (const float*)d_in[8];
    const float* qn = (const float*)d_in[9];
    const float* kn = (const float*)d_in[10];
    const float* gl = (const float*)d_in[11];
    const int* sp   = (const int*)d_in[13];
    float* out = (float*)d_out;

    char* ws = (char*)d_ws;
    const size_t NEED = 96481280;
    if (ws_size < NEED) return;
    short* xb    = (short*)(ws + 0);            // 16 MiB, reused as Qb
    short* wqkvT = (short*)(ws + 16777216);     // 12 MiB
    short* woT   = (short*)(ws + 29360128);     // 8 MiB
    float* bqkv  = (float*)(ws + 37748736);     // 12 KiB
    float* Y     = (float*)(ws + 37761024);     // 48 MiB, head reused as attnb
    short* Kb    = (short*)(ws + 88092672);     // 4 MiB
    short* Vtb   = (short*)(ws + 92286976);     // 4 MiB
    short* Qb    = xb;
    short* attnb = (short*)Y;

    f32_to_bf16_k<<<4096, 256, 0, stream>>>(x, xb, 1048576);
    transpose_f32_bf16_k<<<dim3(32, 32, 1), 256, 0, stream>>>(Wq, 0, 2048, wqkvT, 0, 2048);
    transpose_f32_bf16_k<<<dim3(8, 32, 1), 256, 0, stream>>>(Wk, 0, 512, wqkvT + (size_t)2048 * 2048, 0, 2048);
    transpose_f32_bf16_k<<<dim3(8, 32, 1), 256, 0, stream>>>(Wv, 0, 512, wqkvT + (size_t)2560 * 2048, 0, 2048);
    transpose_f32_bf16_k<<<dim3(32, 32, 1), 256, 0, stream>>>(Wo, 0, 2048, woT, 0, 2048);
    concat_bias_k<<<12, 256, 0, stream>>>(bq, bk, bv, bqkv);
    gemm_bt_k<<<dim3(24, 32), 512, 0, stream>>>(xb, wqkvT, bqkv, Y, 4096, 3072, 2048);
    qkv_post_k<<<4096, 256, 0, stream>>>(Y, qn, kn, sp, Qb, Kb);
    transpose_f32_bf16_k<<<dim3(8, 32, 2), 256, 0, stream>>>(
        Y + 2560, (size_t)2048 * 3072, 3072, Vtb, (size_t)512 * 2048, 2048);
    attn_fwd_k<<<dim3(8, 64), 256, 0, stream>>>(Qb, Kb, Vtb, gl, attnb);
    gemm_bt_k<<<dim3(16, 32), 512, 0, stream>>>(attnb, woT, bo, out, 4096, 2048, 2048);
}

// Round 7
// 273.814 us; speedup vs baseline: 1.0713x; 1.0713x over previous
//
#include <hip/hip_runtime.h>
#include <hip/hip_bf16.h>
#include <stdint.h>

#define DEV __device__ __forceinline__

typedef short     s16x8  __attribute__((ext_vector_type(8)));
typedef __bf16    bf16v8 __attribute__((ext_vector_type(8)));
typedef float     f32x4  __attribute__((ext_vector_type(4)));
typedef float     f32x16 __attribute__((ext_vector_type(16)));

// ---------- helpers ----------
DEV unsigned short f2bf(float x) {
    uint32_t u = __float_as_uint(x);
    uint32_t r = (u + 0x7FFFu + ((u >> 16) & 1u)) >> 16;
    return (unsigned short)r;
}

DEV void gload_lds16(const void* g, void* l) {
    __builtin_amdgcn_global_load_lds((const __attribute__((address_space(1))) void*)g,
                                     (__attribute__((address_space(3))) void*)l,
                                     16, 0, 0);
}

DEV f32x4 mfma16(s16x8 a, s16x8 b, f32x4 c) {
    return __builtin_amdgcn_mfma_f32_16x16x32_bf16(
        __builtin_bit_cast(bf16v8, a), __builtin_bit_cast(bf16v8, b), c, 0, 0, 0);
}
DEV f32x16 mfma32(s16x8 a, s16x8 b, f32x16 c) {
    return __builtin_amdgcn_mfma_f32_32x32x16_bf16(
        __builtin_bit_cast(bf16v8, a), __builtin_bit_cast(bf16v8, b), c, 0, 0, 0);
}

DEV uint32_t cvtpk_bf16(float lo, float hi) {
    uint32_t r;
    asm volatile("v_cvt_pk_bf16_f32 %0, %1, %2" : "=v"(r) : "v"(lo), "v"(hi));
    return r;
}

// raw barrier with compiler + scheduler fences (NO vmcnt/lgkm drain)
DEV void barx() {
    asm volatile("" ::: "memory");
    __builtin_amdgcn_s_barrier();
    __builtin_amdgcn_sched_barrier(0);
    asm volatile("" ::: "memory");
}

// ---------- elementwise f32 -> bf16 (8 elems / thread) ----------
__global__ void f32_to_bf16_k(const float* __restrict__ in, short* __restrict__ out, int n8) {
    int i = blockIdx.x * blockDim.x + threadIdx.x;
    if (i >= n8) return;
    const float4 a = *(const float4*)(in + (size_t)i * 8);
    const float4 b = *(const float4*)(in + (size_t)i * 8 + 4);
    uint4 w;
    w.x = (uint32_t)f2bf(a.x) | ((uint32_t)f2bf(a.y) << 16);
    w.y = (uint32_t)f2bf(a.z) | ((uint32_t)f2bf(a.w) << 16);
    w.z = (uint32_t)f2bf(b.x) | ((uint32_t)f2bf(b.y) << 16);
    w.w = (uint32_t)f2bf(b.z) | ((uint32_t)f2bf(b.w) << 16);
    *(uint4*)(out + (size_t)i * 8) = w;
}

// ---------- tiled transpose f32 (R x C) -> bf16 (C x R) ----------
__global__ __launch_bounds__(256) void transpose_f32_bf16_k(
    const float* __restrict__ in, size_t in_batch, int ld_in,
    short* __restrict__ out, size_t out_batch, int ld_out) {
    __shared__ float tile[64][65];
    const float* ip = in + (size_t)blockIdx.z * in_batch;
    short* op = out + (size_t)blockIdx.z * out_batch;
    const int c0 = blockIdx.x * 64, r0 = blockIdx.y * 64;
    const int t = threadIdx.x;
    const int cc4 = (t & 15) * 4;
    const int rr  = t >> 4;
#pragma unroll
    for (int p = 0; p < 4; ++p) {
        int r = rr + p * 16;
        float4 v = *(const float4*)(ip + (size_t)(r0 + r) * ld_in + c0 + cc4);
        tile[r][cc4 + 0] = v.x; tile[r][cc4 + 1] = v.y;
        tile[r][cc4 + 2] = v.z; tile[r][cc4 + 3] = v.w;
    }
    __syncthreads();
#pragma unroll
    for (int p = 0; p < 4; ++p) {
        int oc  = (t >> 4) + p * 16;
        int rr4 = (t & 15) * 4;
        ushort4 w;
        w.x = f2bf(tile[rr4 + 0][oc]);
        w.y = f2bf(tile[rr4 + 1][oc]);
        w.z = f2bf(tile[rr4 + 2][oc]);
        w.w = f2bf(tile[rr4 + 3][oc]);
        *(ushort4*)(op + (size_t)(c0 + oc) * ld_out + r0 + rr4) = w;
    }
}

// ---------- bias concat ----------
__global__ void concat_bias_k(const float* __restrict__ bq, const float* __restrict__ bk,
                              const float* __restrict__ bv, float* __restrict__ o) {
    int i = blockIdx.x * 256 + threadIdx.x;
    if (i < 2048)       o[i] = bq[i];
    else if (i < 2560)  o[i] = bk[i - 2048];
    else if (i < 3072)  o[i] = bv[i - 2560];
}

// ---------- GEMM v3: phase-interleaved (T3+T4+T2+T5) ----------
// C[M,N] = A[M,K](bf16) * Bt[N,K]^T + bias, f32 out.
// BM=256, BN=128, BK=64; 8 waves (4M x 2N), wave-out 64x64 via 32x32x16 MFMA.
// LDS k-major: A[buf][ks][256][16], B[buf][ks][128][16] (96 KB total).
// 2 phases/K-tile (kslices 0-1, 2-3); each phase: 8 ds_read || 3 gload_lds
// -> barrier -> setprio(1) 8 MFMA setprio(0) -> counted vmcnt -> barrier.
// Steady-state vmcnt(6): 2 half-K staging units (3 lines each) stay in flight.
__global__ __launch_bounds__(512, 2) void gemm256_k(
    const short* __restrict__ A, const short* __restrict__ Bt,
    const float* __restrict__ bias, float* __restrict__ C,
    int M, int N, int K) {
    __shared__ short As[2][16384];   // [buf][ks*4096 + row*16 + k'']
    __shared__ short Bs[2][8192];    // [buf][ks*2048 + row*16 + k'']
    const int tid = threadIdx.x;
    const int gx = gridDim.x;
    const int nwg = gx * gridDim.y;
    const int flat = blockIdx.y * gx + blockIdx.x;
    const int cpx = nwg >> 3;
    const int swz = (flat & 7) * cpx + (flat >> 3);
    const int m0 = (swz / gx) * 256, n0 = (swz % gx) * 128;
    const int lane = tid & 63, wid = tid >> 6;
    const int wm = wid >> 1, wn = wid & 1;
    const int ql = lane & 31, hi = lane >> 5;

    // staging source (pre-swizzled: linear LDS slot s holds logical k-block s^(row&1))
    const int slotswz = ((tid & 1) ^ ((tid >> 1) & 1)) * 8;
    const short* Ag = A  + (size_t)(m0 + (tid >> 1)) * K + slotswz;          // rows 0..255
    const short* Bg = Bt + (size_t)(n0 + ((tid >> 1) & 127)) * K
                         + (tid >> 8) * 16 + slotswz;                         // ksl = tid>>8
    const int lwb = (tid & ~63) * 8;   // wave-uniform LDS base (shorts)

    f32x16 acc[2][2];
#pragma unroll
    for (int mi = 0; mi < 2; ++mi)
#pragma unroll
        for (int ni = 0; ni < 2; ++ni)
#pragma unroll
            for (int r = 0; r < 16; ++r) acc[mi][ni][r] = 0.f;

    const int nk = K >> 6;

#define SKP0(kt, dd) do {                                        \
        gload_lds16(Ag + (kt) * 64,      &As[dd][lwb]);          \
        gload_lds16(Ag + (kt) * 64 + 16, &As[dd][4096 + lwb]);   \
        gload_lds16(Bg + (kt) * 64,      &Bs[dd][lwb]);          \
    } while (0)
#define SKP1(kt, dd) do {                                        \
        gload_lds16(Ag + (kt) * 64 + 32, &As[dd][8192 + lwb]);   \
        gload_lds16(Ag + (kt) * 64 + 48, &As[dd][12288 + lwb]);  \
        gload_lds16(Bg + (kt) * 64 + 32, &Bs[dd][4096 + lwb]);   \
    } while (0)

    // prologue: t0 fully (6 lines), t1.kp0 (3 lines); oldest 3 must land
    SKP0(0, 0); SKP1(0, 0); SKP0(1, 1);
    asm volatile("s_waitcnt vmcnt(6)" ::: "memory");
    barx();

    const int swz8 = (hi ^ (ql & 1)) << 3;
    const int arow = wm * 64 + ql;
    const int brow = wn * 64 + ql;

    for (int t = 0; t < nk; ++t) {
        const int d = t & 1;
        const short* ab = As[d];
        const short* bb = Bs[d];
        // ---- Phase A: kslices 0,1 ----
        {
            s16x8 af[2][2], bf_[2][2];
#pragma unroll
            for (int k2 = 0; k2 < 2; ++k2) {
                af[k2][0]  = *(const s16x8*)&ab[k2 * 4096 + arow * 16 + swz8];
                af[k2][1]  = *(const s16x8*)&ab[k2 * 4096 + (arow + 32) * 16 + swz8];
                bf_[k2][0] = *(const s16x8*)&bb[k2 * 2048 + brow * 16 + swz8];
                bf_[k2][1] = *(const s16x8*)&bb[k2 * 2048 + (brow + 32) * 16 + swz8];
            }
            if (t + 1 < nk) SKP1(t + 1, d ^ 1);
            barx();
            __builtin_amdgcn_s_setprio(1);
#pragma unroll
            for (int k2 = 0; k2 < 2; ++k2)
#pragma unroll
                for (int mi = 0; mi < 2; ++mi)
#pragma unroll
                    for (int ni = 0; ni < 2; ++ni)
                        acc[mi][ni] = mfma32(af[k2][mi], bf_[k2][ni], acc[mi][ni]);
            __builtin_amdgcn_s_setprio(0);
            __builtin_amdgcn_sched_barrier(0);
            if (t + 1 < nk) asm volatile("s_waitcnt vmcnt(6)" ::: "memory"); // t.kp1 done
            else            asm volatile("s_waitcnt vmcnt(0)" ::: "memory");
            barx();
        }
        // ---- Phase B: kslices 2,3 ----
        {
            s16x8 af[2][2], bf_[2][2];
#pragma unroll
            for (int k2 = 0; k2 < 2; ++k2) {
                const int ksl = 2 + k2;
                af[k2][0]  = *(const s16x8*)&ab[ksl * 4096 + arow * 16 + swz8];
                af[k2][1]  = *(const s16x8*)&ab[ksl * 4096 + (arow + 32) * 16 + swz8];
                bf_[k2][0] = *(const s16x8*)&bb[ksl * 2048 + brow * 16 + swz8];
                bf_[k2][1] = *(const s16x8*)&bb[ksl * 2048 + (brow + 32) * 16 + swz8];
            }
            if (t + 2 < nk) SKP0(t + 2, d);
            barx();
            __builtin_amdgcn_s_setprio(1);
#pragma unroll
            for (int k2 = 0; k2 < 2; ++k2)
#pragma unroll
                for (int mi = 0; mi < 2; ++mi)
#pragma unroll
                    for (int ni = 0; ni < 2; ++ni)
                        acc[mi][ni] = mfma32(af[k2][mi], bf_[k2][ni], acc[mi][ni]);
            __builtin_amdgcn_s_setprio(0);
            __builtin_amdgcn_sched_barrier(0);
            if (t + 1 < nk) {                      // (t+1).kp0 must be done
                if (t + 2 < nk) asm volatile("s_waitcnt vmcnt(6)" ::: "memory");
                else            asm volatile("s_waitcnt vmcnt(3)" ::: "memory");
                barx();
            }
        }
    }
#undef SKP0
#undef SKP1

    // epilogue: C = acc + bias
#pragma unroll
    for (int ni = 0; ni < 2; ++ni) {
        const int col = n0 + wn * 64 + ni * 32 + ql;
        const float bbv = bias[col];
#pragma unroll
        for (int mi = 0; mi < 2; ++mi) {
            const int rb = m0 + wm * 64 + mi * 32;
#pragma unroll
            for (int r = 0; r < 16; ++r) {
                const int row = rb + (r & 3) + 8 * (r >> 2) + 4 * hi;
                C[(size_t)row * N + col] = acc[mi][ni][r] + bbv;
            }
        }
    }
}

// ---------- rmsnorm + rope + head layout for Q,K ----------
__global__ __launch_bounds__(256) void qkv_post_k(
    const float* __restrict__ Y, const float* __restrict__ qn_w,
    const float* __restrict__ kn_w, const int* __restrict__ start_pos,
    short* __restrict__ Qb, short* __restrict__ Kb) {
    const int m = blockIdx.x;
    const int b = m >> 11, s = m & 2047;
    const float* y = Y + (size_t)m * 3072;
    const int tid = threadIdx.x;

    const float4 q1 = *(const float4*)(y + tid * 8);
    const float4 q2 = *(const float4*)(y + tid * 8 + 4);
    const float2 kv = *(const float2*)(y + 2048 + tid * 2);
    float ssq = q1.x * q1.x + q1.y * q1.y + q1.z * q1.z + q1.w * q1.w
              + q2.x * q2.x + q2.y * q2.y + q2.z * q2.z + q2.w * q2.w;
    float ssk = kv.x * kv.x + kv.y * kv.y;
#pragma unroll
    for (int off = 1; off < 64; off <<= 1) {
        ssq += __shfl_xor(ssq, off);
        ssk += __shfl_xor(ssk, off);
    }
    __shared__ float red[8];
    if ((tid & 63) == 0) { red[tid >> 6] = ssq; red[4 + (tid >> 6)] = ssk; }
    __syncthreads();
    const float tq = red[0] + red[1] + red[2] + red[3];
    const float tk = red[4] + red[5] + red[6] + red[7];
    const float rq = rsqrtf(tq * (1.f / 2048.f) + 1.1920929e-07f);
    const float rk = rsqrtf(tk * (1.f / 512.f) + 1.1920929e-07f);
    const int pos = start_pos[0] + s;

    float qn[8];
    qn[0] = q1.x; qn[1] = q1.y; qn[2] = q1.z; qn[3] = q1.w;
    qn[4] = q2.x; qn[5] = q2.y; qn[6] = q2.z; qn[7] = q2.w;
#pragma unroll
    for (int j = 0; j < 8; ++j) qn[j] *= rq * qn_w[tid * 8 + j];
    const int hq = tid >> 4;
    const int din = (tid * 8) & 127;
    unsigned short ob[8];
#pragma unroll
    for (int j = 0; j < 4; ++j) {
        int tt = (din >> 1) + j;
        float inv = __builtin_exp2f(-0.20762050f * (float)tt);
        float ang = (float)pos * inv;
        float sn, cn;
        __sincosf(ang, &sn, &cn);
        float x1 = qn[2 * j], x2 = qn[2 * j + 1];
        ob[2 * j]     = f2bf(x1 * cn - x2 * sn);
        ob[2 * j + 1] = f2bf(x1 * sn + x2 * cn);
    }
    short* qdst = Qb + (((size_t)(b * 16 + hq) * 2048 + s) * 128 + din);
    uint4 w;
    w.x = (uint32_t)ob[0] | ((uint32_t)ob[1] << 16);
    w.y = (uint32_t)ob[2] | ((uint32_t)ob[3] << 16);
    w.z = (uint32_t)ob[4] | ((uint32_t)ob[5] << 16);
    w.w = (uint32_t)ob[6] | ((uint32_t)ob[7] << 16);
    *(uint4*)qdst = w;

    const int colk = tid * 2;
    const int hk = colk >> 7, dk = colk & 127;
    float k1 = kv.x * rk * kn_w[colk], k2 = kv.y * rk * kn_w[colk + 1];
    {
        int tt = dk >> 1;
        float inv = __builtin_exp2f(-0.20762050f * (float)tt);
        float ang = (float)pos * inv;
        float sn, cn;
        __sincosf(ang, &sn, &cn);
        float r1 = k1 * cn - k2 * sn, r2 = k1 * sn + k2 * cn;
        short* kdst = Kb + (((size_t)(b * 4 + hk) * 2048 + s) * 128 + dk);
        *(uint32_t*)kdst = (uint32_t)f2bf(r1) | ((uint32_t)f2bf(r2) << 16);
    }
}

// ---------- flash attention: LPT dispatch + setprio ----------
__global__ __launch_bounds__(256, 2) void attn_fwd_k(
    const short* __restrict__ Qb, const short* __restrict__ Kb,
    const short* __restrict__ Vtb, const float* __restrict__ gate_logits,
    short* __restrict__ attnb) {
    const int S = 2048;
    __shared__ short Ks[2][64 * 128];
    __shared__ short Vs[2][128 * 64];
    const int tid = threadIdx.x, lane = tid & 63;
    const int wid = tid >> 6;
    const int qt = 63 - (int)blockIdx.y;      // LPT: longest first
    const int bhk = blockIdx.x;
    const int b = bhk >> 2, hk = bhk & 3;
    const int h = hk * 4 + wid;
    const int q0 = qt * 32;
    const int ql = lane & 31, hi = lane >> 5;
    const int qg = q0 + ql;

    s16x8 qf[8];
    {
        const short* qrow = Qb + (((size_t)(b * 16 + h) * S + qg) * 128 + hi * 8);
#pragma unroll
        for (int kc = 0; kc < 8; ++kc) qf[kc] = *(const s16x8*)(qrow + kc * 16);
    }
    f32x16 ov[4];
#pragma unroll
    for (int dc = 0; dc < 4; ++dc)
#pragma unroll
        for (int r = 0; r < 16; ++r) ov[dc][r] = 0.f;
    float mrun = -3.0e38f, lrun = 0.f;
    const float cs = 0.12751745f;
    const float THR = 90.509668f;

    const short* kg[4]; const short* vg[4]; int lb[4];
#pragma unroll
    for (int i = 0; i < 4; ++i) {
        int oo = (i * 256 + tid) * 8;
        lb[i] = (i * 256 + (tid & ~63)) * 8;
        {
            int row = oo >> 7, col = oo & 127, ch = col >> 3;
            kg[i] = Kb + ((size_t)bhk * S + row) * 128 + ((ch ^ (row & 7)) << 3);
        }
        {
            int row = oo >> 6, col = oo & 63, ch = col >> 3;
            vg[i] = Vtb + ((size_t)bhk * 128 + row) * S + ((ch ^ (row & 7)) << 3);
        }
    }
    const int ntiles = ((q0 + 31) >> 6) + 1;
#pragma unroll
    for (int i = 0; i < 4; ++i) gload_lds16(kg[i], &Ks[0][lb[i]]);
#pragma unroll
    for (int i = 0; i < 4; ++i) gload_lds16(vg[i], &Vs[0][lb[i]]);
    asm volatile("s_waitcnt vmcnt(0)");
    __syncthreads();

    int cur = 0;
    for (int jt = 0; jt < ntiles; ++jt) {
        const int j0 = jt * 64;
        if (jt + 1 < ntiles) {
            const int jn = j0 + 64;
#pragma unroll
            for (int i = 0; i < 4; ++i) gload_lds16(kg[i] + (size_t)jn * 128, &Ks[cur ^ 1][lb[i]]);
#pragma unroll
            for (int i = 0; i < 4; ++i) gload_lds16(vg[i] + jn, &Vs[cur ^ 1][lb[i]]);
        }
#pragma unroll
        for (int t = 0; t < 2; ++t) {
            const int jb = j0 + t * 32;
            if (jb > q0 + 31) continue;
            const bool fsub = (jb + 31 <= q0);
            f32x16 sacc;
#pragma unroll
            for (int r = 0; r < 16; ++r) sacc[r] = 0.f;
            const int krl = t * 32 + ql;
            __builtin_amdgcn_s_setprio(1);
#pragma unroll
            for (int kc = 0; kc < 8; ++kc) {
                int ch = kc * 2 + hi;
                s16x8 kf = *(const s16x8*)&Ks[cur][krl * 128 + ((ch ^ (krl & 7)) << 3)];
                sacc = mfma32(kf, qf[kc], sacc);
            }
            __builtin_amdgcn_s_setprio(0);
            float p[16];
            if (fsub) {
#pragma unroll
                for (int r = 0; r < 16; ++r) p[r] = sacc[r];
            } else {
#pragma unroll
                for (int r = 0; r < 16; ++r) {
                    int kvg = jb + ((r & 3) + 8 * (r >> 2) + 4 * hi);
                    p[r] = (kvg <= qg) ? sacc[r] : -3.0e38f;
                }
            }
            float m0a = fmaxf(p[0], p[1]),  m1a = fmaxf(p[2], p[3]);
            float m2a = fmaxf(p[4], p[5]),  m3a = fmaxf(p[6], p[7]);
            float m4a = fmaxf(p[8], p[9]),  m5a = fmaxf(p[10], p[11]);
            float m6a = fmaxf(p[12], p[13]), m7a = fmaxf(p[14], p[15]);
            float mb0 = fmaxf(m0a, m1a), mb1 = fmaxf(m2a, m3a);
            float mb2 = fmaxf(m4a, m5a), mb3 = fmaxf(m6a, m7a);
            float pmax = fmaxf(fmaxf(mb0, mb1), fmaxf(mb2, mb3));
            pmax = fmaxf(pmax, __shfl_xor(pmax, 32));
            if (__any(pmax - mrun > THR)) {
                float mnew = fmaxf(mrun, pmax);
                float alpha = __builtin_exp2f((mrun - mnew) * cs);
                lrun *= alpha;
#pragma unroll
                for (int r = 0; r < 16; ++r) {
                    int cr = (r & 3) + 8 * (r >> 2) + 4 * hi;
                    float ar = __uint_as_float(
                        (uint32_t)__builtin_amdgcn_ds_bpermute(cr << 2, (int)__float_as_uint(alpha)));
                    ov[0][r] *= ar; ov[1][r] *= ar; ov[2][r] *= ar; ov[3][r] *= ar;
                }
                mrun = mnew;
            }
#pragma unroll
            for (int r = 0; r < 16; ++r) p[r] = __builtin_exp2f((p[r] - mrun) * cs);
            float s0a = p[0] + p[1],  s1a = p[2] + p[3];
            float s2a = p[4] + p[5],  s3a = p[6] + p[7];
            float s4a = p[8] + p[9],  s5a = p[10] + p[11];
            float s6a = p[12] + p[13], s7a = p[14] + p[15];
            float ps = ((s0a + s1a) + (s2a + s3a)) + ((s4a + s5a) + (s6a + s7a));
            ps += __shfl_xor(ps, 32);
            lrun += ps;
            uint32_t w0 = cvtpk_bf16(p[0], p[1]),   w1 = cvtpk_bf16(p[2], p[3]);
            uint32_t w2 = cvtpk_bf16(p[4], p[5]),   w3 = cvtpk_bf16(p[6], p[7]);
            uint32_t w4 = cvtpk_bf16(p[8], p[9]),   w5 = cvtpk_bf16(p[10], p[11]);
            uint32_t w6 = cvtpk_bf16(p[12], p[13]), w7 = cvtpk_bf16(p[14], p[15]);
            uint32_t w0s = (uint32_t)__shfl_xor((int)w0, 32);
            uint32_t w1s = (uint32_t)__shfl_xor((int)w1, 32);
            uint32_t w2s = (uint32_t)__shfl_xor((int)w2, 32);
            uint32_t w3s = (uint32_t)__shfl_xor((int)w3, 32);
            uint32_t w4s = (uint32_t)__shfl_xor((int)w4, 32);
            uint32_t w5s = (uint32_t)__shfl_xor((int)w5, 32);
            uint32_t w6s = (uint32_t)__shfl_xor((int)w6, 32);
            uint32_t w7s = (uint32_t)__shfl_xor((int)w7, 32);
            union { uint32_t u[4]; s16x8 v; } pa0, pa1;
            pa0.u[0] = hi ? w2s : w0;  pa0.u[1] = hi ? w3s : w1;
            pa0.u[2] = hi ? w2  : w0s; pa0.u[3] = hi ? w3  : w1s;
            pa1.u[0] = hi ? w6s : w4;  pa1.u[1] = hi ? w7s : w5;
            pa1.u[2] = hi ? w6  : w4s; pa1.u[3] = hi ? w7  : w5s;
            __builtin_amdgcn_s_setprio(1);
#pragma unroll
            for (int dc = 0; dc < 4; ++dc) {
                int d = dc * 32 + ql;
                int c0i = t * 4 + hi;
                s16x8 vf0 = *(const s16x8*)&Vs[cur][d * 64 + ((c0i ^ (d & 7)) << 3)];
                ov[dc] = mfma32(pa0.v, vf0, ov[dc]);
                int c1i = t * 4 + 2 + hi;
                s16x8 vf1 = *(const s16x8*)&Vs[cur][d * 64 + ((c1i ^ (d & 7)) << 3)];
                ov[dc] = mfma32(pa1.v, vf1, ov[dc]);
            }
            __builtin_amdgcn_s_setprio(0);
        }
        asm volatile("s_waitcnt vmcnt(0)");
        __syncthreads();
        cur ^= 1;
    }
    const float gl = gate_logits[h];
    const float gate = 1.f / (1.f + __expf(-gl));
    const float linv = gate / lrun;
#pragma unroll
    for (int r = 0; r < 16; ++r) {
        int cr = (r & 3) + 8 * (r >> 2) + 4 * hi;
        float sc = __uint_as_float(
            (uint32_t)__builtin_amdgcn_ds_bpermute(cr << 2, (int)__float_as_uint(linv)));
        int qrow = q0 + cr;
        short* orow = attnb + ((size_t)(b * S) + qrow) * 2048 + h * 128 + ql;
#pragma unroll
        for (int dc = 0; dc < 4; ++dc)
            orow[dc * 32] = (short)f2bf(ov[dc][r] * sc);
    }
}

// ---------- launch ----------
extern "C" void kernel_launch(void* const* d_in, const int* in_sizes, int n_in,
                              void* d_out, int out_size, void* d_ws, size_t ws_size,
                              hipStream_t stream) {
    const float* x  = (const float*)d_in[0];
    const float* Wq = (const float*)d_in[1];
    const float* bq = (const float*)d_in[2];
    const float* Wk = (const float*)d_in[3];
    const float* bk = (const float*)d_in[4];
    const float* Wv = (const float*)d_in[5];
    const float* bv = (const float*)d_in[6];
    const float* Wo = (const float*)d_in[7];
    const float* bo = (const float*)d_in[8];
    const float* qn = (const float*)d_in[9];
    const float* kn = (const float*)d_in[10];
    const float* gl = (const float*)d_in[11];
    const int* sp   = (const int*)d_in[13];
    float* out = (float*)d_out;

    char* ws = (char*)d_ws;
    const size_t NEED = 96481280;
    if (ws_size < NEED) return;
    short* xb    = (short*)(ws + 0);            // 16 MiB, reused as Qb
    short* wqkvT = (short*)(ws + 16777216);     // 12 MiB
    short* woT   = (short*)(ws + 29360128);     // 8 MiB
    float* bqkv  = (float*)(ws + 37748736);     // 12 KiB
    float* Y     = (float*)(ws + 37761024);     // 48 MiB, head reused as attnb
    short* Kb    = (short*)(ws + 88092672);     // 4 MiB
    short* Vtb   = (short*)(ws + 92286976);     // 4 MiB
    short* Qb    = xb;
    short* attnb = (short*)Y;

    f32_to_bf16_k<<<4096, 256, 0, stream>>>(x, xb, 1048576);
    transpose_f32_bf16_k<<<dim3(32, 32, 1), 256, 0, stream>>>(Wq, 0, 2048, wqkvT, 0, 2048);
    transpose_f32_bf16_k<<<dim3(8, 32, 1), 256, 0, stream>>>(Wk, 0, 512, wqkvT + (size_t)2048 * 2048, 0, 2048);
    transpose_f32_bf16_k<<<dim3(8, 32, 1), 256, 0, stream>>>(Wv, 0, 512, wqkvT + (size_t)2560 * 2048, 0, 2048);
    transpose_f32_bf16_k<<<dim3(32, 32, 1), 256, 0, stream>>>(Wo, 0, 2048, woT, 0, 2048);
    concat_bias_k<<<12, 256, 0, stream>>>(bq, bk, bv, bqkv);
    gemm256_k<<<dim3(24, 16), 512, 0, stream>>>(xb, wqkvT, bqkv, Y, 4096, 3072, 2048);
    qkv_post_k<<<4096, 256, 0, stream>>>(Y, qn, kn, sp, Qb, Kb);
    transpose_f32_bf16_k<<<dim3(8, 32, 2), 256, 0, stream>>>(
        Y + 2560, (size_t)2048 * 3072, 3072, Vtb, (size_t)512 * 2048, 2048);
    attn_fwd_k<<<dim3(8, 64), 256, 0, stream>>>(Qb, Kb, Vtb, gl, attnb);
    gemm256_k<<<dim3(16, 16), 512, 0, stream>>>(attnb, woT, bo, out, 4096, 2048, 2048);
}

// Round 8
// 253.637 us; speedup vs baseline: 1.1565x; 1.0796x over previous
//
#include <hip/hip_runtime.h>
#include <hip/hip_bf16.h>
#include <stdint.h>

#define DEV __device__ __forceinline__

typedef short     s16x8  __attribute__((ext_vector_type(8)));
typedef __bf16    bf16v8 __attribute__((ext_vector_type(8)));
typedef float     f32x4  __attribute__((ext_vector_type(4)));
typedef float     f32x16 __attribute__((ext_vector_type(16)));

// ---------- helpers ----------
DEV unsigned short f2bf(float x) {
    uint32_t u = __float_as_uint(x);
    uint32_t r = (u + 0x7FFFu + ((u >> 16) & 1u)) >> 16;
    return (unsigned short)r;
}

DEV void gload_lds16(const void* g, void* l) {
    __builtin_amdgcn_global_load_lds((const __attribute__((address_space(1))) void*)g,
                                     (__attribute__((address_space(3))) void*)l,
                                     16, 0, 0);
}

DEV f32x4 mfma16(s16x8 a, s16x8 b, f32x4 c) {
    return __builtin_amdgcn_mfma_f32_16x16x32_bf16(
        __builtin_bit_cast(bf16v8, a), __builtin_bit_cast(bf16v8, b), c, 0, 0, 0);
}
DEV f32x16 mfma32(s16x8 a, s16x8 b, f32x16 c) {
    return __builtin_amdgcn_mfma_f32_32x32x16_bf16(
        __builtin_bit_cast(bf16v8, a), __builtin_bit_cast(bf16v8, b), c, 0, 0, 0);
}

DEV uint32_t cvtpk_bf16(float lo, float hi) {
    uint32_t r;
    asm volatile("v_cvt_pk_bf16_f32 %0, %1, %2" : "=v"(r) : "v"(lo), "v"(hi));
    return r;
}

// raw barrier with compiler + scheduler fences (NO vmcnt/lgkm drain)
DEV void barx() {
    asm volatile("" ::: "memory");
    __builtin_amdgcn_s_barrier();
    __builtin_amdgcn_sched_barrier(0);
    asm volatile("" ::: "memory");
}

// ---------- elementwise f32 -> bf16 (8 elems / thread) ----------
__global__ void f32_to_bf16_k(const float* __restrict__ in, short* __restrict__ out, int n8) {
    int i = blockIdx.x * blockDim.x + threadIdx.x;
    if (i >= n8) return;
    const float4 a = *(const float4*)(in + (size_t)i * 8);
    const float4 b = *(const float4*)(in + (size_t)i * 8 + 4);
    uint4 w;
    w.x = (uint32_t)f2bf(a.x) | ((uint32_t)f2bf(a.y) << 16);
    w.y = (uint32_t)f2bf(a.z) | ((uint32_t)f2bf(a.w) << 16);
    w.z = (uint32_t)f2bf(b.x) | ((uint32_t)f2bf(b.y) << 16);
    w.w = (uint32_t)f2bf(b.z) | ((uint32_t)f2bf(b.w) << 16);
    *(uint4*)(out + (size_t)i * 8) = w;
}

// ---------- tiled transpose f32 (R x C) -> bf16 (C x R) ----------
__global__ __launch_bounds__(256) void transpose_f32_bf16_k(
    const float* __restrict__ in, size_t in_batch, int ld_in,
    short* __restrict__ out, size_t out_batch, int ld_out) {
    __shared__ float tile[64][65];
    const float* ip = in + (size_t)blockIdx.z * in_batch;
    short* op = out + (size_t)blockIdx.z * out_batch;
    const int c0 = blockIdx.x * 64, r0 = blockIdx.y * 64;
    const int t = threadIdx.x;
    const int cc4 = (t & 15) * 4;
    const int rr  = t >> 4;
#pragma unroll
    for (int p = 0; p < 4; ++p) {
        int r = rr + p * 16;
        float4 v = *(const float4*)(ip + (size_t)(r0 + r) * ld_in + c0 + cc4);
        tile[r][cc4 + 0] = v.x; tile[r][cc4 + 1] = v.y;
        tile[r][cc4 + 2] = v.z; tile[r][cc4 + 3] = v.w;
    }
    __syncthreads();
#pragma unroll
    for (int p = 0; p < 4; ++p) {
        int oc  = (t >> 4) + p * 16;
        int rr4 = (t & 15) * 4;
        ushort4 w;
        w.x = f2bf(tile[rr4 + 0][oc]);
        w.y = f2bf(tile[rr4 + 1][oc]);
        w.z = f2bf(tile[rr4 + 2][oc]);
        w.w = f2bf(tile[rr4 + 3][oc]);
        *(ushort4*)(op + (size_t)(c0 + oc) * ld_out + r0 + rr4) = w;
    }
}

// ---------- bias concat ----------
__global__ void concat_bias_k(const float* __restrict__ bq, const float* __restrict__ bk,
                              const float* __restrict__ bv, float* __restrict__ o) {
    int i = blockIdx.x * 256 + threadIdx.x;
    if (i < 2048)       o[i] = bq[i];
    else if (i < 2560)  o[i] = bk[i - 2048];
    else if (i < 3072)  o[i] = bv[i - 2560];
}

// ---------- GEMM v4: high-reuse 256x256 tile, 4-phase counted-vmcnt ----------
// C[M,N] = A[M,K](bf16) * Bt[N,K]^T + bias, f32 out.
// 8 waves (2M x 4N), wave-out 128x64 of 16x16x32 frags (8x4 grid, reuse 4/8).
// LDS: As[2][256x64], Bs[2][256x64] bf16 = 128 KB, [row][64] XOR-swizzled
// layout (proven zero-conflict in r6). Per K-tile: 4 phases, one C-quadrant
// (mh,nh) each: 12 ds_read_b128 + 2 x 8KB gload_lds (t+1 units) + 16 MFMA.
// Stage order A0,A2 | B0,B1 | B2,B3 | A1,A3. Hazard ledger:
//   end-ph1: vmcnt(4)+bar -> A1,A3 of THIS tile landed (needed ph2/ph3)
//   end-ph3: vmcnt(2)+bar -> A0,A2,B0..B3 of NEXT tile landed (needed ph0)
//   buf overwrite: t+2 writes to buf d issue after t's closing barrier.
__global__ __launch_bounds__(512, 2) void gemm256_k(
    const short* __restrict__ A, const short* __restrict__ Bt,
    const float* __restrict__ bias, float* __restrict__ C,
    int M, int N, int K) {
    __shared__ short As[2][16384];
    __shared__ short Bs[2][16384];
    const int tid = threadIdx.x;
    const int gx = gridDim.x;
    const int nwg = gx * gridDim.y;
    const int flat = blockIdx.y * gx + blockIdx.x;
    const int cpx = nwg >> 3;
    const int swz = (flat & 7) * cpx + (flat >> 3);
    const int m0 = (swz / gx) * 256, n0 = (swz % gx) * 256;
    const int lane = tid & 63, wid = tid >> 6;
    const int wm = wid >> 2, wn = wid & 3;       // wave-out rows wm*128, cols wn*64
    const int lr = lane & 15, lg = lane >> 4;

    // staging: unit = 64 rows x 64 k = 8KB = ONE gload_lds across 512 threads.
    // linear LDS slot chunk c holds logical chunk c^(row&7) (pre-swizzled src).
    const int srow = tid >> 3;                    // row within unit 0..63
    const int schunk = ((tid & 7) ^ (srow & 7)) << 3;
    const short* Ag = A  + (size_t)(m0 + srow) * K + schunk;
    const short* Bg = Bt + (size_t)(n0 + srow) * K + schunk;
    const int lwb = (tid & ~63) * 8;              // wave-uniform LDS base (shorts)

    f32x4 acc[8][4];
#pragma unroll
    for (int fr = 0; fr < 8; ++fr)
#pragma unroll
        for (int fc = 0; fc < 4; ++fc)
#pragma unroll
            for (int r = 0; r < 4; ++r) acc[fr][fc][r] = 0.f;

    const int nk = K >> 6;

#define SA(u, kt, dd) gload_lds16(Ag + (size_t)(u) * 64 * K + (kt) * 64, &As[dd][(u) * 4096 + lwb])
#define SB(u, kt, dd) gload_lds16(Bg + (size_t)(u) * 64 * K + (kt) * 64, &Bs[dd][(u) * 4096 + lwb])

    // prologue: tile 0 fully staged
    SA(0, 0, 0); SA(1, 0, 0); SA(2, 0, 0); SA(3, 0, 0);
    SB(0, 0, 0); SB(1, 0, 0); SB(2, 0, 0); SB(3, 0, 0);
    asm volatile("s_waitcnt vmcnt(0)" ::: "memory");
    barx();

#define PHASE(mh, nh, STG, WAIT)                                               \
    {                                                                          \
        s16x8 af[2][4], bfv[2][2];                                             \
        _Pragma("unroll")                                                      \
        for (int ks = 0; ks < 2; ++ks) {                                       \
            const int csw = ((ks * 4 + lg) ^ (lr & 7)) * 8;                    \
            _Pragma("unroll")                                                  \
            for (int i = 0; i < 4; ++i) {                                      \
                const int row = wm * 128 + (mh) * 64 + i * 16 + lr;            \
                af[ks][i] = *(const s16x8*)&As[d][row * 64 + csw];             \
            }                                                                  \
            _Pragma("unroll")                                                  \
            for (int j = 0; j < 2; ++j) {                                      \
                const int row = wn * 64 + (nh) * 32 + j * 16 + lr;             \
                bfv[ks][j] = *(const s16x8*)&Bs[d][row * 64 + csw];            \
            }                                                                  \
        }                                                                      \
        if (more) { STG; }                                                     \
        __builtin_amdgcn_s_setprio(1);                                         \
        _Pragma("unroll")                                                      \
        for (int ks = 0; ks < 2; ++ks)                                        \
            _Pragma("unroll")                                                  \
            for (int i = 0; i < 4; ++i)                                        \
                _Pragma("unroll")                                              \
                for (int j = 0; j < 2; ++j)                                    \
                    acc[(mh) * 4 + i][(nh) * 2 + j] =                          \
                        mfma16(af[ks][i], bfv[ks][j],                          \
                               acc[(mh) * 4 + i][(nh) * 2 + j]);               \
        __builtin_amdgcn_s_setprio(0);                                         \
        WAIT;                                                                  \
        barx();                                                                \
    }

    for (int t = 0; t < nk; ++t) {
        const int d = t & 1, e = d ^ 1;
        const bool more = (t + 1 < nk);
        PHASE(0, 0, (SA(0, t + 1, e), SA(2, t + 1, e)), );
        PHASE(0, 1, (SB(0, t + 1, e), SB(1, t + 1, e)),
              if (more) { asm volatile("s_waitcnt vmcnt(4)" ::: "memory"); }
              else      { asm volatile("s_waitcnt vmcnt(0)" ::: "memory"); });
        PHASE(1, 0, (SB(2, t + 1, e), SB(3, t + 1, e)), );
        PHASE(1, 1, (SA(1, t + 1, e), SA(3, t + 1, e)),
              if (more) { asm volatile("s_waitcnt vmcnt(2)" ::: "memory"); });
    }
#undef PHASE
#undef SA
#undef SB

    // epilogue
#pragma unroll
    for (int fr = 0; fr < 8; ++fr) {
        const int row = m0 + wm * 128 + fr * 16 + lg * 4;
#pragma unroll
        for (int fc = 0; fc < 4; ++fc) {
            const int col = n0 + wn * 64 + fc * 16 + lr;
            const float bbv = bias[col];
#pragma unroll
            for (int r = 0; r < 4; ++r)
                C[(size_t)(row + r) * N + col] = acc[fr][fc][r] + bbv;
        }
    }
}

// ---------- rmsnorm + rope + head layout for Q,K ----------
__global__ __launch_bounds__(256) void qkv_post_k(
    const float* __restrict__ Y, const float* __restrict__ qn_w,
    const float* __restrict__ kn_w, const int* __restrict__ start_pos,
    short* __restrict__ Qb, short* __restrict__ Kb) {
    const int m = blockIdx.x;
    const int b = m >> 11, s = m & 2047;
    const float* y = Y + (size_t)m * 3072;
    const int tid = threadIdx.x;

    const float4 q1 = *(const float4*)(y + tid * 8);
    const float4 q2 = *(const float4*)(y + tid * 8 + 4);
    const float2 kv = *(const float2*)(y + 2048 + tid * 2);
    float ssq = q1.x * q1.x + q1.y * q1.y + q1.z * q1.z + q1.w * q1.w
              + q2.x * q2.x + q2.y * q2.y + q2.z * q2.z + q2.w * q2.w;
    float ssk = kv.x * kv.x + kv.y * kv.y;
#pragma unroll
    for (int off = 1; off < 64; off <<= 1) {
        ssq += __shfl_xor(ssq, off);
        ssk += __shfl_xor(ssk, off);
    }
    __shared__ float red[8];
    if ((tid & 63) == 0) { red[tid >> 6] = ssq; red[4 + (tid >> 6)] = ssk; }
    __syncthreads();
    const float tq = red[0] + red[1] + red[2] + red[3];
    const float tk = red[4] + red[5] + red[6] + red[7];
    const float rq = rsqrtf(tq * (1.f / 2048.f) + 1.1920929e-07f);
    const float rk = rsqrtf(tk * (1.f / 512.f) + 1.1920929e-07f);
    const int pos = start_pos[0] + s;

    float qn[8];
    qn[0] = q1.x; qn[1] = q1.y; qn[2] = q1.z; qn[3] = q1.w;
    qn[4] = q2.x; qn[5] = q2.y; qn[6] = q2.z; qn[7] = q2.w;
#pragma unroll
    for (int j = 0; j < 8; ++j) qn[j] *= rq * qn_w[tid * 8 + j];
    const int hq = tid >> 4;
    const int din = (tid * 8) & 127;
    unsigned short ob[8];
#pragma unroll
    for (int j = 0; j < 4; ++j) {
        int tt = (din >> 1) + j;
        float inv = __builtin_exp2f(-0.20762050f * (float)tt);
        float ang = (float)pos * inv;
        float sn, cn;
        __sincosf(ang, &sn, &cn);
        float x1 = qn[2 * j], x2 = qn[2 * j + 1];
        ob[2 * j]     = f2bf(x1 * cn - x2 * sn);
        ob[2 * j + 1] = f2bf(x1 * sn + x2 * cn);
    }
    short* qdst = Qb + (((size_t)(b * 16 + hq) * 2048 + s) * 128 + din);
    uint4 w;
    w.x = (uint32_t)ob[0] | ((uint32_t)ob[1] << 16);
    w.y = (uint32_t)ob[2] | ((uint32_t)ob[3] << 16);
    w.z = (uint32_t)ob[4] | ((uint32_t)ob[5] << 16);
    w.w = (uint32_t)ob[6] | ((uint32_t)ob[7] << 16);
    *(uint4*)qdst = w;

    const int colk = tid * 2;
    const int hk = colk >> 7, dk = colk & 127;
    float k1 = kv.x * rk * kn_w[colk], k2 = kv.y * rk * kn_w[colk + 1];
    {
        int tt = dk >> 1;
        float inv = __builtin_exp2f(-0.20762050f * (float)tt);
        float ang = (float)pos * inv;
        float sn, cn;
        __sincosf(ang, &sn, &cn);
        float r1 = k1 * cn - k2 * sn, r2 = k1 * sn + k2 * cn;
        short* kdst = Kb + (((size_t)(b * 4 + hk) * 2048 + s) * 128 + dk);
        *(uint32_t*)kdst = (uint32_t)f2bf(r1) | ((uint32_t)f2bf(r2) << 16);
    }
}

// ---------- flash attention: LPT dispatch + setprio ----------
__global__ __launch_bounds__(256, 2) void attn_fwd_k(
    const short* __restrict__ Qb, const short* __restrict__ Kb,
    const short* __restrict__ Vtb, const float* __restrict__ gate_logits,
    short* __restrict__ attnb) {
    const int S = 2048;
    __shared__ short Ks[2][64 * 128];
    __shared__ short Vs[2][128 * 64];
    const int tid = threadIdx.x, lane = tid & 63;
    const int wid = tid >> 6;
    const int qt = 63 - (int)blockIdx.y;      // LPT: longest first
    const int bhk = blockIdx.x;
    const int b = bhk >> 2, hk = bhk & 3;
    const int h = hk * 4 + wid;
    const int q0 = qt * 32;
    const int ql = lane & 31, hi = lane >> 5;
    const int qg = q0 + ql;

    s16x8 qf[8];
    {
        const short* qrow = Qb + (((size_t)(b * 16 + h) * S + qg) * 128 + hi * 8);
#pragma unroll
        for (int kc = 0; kc < 8; ++kc) qf[kc] = *(const s16x8*)(qrow + kc * 16);
    }
    f32x16 ov[4];
#pragma unroll
    for (int dc = 0; dc < 4; ++dc)
#pragma unroll
        for (int r = 0; r < 16; ++r) ov[dc][r] = 0.f;
    float mrun = -3.0e38f, lrun = 0.f;
    const float cs = 0.12751745f;
    const float THR = 90.509668f;

    const short* kg[4]; const short* vg[4]; int lb[4];
#pragma unroll
    for (int i = 0; i < 4; ++i) {
        int oo = (i * 256 + tid) * 8;
        lb[i] = (i * 256 + (tid & ~63)) * 8;
        {
            int row = oo >> 7, col = oo & 127, ch = col >> 3;
            kg[i] = Kb + ((size_t)bhk * S + row) * 128 + ((ch ^ (row & 7)) << 3);
        }
        {
            int row = oo >> 6, col = oo & 63, ch = col >> 3;
            vg[i] = Vtb + ((size_t)bhk * 128 + row) * S + ((ch ^ (row & 7)) << 3);
        }
    }
    const int ntiles = ((q0 + 31) >> 6) + 1;
#pragma unroll
    for (int i = 0; i < 4; ++i) gload_lds16(kg[i], &Ks[0][lb[i]]);
#pragma unroll
    for (int i = 0; i < 4; ++i) gload_lds16(vg[i], &Vs[0][lb[i]]);
    asm volatile("s_waitcnt vmcnt(0)");
    __syncthreads();

    int cur = 0;
    for (int jt = 0; jt < ntiles; ++jt) {
        const int j0 = jt * 64;
        if (jt + 1 < ntiles) {
            const int jn = j0 + 64;
#pragma unroll
            for (int i = 0; i < 4; ++i) gload_lds16(kg[i] + (size_t)jn * 128, &Ks[cur ^ 1][lb[i]]);
#pragma unroll
            for (int i = 0; i < 4; ++i) gload_lds16(vg[i] + jn, &Vs[cur ^ 1][lb[i]]);
        }
#pragma unroll
        for (int t = 0; t < 2; ++t) {
            const int jb = j0 + t * 32;
            if (jb > q0 + 31) continue;
            const bool fsub = (jb + 31 <= q0);
            f32x16 sacc;
#pragma unroll
            for (int r = 0; r < 16; ++r) sacc[r] = 0.f;
            const int krl = t * 32 + ql;
            __builtin_amdgcn_s_setprio(1);
#pragma unroll
            for (int kc = 0; kc < 8; ++kc) {
                int ch = kc * 2 + hi;
                s16x8 kf = *(const s16x8*)&Ks[cur][krl * 128 + ((ch ^ (krl & 7)) << 3)];
                sacc = mfma32(kf, qf[kc], sacc);
            }
            __builtin_amdgcn_s_setprio(0);
            float p[16];
            if (fsub) {
#pragma unroll
                for (int r = 0; r < 16; ++r) p[r] = sacc[r];
            } else {
#pragma unroll
                for (int r = 0; r < 16; ++r) {
                    int kvg = jb + ((r & 3) + 8 * (r >> 2) + 4 * hi);
                    p[r] = (kvg <= qg) ? sacc[r] : -3.0e38f;
                }
            }
            float m0a = fmaxf(p[0], p[1]),  m1a = fmaxf(p[2], p[3]);
            float m2a = fmaxf(p[4], p[5]),  m3a = fmaxf(p[6], p[7]);
            float m4a = fmaxf(p[8], p[9]),  m5a = fmaxf(p[10], p[11]);
            float m6a = fmaxf(p[12], p[13]), m7a = fmaxf(p[14], p[15]);
            float mb0 = fmaxf(m0a, m1a), mb1 = fmaxf(m2a, m3a);
            float mb2 = fmaxf(m4a, m5a), mb3 = fmaxf(m6a, m7a);
            float pmax = fmaxf(fmaxf(mb0, mb1), fmaxf(mb2, mb3));
            pmax = fmaxf(pmax, __shfl_xor(pmax, 32));
            if (__any(pmax - mrun > THR)) {
                float mnew = fmaxf(mrun, pmax);
                float alpha = __builtin_exp2f((mrun - mnew) * cs);
                lrun *= alpha;
#pragma unroll
                for (int r = 0; r < 16; ++r) {
                    int cr = (r & 3) + 8 * (r >> 2) + 4 * hi;
                    float ar = __uint_as_float(
                        (uint32_t)__builtin_amdgcn_ds_bpermute(cr << 2, (int)__float_as_uint(alpha)));
                    ov[0][r] *= ar; ov[1][r] *= ar; ov[2][r] *= ar; ov[3][r] *= ar;
                }
                mrun = mnew;
            }
#pragma unroll
            for (int r = 0; r < 16; ++r) p[r] = __builtin_exp2f((p[r] - mrun) * cs);
            float s0a = p[0] + p[1],  s1a = p[2] + p[3];
            float s2a = p[4] + p[5],  s3a = p[6] + p[7];
            float s4a = p[8] + p[9],  s5a = p[10] + p[11];
            float s6a = p[12] + p[13], s7a = p[14] + p[15];
            float ps = ((s0a + s1a) + (s2a + s3a)) + ((s4a + s5a) + (s6a + s7a));
            ps += __shfl_xor(ps, 32);
            lrun += ps;
            uint32_t w0 = cvtpk_bf16(p[0], p[1]),   w1 = cvtpk_bf16(p[2], p[3]);
            uint32_t w2 = cvtpk_bf16(p[4], p[5]),   w3 = cvtpk_bf16(p[6], p[7]);
            uint32_t w4 = cvtpk_bf16(p[8], p[9]),   w5 = cvtpk_bf16(p[10], p[11]);
            uint32_t w6 = cvtpk_bf16(p[12], p[13]), w7 = cvtpk_bf16(p[14], p[15]);
            uint32_t w0s = (uint32_t)__shfl_xor((int)w0, 32);
            uint32_t w1s = (uint32_t)__shfl_xor((int)w1, 32);
            uint32_t w2s = (uint32_t)__shfl_xor((int)w2, 32);
            uint32_t w3s = (uint32_t)__shfl_xor((int)w3, 32);
            uint32_t w4s = (uint32_t)__shfl_xor((int)w4, 32);
            uint32_t w5s = (uint32_t)__shfl_xor((int)w5, 32);
            uint32_t w6s = (uint32_t)__shfl_xor((int)w6, 32);
            uint32_t w7s = (uint32_t)__shfl_xor((int)w7, 32);
            union { uint32_t u[4]; s16x8 v; } pa0, pa1;
            pa0.u[0] = hi ? w2s : w0;  pa0.u[1] = hi ? w3s : w1;
            pa0.u[2] = hi ? w2  : w0s; pa0.u[3] = hi ? w3  : w1s;
            pa1.u[0] = hi ? w6s : w4;  pa1.u[1] = hi ? w7s : w5;
            pa1.u[2] = hi ? w6  : w4s; pa1.u[3] = hi ? w7  : w5s;
            __builtin_amdgcn_s_setprio(1);
#pragma unroll
            for (int dc = 0; dc < 4; ++dc) {
                int dd = dc * 32 + ql;
                int c0i = t * 4 + hi;
                s16x8 vf0 = *(const s16x8*)&Vs[cur][dd * 64 + ((c0i ^ (dd & 7)) << 3)];
                ov[dc] = mfma32(pa0.v, vf0, ov[dc]);
                int c1i = t * 4 + 2 + hi;
                s16x8 vf1 = *(const s16x8*)&Vs[cur][dd * 64 + ((c1i ^ (dd & 7)) << 3)];
                ov[dc] = mfma32(pa1.v, vf1, ov[dc]);
            }
            __builtin_amdgcn_s_setprio(0);
        }
        asm volatile("s_waitcnt vmcnt(0)");
        __syncthreads();
        cur ^= 1;
    }
    const float gl = gate_logits[h];
    const float gate = 1.f / (1.f + __expf(-gl));
    const float linv = gate / lrun;
#pragma unroll
    for (int r = 0; r < 16; ++r) {
        int cr = (r & 3) + 8 * (r >> 2) + 4 * hi;
        float sc = __uint_as_float(
            (uint32_t)__builtin_amdgcn_ds_bpermute(cr << 2, (int)__float_as_uint(linv)));
        int qrow = q0 + cr;
        short* orow = attnb + ((size_t)(b * S) + qrow) * 2048 + h * 128 + ql;
#pragma unroll
        for (int dc = 0; dc < 4; ++dc)
            orow[dc * 32] = (short)f2bf(ov[dc][r] * sc);
    }
}

// ---------- launch ----------
extern "C" void kernel_launch(void* const* d_in, const int* in_sizes, int n_in,
                              void* d_out, int out_size, void* d_ws, size_t ws_size,
                              hipStream_t stream) {
    const float* x  = (const float*)d_in[0];
    const float* Wq = (const float*)d_in[1];
    const float* bq = (const float*)d_in[2];
    const float* Wk = (const float*)d_in[3];
    const float* bk = (const float*)d_in[4];
    const float* Wv = (const float*)d_in[5];
    const float* bv = (const float*)d_in[6];
    const float* Wo = (const float*)d_in[7];
    const float* bo = (const float*)d_in[8];
    const float* qn = (const float*)d_in[9];
    const float* kn = (const float*)d_in[10];
    const float* gl = (const float*)d_in[11];
    const int* sp   = (const int*)d_in[13];
    float* out = (float*)d_out;

    char* ws = (char*)d_ws;
    const size_t NEED = 96481280;
    if (ws_size < NEED) return;
    short* xb    = (short*)(ws + 0);            // 16 MiB, reused as Qb
    short* wqkvT = (short*)(ws + 16777216);     // 12 MiB
    short* woT   = (short*)(ws + 29360128);     // 8 MiB
    float* bqkv  = (float*)(ws + 37748736);     // 12 KiB
    float* Y     = (float*)(ws + 37761024);     // 48 MiB, head reused as attnb
    short* Kb    = (short*)(ws + 88092672);     // 4 MiB
    short* Vtb   = (short*)(ws + 92286976);     // 4 MiB
    short* Qb    = xb;
    short* attnb = (short*)Y;

    f32_to_bf16_k<<<4096, 256, 0, stream>>>(x, xb, 1048576);
    transpose_f32_bf16_k<<<dim3(32, 32, 1), 256, 0, stream>>>(Wq, 0, 2048, wqkvT, 0, 2048);
    transpose_f32_bf16_k<<<dim3(8, 32, 1), 256, 0, stream>>>(Wk, 0, 512, wqkvT + (size_t)2048 * 2048, 0, 2048);
    transpose_f32_bf16_k<<<dim3(8, 32, 1), 256, 0, stream>>>(Wv, 0, 512, wqkvT + (size_t)2560 * 2048, 0, 2048);
    transpose_f32_bf16_k<<<dim3(32, 32, 1), 256, 0, stream>>>(Wo, 0, 2048, woT, 0, 2048);
    concat_bias_k<<<12, 256, 0, stream>>>(bq, bk, bv, bqkv);
    gemm256_k<<<dim3(12, 16), 512, 0, stream>>>(xb, wqkvT, bqkv, Y, 4096, 3072, 2048);
    qkv_post_k<<<4096, 256, 0, stream>>>(Y, qn, kn, sp, Qb, Kb);
    transpose_f32_bf16_k<<<dim3(8, 32, 2), 256, 0, stream>>>(
        Y + 2560, (size_t)2048 * 3072, 3072, Vtb, (size_t)512 * 2048, 2048);
    attn_fwd_k<<<dim3(8, 64), 256, 0, stream>>>(Qb, Kb, Vtb, gl, attnb);
    gemm256_k<<<dim3(8, 16), 512, 0, stream>>>(attnb, woT, bo, out, 4096, 2048, 2048);
}

// Round 9
// 250.985 us; speedup vs baseline: 1.1687x; 1.0106x over previous
//
#include <hip/hip_runtime.h>
#include <hip/hip_bf16.h>
#include <stdint.h>

#define DEV __device__ __forceinline__

typedef short     s16x8  __attribute__((ext_vector_type(8)));
typedef __bf16    bf16v8 __attribute__((ext_vector_type(8)));
typedef float     f32x4  __attribute__((ext_vector_type(4)));
typedef float     f32x16 __attribute__((ext_vector_type(16)));

// ---------- helpers ----------
DEV unsigned short f2bf(float x) {
    uint32_t u = __float_as_uint(x);
    uint32_t r = (u + 0x7FFFu + ((u >> 16) & 1u)) >> 16;
    return (unsigned short)r;
}

DEV void gload_lds16(const void* g, void* l) {
    __builtin_amdgcn_global_load_lds((const __attribute__((address_space(1))) void*)g,
                                     (__attribute__((address_space(3))) void*)l,
                                     16, 0, 0);
}

DEV f32x4 mfma16(s16x8 a, s16x8 b, f32x4 c) {
    return __builtin_amdgcn_mfma_f32_16x16x32_bf16(
        __builtin_bit_cast(bf16v8, a), __builtin_bit_cast(bf16v8, b), c, 0, 0, 0);
}
DEV f32x16 mfma32(s16x8 a, s16x8 b, f32x16 c) {
    return __builtin_amdgcn_mfma_f32_32x32x16_bf16(
        __builtin_bit_cast(bf16v8, a), __builtin_bit_cast(bf16v8, b), c, 0, 0, 0);
}

DEV uint32_t cvtpk_bf16(float lo, float hi) {
    uint32_t r;
    asm volatile("v_cvt_pk_bf16_f32 %0, %1, %2" : "=v"(r) : "v"(lo), "v"(hi));
    return r;
}

// raw barrier with compiler + scheduler fences (NO vmcnt/lgkm drain)
DEV void barx() {
    asm volatile("" ::: "memory");
    __builtin_amdgcn_s_barrier();
    __builtin_amdgcn_sched_barrier(0);
    asm volatile("" ::: "memory");
}

// ---------- elementwise f32 -> bf16 (8 elems / thread) ----------
__global__ void f32_to_bf16_k(const float* __restrict__ in, short* __restrict__ out, int n8) {
    int i = blockIdx.x * blockDim.x + threadIdx.x;
    if (i >= n8) return;
    const float4 a = *(const float4*)(in + (size_t)i * 8);
    const float4 b = *(const float4*)(in + (size_t)i * 8 + 4);
    uint4 w;
    w.x = (uint32_t)f2bf(a.x) | ((uint32_t)f2bf(a.y) << 16);
    w.y = (uint32_t)f2bf(a.z) | ((uint32_t)f2bf(a.w) << 16);
    w.z = (uint32_t)f2bf(b.x) | ((uint32_t)f2bf(b.y) << 16);
    w.w = (uint32_t)f2bf(b.z) | ((uint32_t)f2bf(b.w) << 16);
    *(uint4*)(out + (size_t)i * 8) = w;
}

// ---------- tiled transpose f32 (R x C) -> bf16 (C x R) ----------
__global__ __launch_bounds__(256) void transpose_f32_bf16_k(
    const float* __restrict__ in, size_t in_batch, int ld_in,
    short* __restrict__ out, size_t out_batch, int ld_out) {
    __shared__ float tile[64][65];
    const float* ip = in + (size_t)blockIdx.z * in_batch;
    short* op = out + (size_t)blockIdx.z * out_batch;
    const int c0 = blockIdx.x * 64, r0 = blockIdx.y * 64;
    const int t = threadIdx.x;
    const int cc4 = (t & 15) * 4;
    const int rr  = t >> 4;
#pragma unroll
    for (int p = 0; p < 4; ++p) {
        int r = rr + p * 16;
        float4 v = *(const float4*)(ip + (size_t)(r0 + r) * ld_in + c0 + cc4);
        tile[r][cc4 + 0] = v.x; tile[r][cc4 + 1] = v.y;
        tile[r][cc4 + 2] = v.z; tile[r][cc4 + 3] = v.w;
    }
    __syncthreads();
#pragma unroll
    for (int p = 0; p < 4; ++p) {
        int oc  = (t >> 4) + p * 16;
        int rr4 = (t & 15) * 4;
        ushort4 w;
        w.x = f2bf(tile[rr4 + 0][oc]);
        w.y = f2bf(tile[rr4 + 1][oc]);
        w.z = f2bf(tile[rr4 + 2][oc]);
        w.w = f2bf(tile[rr4 + 3][oc]);
        *(ushort4*)(op + (size_t)(c0 + oc) * ld_out + r0 + rr4) = w;
    }
}

// ---------- bias concat ----------
__global__ void concat_bias_k(const float* __restrict__ bq, const float* __restrict__ bk,
                              const float* __restrict__ bv, float* __restrict__ o) {
    int i = blockIdx.x * 256 + threadIdx.x;
    if (i < 2048)       o[i] = bq[i];
    else if (i < 2560)  o[i] = bk[i - 2048];
    else if (i < 3072)  o[i] = bv[i - 2560];
}

// ---------- GEMM v4: high-reuse 256x256 tile, 4-phase counted-vmcnt ----------
__global__ __launch_bounds__(512, 2) void gemm256_k(
    const short* __restrict__ A, const short* __restrict__ Bt,
    const float* __restrict__ bias, float* __restrict__ C,
    int M, int N, int K) {
    __shared__ short As[2][16384];
    __shared__ short Bs[2][16384];
    const int tid = threadIdx.x;
    const int gx = gridDim.x;
    const int nwg = gx * gridDim.y;
    const int flat = blockIdx.y * gx + blockIdx.x;
    const int cpx = nwg >> 3;
    const int swz = (flat & 7) * cpx + (flat >> 3);
    const int m0 = (swz / gx) * 256, n0 = (swz % gx) * 256;
    const int lane = tid & 63, wid = tid >> 6;
    const int wm = wid >> 2, wn = wid & 3;
    const int lr = lane & 15, lg = lane >> 4;

    const int srow = tid >> 3;
    const int schunk = ((tid & 7) ^ (srow & 7)) << 3;
    const short* Ag = A  + (size_t)(m0 + srow) * K + schunk;
    const short* Bg = Bt + (size_t)(n0 + srow) * K + schunk;
    const int lwb = (tid & ~63) * 8;

    f32x4 acc[8][4];
#pragma unroll
    for (int fr = 0; fr < 8; ++fr)
#pragma unroll
        for (int fc = 0; fc < 4; ++fc)
#pragma unroll
            for (int r = 0; r < 4; ++r) acc[fr][fc][r] = 0.f;

    const int nk = K >> 6;

#define SA(u, kt, dd) gload_lds16(Ag + (size_t)(u) * 64 * K + (kt) * 64, &As[dd][(u) * 4096 + lwb])
#define SB(u, kt, dd) gload_lds16(Bg + (size_t)(u) * 64 * K + (kt) * 64, &Bs[dd][(u) * 4096 + lwb])

    SA(0, 0, 0); SA(1, 0, 0); SA(2, 0, 0); SA(3, 0, 0);
    SB(0, 0, 0); SB(1, 0, 0); SB(2, 0, 0); SB(3, 0, 0);
    asm volatile("s_waitcnt vmcnt(0)" ::: "memory");
    barx();

#define PHASE(mh, nh, STG, WAIT)                                               \
    {                                                                          \
        s16x8 af[2][4], bfv[2][2];                                             \
        _Pragma("unroll")                                                      \
        for (int ks = 0; ks < 2; ++ks) {                                       \
            const int csw = ((ks * 4 + lg) ^ (lr & 7)) * 8;                    \
            _Pragma("unroll")                                                  \
            for (int i = 0; i < 4; ++i) {                                      \
                const int row = wm * 128 + (mh) * 64 + i * 16 + lr;            \
                af[ks][i] = *(const s16x8*)&As[d][row * 64 + csw];             \
            }                                                                  \
            _Pragma("unroll")                                                  \
            for (int j = 0; j < 2; ++j) {                                      \
                const int row = wn * 64 + (nh) * 32 + j * 16 + lr;             \
                bfv[ks][j] = *(const s16x8*)&Bs[d][row * 64 + csw];            \
            }                                                                  \
        }                                                                      \
        if (more) { STG; }                                                     \
        __builtin_amdgcn_s_setprio(1);                                         \
        _Pragma("unroll")                                                      \
        for (int ks = 0; ks < 2; ++ks)                                        \
            _Pragma("unroll")                                                  \
            for (int i = 0; i < 4; ++i)                                        \
                _Pragma("unroll")                                              \
                for (int j = 0; j < 2; ++j)                                    \
                    acc[(mh) * 4 + i][(nh) * 2 + j] =                          \
                        mfma16(af[ks][i], bfv[ks][j],                          \
                               acc[(mh) * 4 + i][(nh) * 2 + j]);               \
        __builtin_amdgcn_s_setprio(0);                                         \
        WAIT;                                                                  \
        barx();                                                                \
    }

    for (int t = 0; t < nk; ++t) {
        const int d = t & 1, e = d ^ 1;
        const bool more = (t + 1 < nk);
        PHASE(0, 0, (SA(0, t + 1, e), SA(2, t + 1, e)), );
        PHASE(0, 1, (SB(0, t + 1, e), SB(1, t + 1, e)),
              if (more) { asm volatile("s_waitcnt vmcnt(4)" ::: "memory"); }
              else      { asm volatile("s_waitcnt vmcnt(0)" ::: "memory"); });
        PHASE(1, 0, (SB(2, t + 1, e), SB(3, t + 1, e)), );
        PHASE(1, 1, (SA(1, t + 1, e), SA(3, t + 1, e)),
              if (more) { asm volatile("s_waitcnt vmcnt(2)" ::: "memory"); });
    }
#undef PHASE
#undef SA
#undef SB

#pragma unroll
    for (int fr = 0; fr < 8; ++fr) {
        const int row = m0 + wm * 128 + fr * 16 + lg * 4;
#pragma unroll
        for (int fc = 0; fc < 4; ++fc) {
            const int col = n0 + wn * 64 + fc * 16 + lr;
            const float bbv = bias[col];
#pragma unroll
            for (int r = 0; r < 4; ++r)
                C[(size_t)(row + r) * N + col] = acc[fr][fc][r] + bbv;
        }
    }
}

// ---------- rmsnorm + rope + head layout for Q,K ----------
__global__ __launch_bounds__(256) void qkv_post_k(
    const float* __restrict__ Y, const float* __restrict__ qn_w,
    const float* __restrict__ kn_w, const int* __restrict__ start_pos,
    short* __restrict__ Qb, short* __restrict__ Kb) {
    const int m = blockIdx.x;
    const int b = m >> 11, s = m & 2047;
    const float* y = Y + (size_t)m * 3072;
    const int tid = threadIdx.x;

    const float4 q1 = *(const float4*)(y + tid * 8);
    const float4 q2 = *(const float4*)(y + tid * 8 + 4);
    const float2 kv = *(const float2*)(y + 2048 + tid * 2);
    float ssq = q1.x * q1.x + q1.y * q1.y + q1.z * q1.z + q1.w * q1.w
              + q2.x * q2.x + q2.y * q2.y + q2.z * q2.z + q2.w * q2.w;
    float ssk = kv.x * kv.x + kv.y * kv.y;
#pragma unroll
    for (int off = 1; off < 64; off <<= 1) {
        ssq += __shfl_xor(ssq, off);
        ssk += __shfl_xor(ssk, off);
    }
    __shared__ float red[8];
    if ((tid & 63) == 0) { red[tid >> 6] = ssq; red[4 + (tid >> 6)] = ssk; }
    __syncthreads();
    const float tq = red[0] + red[1] + red[2] + red[3];
    const float tk = red[4] + red[5] + red[6] + red[7];
    const float rq = rsqrtf(tq * (1.f / 2048.f) + 1.1920929e-07f);
    const float rk = rsqrtf(tk * (1.f / 512.f) + 1.1920929e-07f);
    const int pos = start_pos[0] + s;

    float qn[8];
    qn[0] = q1.x; qn[1] = q1.y; qn[2] = q1.z; qn[3] = q1.w;
    qn[4] = q2.x; qn[5] = q2.y; qn[6] = q2.z; qn[7] = q2.w;
#pragma unroll
    for (int j = 0; j < 8; ++j) qn[j] *= rq * qn_w[tid * 8 + j];
    const int hq = tid >> 4;
    const int din = (tid * 8) & 127;
    unsigned short ob[8];
#pragma unroll
    for (int j = 0; j < 4; ++j) {
        int tt = (din >> 1) + j;
        float inv = __builtin_exp2f(-0.20762050f * (float)tt);
        float ang = (float)pos * inv;
        float sn, cn;
        __sincosf(ang, &sn, &cn);
        float x1 = qn[2 * j], x2 = qn[2 * j + 1];
        ob[2 * j]     = f2bf(x1 * cn - x2 * sn);
        ob[2 * j + 1] = f2bf(x1 * sn + x2 * cn);
    }
    short* qdst = Qb + (((size_t)(b * 16 + hq) * 2048 + s) * 128 + din);
    uint4 w;
    w.x = (uint32_t)ob[0] | ((uint32_t)ob[1] << 16);
    w.y = (uint32_t)ob[2] | ((uint32_t)ob[3] << 16);
    w.z = (uint32_t)ob[4] | ((uint32_t)ob[5] << 16);
    w.w = (uint32_t)ob[6] | ((uint32_t)ob[7] << 16);
    *(uint4*)qdst = w;

    const int colk = tid * 2;
    const int hk = colk >> 7, dk = colk & 127;
    float k1 = kv.x * rk * kn_w[colk], k2 = kv.y * rk * kn_w[colk + 1];
    {
        int tt = dk >> 1;
        float inv = __builtin_exp2f(-0.20762050f * (float)tt);
        float ang = (float)pos * inv;
        float sn, cn;
        __sincosf(ang, &sn, &cn);
        float r1 = k1 * cn - k2 * sn, r2 = k1 * sn + k2 * cn;
        short* kdst = Kb + (((size_t)(b * 4 + hk) * 2048 + s) * 128 + dk);
        *(uint32_t*)kdst = (uint32_t)f2bf(r1) | ((uint32_t)f2bf(r2) << 16);
    }
}

// ---------- flash attention v5: balanced CU pairing + merged 64-kv subtile ----
// grid (8 bhk, 64 y). qt = y<32 ? 63-y : y-32 -> with 2 resident blocks/CU
// (block c pairs with c+256), each CU gets qt pair (63-y', y') = constant
// 65 subtiles (was 96..34 -> makespan-bound). Per 64-kv tile: both 32-halves'
// QK chains (independent sacc -> MFMA ILP), ONE softmax reduction over p[32],
// then 16 PV MFMAs.
__global__ __launch_bounds__(256, 2) void attn_fwd_k(
    const short* __restrict__ Qb, const short* __restrict__ Kb,
    const short* __restrict__ Vtb, const float* __restrict__ gate_logits,
    short* __restrict__ attnb) {
    const int S = 2048;
    __shared__ short Ks[2][64 * 128];
    __shared__ short Vs[2][128 * 64];
    const int tid = threadIdx.x, lane = tid & 63;
    const int wid = tid >> 6;
    const int y = blockIdx.y;
    const int qt = (y < 32) ? (63 - y) : (y - 32);   // balanced pairing
    const int bhk = blockIdx.x;
    const int b = bhk >> 2, hk = bhk & 3;
    const int h = hk * 4 + wid;
    const int q0 = qt * 32;
    const int ql = lane & 31, hi = lane >> 5;
    const int qg = q0 + ql;

    s16x8 qf[8];
    {
        const short* qrow = Qb + (((size_t)(b * 16 + h) * S + qg) * 128 + hi * 8);
#pragma unroll
        for (int kc = 0; kc < 8; ++kc) qf[kc] = *(const s16x8*)(qrow + kc * 16);
    }
    f32x16 ov[4];
#pragma unroll
    for (int dc = 0; dc < 4; ++dc)
#pragma unroll
        for (int r = 0; r < 16; ++r) ov[dc][r] = 0.f;
    float mrun = -3.0e38f, lrun = 0.f;
    const float cs = 0.12751745f;     // (1/sqrt(128)) * log2(e)
    const float THR = 90.509668f;     // 8*sqrt(128)

    const short* kg[4]; const short* vg[4]; int lb[4];
#pragma unroll
    for (int i = 0; i < 4; ++i) {
        int oo = (i * 256 + tid) * 8;
        lb[i] = (i * 256 + (tid & ~63)) * 8;
        {
            int row = oo >> 7, col = oo & 127, ch = col >> 3;
            kg[i] = Kb + ((size_t)bhk * S + row) * 128 + ((ch ^ (row & 7)) << 3);
        }
        {
            int row = oo >> 6, col = oo & 63, ch = col >> 3;
            vg[i] = Vtb + ((size_t)bhk * 128 + row) * S + ((ch ^ (row & 7)) << 3);
        }
    }
    const int ntiles = ((q0 + 31) >> 6) + 1;
#pragma unroll
    for (int i = 0; i < 4; ++i) gload_lds16(kg[i], &Ks[0][lb[i]]);
#pragma unroll
    for (int i = 0; i < 4; ++i) gload_lds16(vg[i], &Vs[0][lb[i]]);
    asm volatile("s_waitcnt vmcnt(0)");
    __syncthreads();

    int cur = 0;
    for (int jt = 0; jt < ntiles; ++jt) {
        const int j0 = jt * 64;
        if (jt + 1 < ntiles) {
            const int jn = j0 + 64;
#pragma unroll
            for (int i = 0; i < 4; ++i) gload_lds16(kg[i] + (size_t)jn * 128, &Ks[cur ^ 1][lb[i]]);
#pragma unroll
            for (int i = 0; i < 4; ++i) gload_lds16(vg[i] + jn, &Vs[cur ^ 1][lb[i]]);
        }
        const bool have1 = (j0 + 32 <= q0 + 31);    // second 32-half valid
        const bool fsub0 = (j0 + 31 <= q0);         // half0 fully unmasked
        const bool fsub1 = (j0 + 63 <= q0);         // half1 fully unmasked
        // ---- QK^T both halves (independent chains) ----
        f32x16 s0, s1;
#pragma unroll
        for (int r = 0; r < 16; ++r) { s0[r] = 0.f; s1[r] = 0.f; }
        __builtin_amdgcn_s_setprio(1);
#pragma unroll
        for (int kc = 0; kc < 8; ++kc) {
            const int c = kc * 2 + hi;
            s16x8 kf0 = *(const s16x8*)&Ks[cur][ql * 128 + ((c ^ (ql & 7)) << 3)];
            s0 = mfma32(kf0, qf[kc], s0);
        }
        if (have1) {
#pragma unroll
            for (int kc = 0; kc < 8; ++kc) {
                const int c = kc * 2 + hi;
                const int kr = 32 + ql;
                s16x8 kf1 = *(const s16x8*)&Ks[cur][kr * 128 + ((c ^ (kr & 7)) << 3)];
                s1 = mfma32(kf1, qf[kc], s1);
            }
        }
        __builtin_amdgcn_s_setprio(0);
        // ---- mask ----
        float p0[16], p1[16];
        if (fsub0) {
#pragma unroll
            for (int r = 0; r < 16; ++r) p0[r] = s0[r];
        } else {
#pragma unroll
            for (int r = 0; r < 16; ++r) {
                int kvg = j0 + ((r & 3) + 8 * (r >> 2) + 4 * hi);
                p0[r] = (kvg <= qg) ? s0[r] : -3.0e38f;
            }
        }
        if (have1) {
            if (fsub1) {
#pragma unroll
                for (int r = 0; r < 16; ++r) p1[r] = s1[r];
            } else {
#pragma unroll
                for (int r = 0; r < 16; ++r) {
                    int kvg = j0 + 32 + ((r & 3) + 8 * (r >> 2) + 4 * hi);
                    p1[r] = (kvg <= qg) ? s1[r] : -3.0e38f;
                }
            }
        }
        // ---- single max over 16/32 + cross-half ----
        float a0 = fmaxf(p0[0], p0[1]),  a1 = fmaxf(p0[2], p0[3]);
        float a2 = fmaxf(p0[4], p0[5]),  a3 = fmaxf(p0[6], p0[7]);
        float a4 = fmaxf(p0[8], p0[9]),  a5 = fmaxf(p0[10], p0[11]);
        float a6 = fmaxf(p0[12], p0[13]), a7 = fmaxf(p0[14], p0[15]);
        float pmax = fmaxf(fmaxf(fmaxf(a0, a1), fmaxf(a2, a3)),
                           fmaxf(fmaxf(a4, a5), fmaxf(a6, a7)));
        if (have1) {
            float b0 = fmaxf(p1[0], p1[1]),  b1 = fmaxf(p1[2], p1[3]);
            float b2 = fmaxf(p1[4], p1[5]),  b3 = fmaxf(p1[6], p1[7]);
            float b4 = fmaxf(p1[8], p1[9]),  b5 = fmaxf(p1[10], p1[11]);
            float b6 = fmaxf(p1[12], p1[13]), b7 = fmaxf(p1[14], p1[15]);
            pmax = fmaxf(pmax, fmaxf(fmaxf(fmaxf(b0, b1), fmaxf(b2, b3)),
                                     fmaxf(fmaxf(b4, b5), fmaxf(b6, b7))));
        }
        pmax = fmaxf(pmax, __shfl_xor(pmax, 32));
        if (__any(pmax - mrun > THR)) {
            float mnew = fmaxf(mrun, pmax);
            float alpha = __builtin_exp2f((mrun - mnew) * cs);
            lrun *= alpha;
#pragma unroll
            for (int r = 0; r < 16; ++r) {
                int cr = (r & 3) + 8 * (r >> 2) + 4 * hi;
                float ar = __uint_as_float(
                    (uint32_t)__builtin_amdgcn_ds_bpermute(cr << 2, (int)__float_as_uint(alpha)));
                ov[0][r] *= ar; ov[1][r] *= ar; ov[2][r] *= ar; ov[3][r] *= ar;
            }
            mrun = mnew;
        }
        // ---- exp + sum ----
#pragma unroll
        for (int r = 0; r < 16; ++r) p0[r] = __builtin_exp2f((p0[r] - mrun) * cs);
        float ps;
        {
            float t0 = (p0[0] + p0[1]) + (p0[2] + p0[3]);
            float t1 = (p0[4] + p0[5]) + (p0[6] + p0[7]);
            float t2 = (p0[8] + p0[9]) + (p0[10] + p0[11]);
            float t3 = (p0[12] + p0[13]) + (p0[14] + p0[15]);
            ps = (t0 + t1) + (t2 + t3);
        }
        if (have1) {
#pragma unroll
            for (int r = 0; r < 16; ++r) p1[r] = __builtin_exp2f((p1[r] - mrun) * cs);
            float t0 = (p1[0] + p1[1]) + (p1[2] + p1[3]);
            float t1 = (p1[4] + p1[5]) + (p1[6] + p1[7]);
            float t2 = (p1[8] + p1[9]) + (p1[10] + p1[11]);
            float t3 = (p1[12] + p1[13]) + (p1[14] + p1[15]);
            ps += (t0 + t1) + (t2 + t3);
        }
        ps += __shfl_xor(ps, 32);
        lrun += ps;
        // ---- pack to bf16 A-fragments ----
        union { uint32_t u[4]; s16x8 v; } f00, f01, f10, f11;
        {
            uint32_t w0 = cvtpk_bf16(p0[0], p0[1]),   w1 = cvtpk_bf16(p0[2], p0[3]);
            uint32_t w2 = cvtpk_bf16(p0[4], p0[5]),   w3 = cvtpk_bf16(p0[6], p0[7]);
            uint32_t w4 = cvtpk_bf16(p0[8], p0[9]),   w5 = cvtpk_bf16(p0[10], p0[11]);
            uint32_t w6 = cvtpk_bf16(p0[12], p0[13]), w7 = cvtpk_bf16(p0[14], p0[15]);
            uint32_t w0s = (uint32_t)__shfl_xor((int)w0, 32);
            uint32_t w1s = (uint32_t)__shfl_xor((int)w1, 32);
            uint32_t w2s = (uint32_t)__shfl_xor((int)w2, 32);
            uint32_t w3s = (uint32_t)__shfl_xor((int)w3, 32);
            uint32_t w4s = (uint32_t)__shfl_xor((int)w4, 32);
            uint32_t w5s = (uint32_t)__shfl_xor((int)w5, 32);
            uint32_t w6s = (uint32_t)__shfl_xor((int)w6, 32);
            uint32_t w7s = (uint32_t)__shfl_xor((int)w7, 32);
            f00.u[0] = hi ? w2s : w0;  f00.u[1] = hi ? w3s : w1;
            f00.u[2] = hi ? w2  : w0s; f00.u[3] = hi ? w3  : w1s;
            f01.u[0] = hi ? w6s : w4;  f01.u[1] = hi ? w7s : w5;
            f01.u[2] = hi ? w6  : w4s; f01.u[3] = hi ? w7  : w5s;
        }
        if (have1) {
            uint32_t w0 = cvtpk_bf16(p1[0], p1[1]),   w1 = cvtpk_bf16(p1[2], p1[3]);
            uint32_t w2 = cvtpk_bf16(p1[4], p1[5]),   w3 = cvtpk_bf16(p1[6], p1[7]);
            uint32_t w4 = cvtpk_bf16(p1[8], p1[9]),   w5 = cvtpk_bf16(p1[10], p1[11]);
            uint32_t w6 = cvtpk_bf16(p1[12], p1[13]), w7 = cvtpk_bf16(p1[14], p1[15]);
            uint32_t w0s = (uint32_t)__shfl_xor((int)w0, 32);
            uint32_t w1s = (uint32_t)__shfl_xor((int)w1, 32);
            uint32_t w2s = (uint32_t)__shfl_xor((int)w2, 32);
            uint32_t w3s = (uint32_t)__shfl_xor((int)w3, 32);
            uint32_t w4s = (uint32_t)__shfl_xor((int)w4, 32);
            uint32_t w5s = (uint32_t)__shfl_xor((int)w5, 32);
            uint32_t w6s = (uint32_t)__shfl_xor((int)w6, 32);
            uint32_t w7s = (uint32_t)__shfl_xor((int)w7, 32);
            f10.u[0] = hi ? w2s : w0;  f10.u[1] = hi ? w3s : w1;
            f10.u[2] = hi ? w2  : w0s; f10.u[3] = hi ? w3  : w1s;
            f11.u[0] = hi ? w6s : w4;  f11.u[1] = hi ? w7s : w5;
            f11.u[2] = hi ? w6  : w4s; f11.u[3] = hi ? w7  : w5s;
        }
        // ---- PV ----
        __builtin_amdgcn_s_setprio(1);
#pragma unroll
        for (int dc = 0; dc < 4; ++dc) {
            const int dd = dc * 32 + ql;
            const int sw = (dd & 7);
            s16x8 v0 = *(const s16x8*)&Vs[cur][dd * 64 + (((hi) ^ sw) << 3)];
            ov[dc] = mfma32(f00.v, v0, ov[dc]);
            s16x8 v1 = *(const s16x8*)&Vs[cur][dd * 64 + (((2 + hi) ^ sw) << 3)];
            ov[dc] = mfma32(f01.v, v1, ov[dc]);
            if (have1) {
                s16x8 v2 = *(const s16x8*)&Vs[cur][dd * 64 + (((4 + hi) ^ sw) << 3)];
                ov[dc] = mfma32(f10.v, v2, ov[dc]);
                s16x8 v3 = *(const s16x8*)&Vs[cur][dd * 64 + (((6 + hi) ^ sw) << 3)];
                ov[dc] = mfma32(f11.v, v3, ov[dc]);
            }
        }
        __builtin_amdgcn_s_setprio(0);
        asm volatile("s_waitcnt vmcnt(0)");
        __syncthreads();
        cur ^= 1;
    }
    const float gl = gate_logits[h];
    const float gate = 1.f / (1.f + __expf(-gl));
    const float linv = gate / lrun;
#pragma unroll
    for (int r = 0; r < 16; ++r) {
        int cr = (r & 3) + 8 * (r >> 2) + 4 * hi;
        float sc = __uint_as_float(
            (uint32_t)__builtin_amdgcn_ds_bpermute(cr << 2, (int)__float_as_uint(linv)));
        int qrow = q0 + cr;
        short* orow = attnb + ((size_t)(b * S) + qrow) * 2048 + h * 128 + ql;
#pragma unroll
        for (int dc = 0; dc < 4; ++dc)
            orow[dc * 32] = (short)f2bf(ov[dc][r] * sc);
    }
}

// ---------- launch ----------
extern "C" void kernel_launch(void* const* d_in, const int* in_sizes, int n_in,
                              void* d_out, int out_size, void* d_ws, size_t ws_size,
                              hipStream_t stream) {
    const float* x  = (const float*)d_in[0];
    const float* Wq = (const float*)d_in[1];
    const float* bq = (const float*)d_in[2];
    const float* Wk = (const float*)d_in[3];
    const float* bk = (const float*)d_in[4];
    const float* Wv = (const float*)d_in[5];
    const float* bv = (const float*)d_in[6];
    const float* Wo = (const float*)d_in[7];
    const float* bo = (const float*)d_in[8];
    const float* qn = (const float*)d_in[9];
    const float* kn = (const float*)d_in[10];
    const float* gl = (const float*)d_in[11];
    const int* sp   = (const int*)d_in[13];
    float* out = (float*)d_out;

    char* ws = (char*)d_ws;
    const size_t NEED = 96481280;
    if (ws_size < NEED) return;
    short* xb    = (short*)(ws + 0);            // 16 MiB, reused as Qb
    short* wqkvT = (short*)(ws + 16777216);     // 12 MiB
    short* woT   = (short*)(ws + 29360128);     // 8 MiB
    float* bqkv  = (float*)(ws + 37748736);     // 12 KiB
    float* Y     = (float*)(ws + 37761024);     // 48 MiB, head reused as attnb
    short* Kb    = (short*)(ws + 88092672);     // 4 MiB
    short* Vtb   = (short*)(ws + 92286976);     // 4 MiB
    short* Qb    = xb;
    short* attnb = (short*)Y;

    f32_to_bf16_k<<<4096, 256, 0, stream>>>(x, xb, 1048576);
    transpose_f32_bf16_k<<<dim3(32, 32, 1), 256, 0, stream>>>(Wq, 0, 2048, wqkvT, 0, 2048);
    transpose_f32_bf16_k<<<dim3(8, 32, 1), 256, 0, stream>>>(Wk, 0, 512, wqkvT + (size_t)2048 * 2048, 0, 2048);
    transpose_f32_bf16_k<<<dim3(8, 32, 1), 256, 0, stream>>>(Wv, 0, 512, wqkvT + (size_t)2560 * 2048, 0, 2048);
    transpose_f32_bf16_k<<<dim3(32, 32, 1), 256, 0, stream>>>(Wo, 0, 2048, woT, 0, 2048);
    concat_bias_k<<<12, 256, 0, stream>>>(bq, bk, bv, bqkv);
    gemm256_k<<<dim3(12, 16), 512, 0, stream>>>(xb, wqkvT, bqkv, Y, 4096, 3072, 2048);
    qkv_post_k<<<4096, 256, 0, stream>>>(Y, qn, kn, sp, Qb, Kb);
    transpose_f32_bf16_k<<<dim3(8, 32, 2), 256, 0, stream>>>(
        Y + 2560, (size_t)2048 * 3072, 3072, Vtb, (size_t)512 * 2048, 2048);
    attn_fwd_k<<<dim3(8, 64), 256, 0, stream>>>(Qb, Kb, Vtb, gl, attnb);
    gemm256_k<<<dim3(8, 16), 512, 0, stream>>>(attnb, woT, bo, out, 4096, 2048, 2048);
}

// Round 10
// 247.221 us; speedup vs baseline: 1.1865x; 1.0152x over previous
//
#include <hip/hip_runtime.h>
#include <hip/hip_bf16.h>
#include <stdint.h>

#define DEV __device__ __forceinline__

typedef short     s16x8  __attribute__((ext_vector_type(8)));
typedef __bf16    bf16v8 __attribute__((ext_vector_type(8)));
typedef float     f32x4  __attribute__((ext_vector_type(4)));
typedef float     f32x16 __attribute__((ext_vector_type(16)));
typedef unsigned int u32x2 __attribute__((ext_vector_type(2)));

// ---------- helpers ----------
DEV unsigned short f2bf(float x) {
    uint32_t u = __float_as_uint(x);
    uint32_t r = (u + 0x7FFFu + ((u >> 16) & 1u)) >> 16;
    return (unsigned short)r;
}

DEV void gload_lds16(const void* g, void* l) {
    __builtin_amdgcn_global_load_lds((const __attribute__((address_space(1))) void*)g,
                                     (__attribute__((address_space(3))) void*)l,
                                     16, 0, 0);
}

DEV f32x4 mfma16(s16x8 a, s16x8 b, f32x4 c) {
    return __builtin_amdgcn_mfma_f32_16x16x32_bf16(
        __builtin_bit_cast(bf16v8, a), __builtin_bit_cast(bf16v8, b), c, 0, 0, 0);
}
DEV f32x16 mfma32(s16x8 a, s16x8 b, f32x16 c) {
    return __builtin_amdgcn_mfma_f32_32x32x16_bf16(
        __builtin_bit_cast(bf16v8, a), __builtin_bit_cast(bf16v8, b), c, 0, 0, 0);
}

DEV uint32_t cvtpk_bf16(float lo, float hi) {
    uint32_t r;
    asm volatile("v_cvt_pk_bf16_f32 %0, %1, %2" : "=v"(r) : "v"(lo), "v"(hi));
    return r;
}

// T12: compiler-managed cross-half exchange (hazards handled by backend).
// new_a = {a[0..31], b[0..31] into hi}, new_b = {a[32..63] into lo, b[32..63]}
DEV u32x2 pl32swap(uint32_t a, uint32_t b) {
    return __builtin_amdgcn_permlane32_swap(a, b, false, false);
}
DEV float cross_max(float x) {
    u32x2 r = pl32swap(__float_as_uint(x), __float_as_uint(x));
    return fmaxf(__uint_as_float(r[0]), __uint_as_float(r[1]));
}
DEV float cross_sum(float x) {
    u32x2 r = pl32swap(__float_as_uint(x), __float_as_uint(x));
    return __uint_as_float(r[0]) + __uint_as_float(r[1]);
}

// raw barrier with compiler + scheduler fences (NO vmcnt/lgkm drain)
DEV void barx() {
    asm volatile("" ::: "memory");
    __builtin_amdgcn_s_barrier();
    __builtin_amdgcn_sched_barrier(0);
    asm volatile("" ::: "memory");
}

// ---------- elementwise f32 -> bf16 (8 elems / thread) ----------
__global__ void f32_to_bf16_k(const float* __restrict__ in, short* __restrict__ out, int n8) {
    int i = blockIdx.x * blockDim.x + threadIdx.x;
    if (i >= n8) return;
    const float4 a = *(const float4*)(in + (size_t)i * 8);
    const float4 b = *(const float4*)(in + (size_t)i * 8 + 4);
    uint4 w;
    w.x = (uint32_t)f2bf(a.x) | ((uint32_t)f2bf(a.y) << 16);
    w.y = (uint32_t)f2bf(a.z) | ((uint32_t)f2bf(a.w) << 16);
    w.z = (uint32_t)f2bf(b.x) | ((uint32_t)f2bf(b.y) << 16);
    w.w = (uint32_t)f2bf(b.z) | ((uint32_t)f2bf(b.w) << 16);
    *(uint4*)(out + (size_t)i * 8) = w;
}

// ---------- tiled transpose f32 (R x C) -> bf16 (C x R) ----------
__global__ __launch_bounds__(256) void transpose_f32_bf16_k(
    const float* __restrict__ in, size_t in_batch, int ld_in,
    short* __restrict__ out, size_t out_batch, int ld_out) {
    __shared__ float tile[64][65];
    const float* ip = in + (size_t)blockIdx.z * in_batch;
    short* op = out + (size_t)blockIdx.z * out_batch;
    const int c0 = blockIdx.x * 64, r0 = blockIdx.y * 64;
    const int t = threadIdx.x;
    const int cc4 = (t & 15) * 4;
    const int rr  = t >> 4;
#pragma unroll
    for (int p = 0; p < 4; ++p) {
        int r = rr + p * 16;
        float4 v = *(const float4*)(ip + (size_t)(r0 + r) * ld_in + c0 + cc4);
        tile[r][cc4 + 0] = v.x; tile[r][cc4 + 1] = v.y;
        tile[r][cc4 + 2] = v.z; tile[r][cc4 + 3] = v.w;
    }
    __syncthreads();
#pragma unroll
    for (int p = 0; p < 4; ++p) {
        int oc  = (t >> 4) + p * 16;
        int rr4 = (t & 15) * 4;
        ushort4 w;
        w.x = f2bf(tile[rr4 + 0][oc]);
        w.y = f2bf(tile[rr4 + 1][oc]);
        w.z = f2bf(tile[rr4 + 2][oc]);
        w.w = f2bf(tile[rr4 + 3][oc]);
        *(ushort4*)(op + (size_t)(c0 + oc) * ld_out + r0 + rr4) = w;
    }
}

// ---------- bias concat ----------
__global__ void concat_bias_k(const float* __restrict__ bq, const float* __restrict__ bk,
                              const float* __restrict__ bv, float* __restrict__ o) {
    int i = blockIdx.x * 256 + threadIdx.x;
    if (i < 2048)       o[i] = bq[i];
    else if (i < 2560)  o[i] = bk[i - 2048];
    else if (i < 3072)  o[i] = bv[i - 2560];
}

// ---------- GEMM v4: high-reuse 256x256 tile, 4-phase counted-vmcnt ----------
// TAG only distinguishes dispatches in rocprof (QKV vs OUT).
template<int TAG>
__global__ __launch_bounds__(512, 2) void gemm256_k(
    const short* __restrict__ A, const short* __restrict__ Bt,
    const float* __restrict__ bias, float* __restrict__ C,
    int M, int N, int K) {
    __shared__ short As[2][16384];
    __shared__ short Bs[2][16384];
    const int tid = threadIdx.x;
    const int gx = gridDim.x;
    const int nwg = gx * gridDim.y;
    const int flat = blockIdx.y * gx + blockIdx.x;
    const int cpx = nwg >> 3;
    const int swz = (flat & 7) * cpx + (flat >> 3);
    const int m0 = (swz / gx) * 256, n0 = (swz % gx) * 256;
    const int lane = tid & 63, wid = tid >> 6;
    const int wm = wid >> 2, wn = wid & 3;
    const int lr = lane & 15, lg = lane >> 4;

    const int srow = tid >> 3;
    const int schunk = ((tid & 7) ^ (srow & 7)) << 3;
    const short* Ag = A  + (size_t)(m0 + srow) * K + schunk;
    const short* Bg = Bt + (size_t)(n0 + srow) * K + schunk;
    const int lwb = (tid & ~63) * 8;

    f32x4 acc[8][4];
#pragma unroll
    for (int fr = 0; fr < 8; ++fr)
#pragma unroll
        for (int fc = 0; fc < 4; ++fc)
#pragma unroll
            for (int r = 0; r < 4; ++r) acc[fr][fc][r] = 0.f;

    const int nk = K >> 6;

#define SA(u, kt, dd) gload_lds16(Ag + (size_t)(u) * 64 * K + (kt) * 64, &As[dd][(u) * 4096 + lwb])
#define SB(u, kt, dd) gload_lds16(Bg + (size_t)(u) * 64 * K + (kt) * 64, &Bs[dd][(u) * 4096 + lwb])

    SA(0, 0, 0); SA(1, 0, 0); SA(2, 0, 0); SA(3, 0, 0);
    SB(0, 0, 0); SB(1, 0, 0); SB(2, 0, 0); SB(3, 0, 0);
    asm volatile("s_waitcnt vmcnt(0)" ::: "memory");
    barx();

#define PHASE(mh, nh, STG, WAIT)                                               \
    {                                                                          \
        s16x8 af[2][4], bfv[2][2];                                             \
        _Pragma("unroll")                                                      \
        for (int ks = 0; ks < 2; ++ks) {                                       \
            const int csw = ((ks * 4 + lg) ^ (lr & 7)) * 8;                    \
            _Pragma("unroll")                                                  \
            for (int i = 0; i < 4; ++i) {                                      \
                const int row = wm * 128 + (mh) * 64 + i * 16 + lr;            \
                af[ks][i] = *(const s16x8*)&As[d][row * 64 + csw];             \
            }                                                                  \
            _Pragma("unroll")                                                  \
            for (int j = 0; j < 2; ++j) {                                      \
                const int row = wn * 64 + (nh) * 32 + j * 16 + lr;             \
                bfv[ks][j] = *(const s16x8*)&Bs[d][row * 64 + csw];            \
            }                                                                  \
        }                                                                      \
        if (more) { STG; }                                                     \
        __builtin_amdgcn_s_setprio(1);                                         \
        _Pragma("unroll")                                                      \
        for (int ks = 0; ks < 2; ++ks)                                        \
            _Pragma("unroll")                                                  \
            for (int i = 0; i < 4; ++i)                                        \
                _Pragma("unroll")                                              \
                for (int j = 0; j < 2; ++j)                                    \
                    acc[(mh) * 4 + i][(nh) * 2 + j] =                          \
                        mfma16(af[ks][i], bfv[ks][j],                          \
                               acc[(mh) * 4 + i][(nh) * 2 + j]);               \
        __builtin_amdgcn_s_setprio(0);                                         \
        WAIT;                                                                  \
        barx();                                                                \
    }

    for (int t = 0; t < nk; ++t) {
        const int d = t & 1, e = d ^ 1;
        const bool more = (t + 1 < nk);
        PHASE(0, 0, (SA(0, t + 1, e), SA(2, t + 1, e)), );
        PHASE(0, 1, (SB(0, t + 1, e), SB(1, t + 1, e)),
              if (more) { asm volatile("s_waitcnt vmcnt(4)" ::: "memory"); }
              else      { asm volatile("s_waitcnt vmcnt(0)" ::: "memory"); });
        PHASE(1, 0, (SB(2, t + 1, e), SB(3, t + 1, e)), );
        PHASE(1, 1, (SA(1, t + 1, e), SA(3, t + 1, e)),
              if (more) { asm volatile("s_waitcnt vmcnt(2)" ::: "memory"); });
    }
#undef PHASE
#undef SA
#undef SB

#pragma unroll
    for (int fr = 0; fr < 8; ++fr) {
        const int row = m0 + wm * 128 + fr * 16 + lg * 4;
#pragma unroll
        for (int fc = 0; fc < 4; ++fc) {
            const int col = n0 + wn * 64 + fc * 16 + lr;
            const float bbv = bias[col];
#pragma unroll
            for (int r = 0; r < 4; ++r)
                C[(size_t)(row + r) * N + col] = acc[fr][fc][r] + bbv;
        }
    }
}

// ---------- rmsnorm + rope + head layout for Q,K ----------
__global__ __launch_bounds__(256) void qkv_post_k(
    const float* __restrict__ Y, const float* __restrict__ qn_w,
    const float* __restrict__ kn_w, const int* __restrict__ start_pos,
    short* __restrict__ Qb, short* __restrict__ Kb) {
    const int m = blockIdx.x;
    const int b = m >> 11, s = m & 2047;
    const float* y = Y + (size_t)m * 3072;
    const int tid = threadIdx.x;

    const float4 q1 = *(const float4*)(y + tid * 8);
    const float4 q2 = *(const float4*)(y + tid * 8 + 4);
    const float2 kv = *(const float2*)(y + 2048 + tid * 2);
    float ssq = q1.x * q1.x + q1.y * q1.y + q1.z * q1.z + q1.w * q1.w
              + q2.x * q2.x + q2.y * q2.y + q2.z * q2.z + q2.w * q2.w;
    float ssk = kv.x * kv.x + kv.y * kv.y;
#pragma unroll
    for (int off = 1; off < 64; off <<= 1) {
        ssq += __shfl_xor(ssq, off);
        ssk += __shfl_xor(ssk, off);
    }
    __shared__ float red[8];
    if ((tid & 63) == 0) { red[tid >> 6] = ssq; red[4 + (tid >> 6)] = ssk; }
    __syncthreads();
    const float tq = red[0] + red[1] + red[2] + red[3];
    const float tk = red[4] + red[5] + red[6] + red[7];
    const float rq = rsqrtf(tq * (1.f / 2048.f) + 1.1920929e-07f);
    const float rk = rsqrtf(tk * (1.f / 512.f) + 1.1920929e-07f);
    const int pos = start_pos[0] + s;

    float qn[8];
    qn[0] = q1.x; qn[1] = q1.y; qn[2] = q1.z; qn[3] = q1.w;
    qn[4] = q2.x; qn[5] = q2.y; qn[6] = q2.z; qn[7] = q2.w;
#pragma unroll
    for (int j = 0; j < 8; ++j) qn[j] *= rq * qn_w[tid * 8 + j];
    const int hq = tid >> 4;
    const int din = (tid * 8) & 127;
    unsigned short ob[8];
#pragma unroll
    for (int j = 0; j < 4; ++j) {
        int tt = (din >> 1) + j;
        float inv = __builtin_exp2f(-0.20762050f * (float)tt);
        float ang = (float)pos * inv;
        float sn, cn;
        __sincosf(ang, &sn, &cn);
        float x1 = qn[2 * j], x2 = qn[2 * j + 1];
        ob[2 * j]     = f2bf(x1 * cn - x2 * sn);
        ob[2 * j + 1] = f2bf(x1 * sn + x2 * cn);
    }
    short* qdst = Qb + (((size_t)(b * 16 + hq) * 2048 + s) * 128 + din);
    uint4 w;
    w.x = (uint32_t)ob[0] | ((uint32_t)ob[1] << 16);
    w.y = (uint32_t)ob[2] | ((uint32_t)ob[3] << 16);
    w.z = (uint32_t)ob[4] | ((uint32_t)ob[5] << 16);
    w.w = (uint32_t)ob[6] | ((uint32_t)ob[7] << 16);
    *(uint4*)qdst = w;

    const int colk = tid * 2;
    const int hk = colk >> 7, dk = colk & 127;
    float k1 = kv.x * rk * kn_w[colk], k2 = kv.y * rk * kn_w[colk + 1];
    {
        int tt = dk >> 1;
        float inv = __builtin_exp2f(-0.20762050f * (float)tt);
        float ang = (float)pos * inv;
        float sn, cn;
        __sincosf(ang, &sn, &cn);
        float r1 = k1 * cn - k2 * sn, r2 = k1 * sn + k2 * cn;
        short* kdst = Kb + (((size_t)(b * 4 + hk) * 2048 + s) * 128 + dk);
        *(uint32_t*)kdst = (uint32_t)f2bf(r1) | ((uint32_t)f2bf(r2) << 16);
    }
}

// ---------- flash attention v6: permlane cross-half (T12 builtin) ----------
__global__ __launch_bounds__(256, 2) void attn_fwd_k(
    const short* __restrict__ Qb, const short* __restrict__ Kb,
    const short* __restrict__ Vtb, const float* __restrict__ gate_logits,
    short* __restrict__ attnb) {
    const int S = 2048;
    __shared__ short Ks[2][64 * 128];
    __shared__ short Vs[2][128 * 64];
    const int tid = threadIdx.x, lane = tid & 63;
    const int wid = tid >> 6;
    const int y = blockIdx.y;
    const int qt = (y < 32) ? (63 - y) : (y - 32);   // balanced pairing
    const int bhk = blockIdx.x;
    const int b = bhk >> 2, hk = bhk & 3;
    const int h = hk * 4 + wid;
    const int q0 = qt * 32;
    const int ql = lane & 31, hi = lane >> 5;
    const int qg = q0 + ql;

    s16x8 qf[8];
    {
        const short* qrow = Qb + (((size_t)(b * 16 + h) * S + qg) * 128 + hi * 8);
#pragma unroll
        for (int kc = 0; kc < 8; ++kc) qf[kc] = *(const s16x8*)(qrow + kc * 16);
    }
    f32x16 ov[4];
#pragma unroll
    for (int dc = 0; dc < 4; ++dc)
#pragma unroll
        for (int r = 0; r < 16; ++r) ov[dc][r] = 0.f;
    float mrun = -3.0e38f, lrun = 0.f;
    const float cs = 0.12751745f;     // (1/sqrt(128)) * log2(e)
    const float THR = 90.509668f;     // 8*sqrt(128)

    const short* kg[4]; const short* vg[4]; int lb[4];
#pragma unroll
    for (int i = 0; i < 4; ++i) {
        int oo = (i * 256 + tid) * 8;
        lb[i] = (i * 256 + (tid & ~63)) * 8;
        {
            int row = oo >> 7, col = oo & 127, ch = col >> 3;
            kg[i] = Kb + ((size_t)bhk * S + row) * 128 + ((ch ^ (row & 7)) << 3);
        }
        {
            int row = oo >> 6, col = oo & 63, ch = col >> 3;
            vg[i] = Vtb + ((size_t)bhk * 128 + row) * S + ((ch ^ (row & 7)) << 3);
        }
    }
    const int ntiles = ((q0 + 31) >> 6) + 1;
#pragma unroll
    for (int i = 0; i < 4; ++i) gload_lds16(kg[i], &Ks[0][lb[i]]);
#pragma unroll
    for (int i = 0; i < 4; ++i) gload_lds16(vg[i], &Vs[0][lb[i]]);
    asm volatile("s_waitcnt vmcnt(0)");
    __syncthreads();

    int cur = 0;
    for (int jt = 0; jt < ntiles; ++jt) {
        const int j0 = jt * 64;
        if (jt + 1 < ntiles) {
            const int jn = j0 + 64;
#pragma unroll
            for (int i = 0; i < 4; ++i) gload_lds16(kg[i] + (size_t)jn * 128, &Ks[cur ^ 1][lb[i]]);
#pragma unroll
            for (int i = 0; i < 4; ++i) gload_lds16(vg[i] + jn, &Vs[cur ^ 1][lb[i]]);
        }
        const bool have1 = (j0 + 32 <= q0 + 31);
        const bool fsub0 = (j0 + 31 <= q0);
        const bool fsub1 = (j0 + 63 <= q0);
        // ---- QK^T both halves ----
        f32x16 s0, s1;
#pragma unroll
        for (int r = 0; r < 16; ++r) { s0[r] = 0.f; s1[r] = 0.f; }
        __builtin_amdgcn_s_setprio(1);
#pragma unroll
        for (int kc = 0; kc < 8; ++kc) {
            const int c = kc * 2 + hi;
            s16x8 kf0 = *(const s16x8*)&Ks[cur][ql * 128 + ((c ^ (ql & 7)) << 3)];
            s0 = mfma32(kf0, qf[kc], s0);
        }
        if (have1) {
#pragma unroll
            for (int kc = 0; kc < 8; ++kc) {
                const int c = kc * 2 + hi;
                const int kr = 32 + ql;
                s16x8 kf1 = *(const s16x8*)&Ks[cur][kr * 128 + ((c ^ (kr & 7)) << 3)];
                s1 = mfma32(kf1, qf[kc], s1);
            }
        }
        __builtin_amdgcn_s_setprio(0);
        // ---- mask ----
        float p0[16], p1[16];
        if (fsub0) {
#pragma unroll
            for (int r = 0; r < 16; ++r) p0[r] = s0[r];
        } else {
#pragma unroll
            for (int r = 0; r < 16; ++r) {
                int kvg = j0 + ((r & 3) + 8 * (r >> 2) + 4 * hi);
                p0[r] = (kvg <= qg) ? s0[r] : -3.0e38f;
            }
        }
        if (have1) {
            if (fsub1) {
#pragma unroll
                for (int r = 0; r < 16; ++r) p1[r] = s1[r];
            } else {
#pragma unroll
                for (int r = 0; r < 16; ++r) {
                    int kvg = j0 + 32 + ((r & 3) + 8 * (r >> 2) + 4 * hi);
                    p1[r] = (kvg <= qg) ? s1[r] : -3.0e38f;
                }
            }
        }
        // ---- max + cross-half (permlane) ----
        float a0 = fmaxf(p0[0], p0[1]),  a1 = fmaxf(p0[2], p0[3]);
        float a2 = fmaxf(p0[4], p0[5]),  a3 = fmaxf(p0[6], p0[7]);
        float a4 = fmaxf(p0[8], p0[9]),  a5 = fmaxf(p0[10], p0[11]);
        float a6 = fmaxf(p0[12], p0[13]), a7 = fmaxf(p0[14], p0[15]);
        float pmax = fmaxf(fmaxf(fmaxf(a0, a1), fmaxf(a2, a3)),
                           fmaxf(fmaxf(a4, a5), fmaxf(a6, a7)));
        if (have1) {
            float b0 = fmaxf(p1[0], p1[1]),  b1 = fmaxf(p1[2], p1[3]);
            float b2 = fmaxf(p1[4], p1[5]),  b3 = fmaxf(p1[6], p1[7]);
            float b4 = fmaxf(p1[8], p1[9]),  b5 = fmaxf(p1[10], p1[11]);
            float b6 = fmaxf(p1[12], p1[13]), b7 = fmaxf(p1[14], p1[15]);
            pmax = fmaxf(pmax, fmaxf(fmaxf(fmaxf(b0, b1), fmaxf(b2, b3)),
                                     fmaxf(fmaxf(b4, b5), fmaxf(b6, b7))));
        }
        pmax = cross_max(pmax);
        if (__any(pmax - mrun > THR)) {
            float mnew = fmaxf(mrun, pmax);
            float alpha = __builtin_exp2f((mrun - mnew) * cs);
            lrun *= alpha;
#pragma unroll
            for (int r = 0; r < 16; ++r) {
                int cr = (r & 3) + 8 * (r >> 2) + 4 * hi;
                float ar = __uint_as_float(
                    (uint32_t)__builtin_amdgcn_ds_bpermute(cr << 2, (int)__float_as_uint(alpha)));
                ov[0][r] *= ar; ov[1][r] *= ar; ov[2][r] *= ar; ov[3][r] *= ar;
            }
            mrun = mnew;
        }
        // ---- exp + sum ----
#pragma unroll
        for (int r = 0; r < 16; ++r) p0[r] = __builtin_exp2f((p0[r] - mrun) * cs);
        float ps;
        {
            float t0 = (p0[0] + p0[1]) + (p0[2] + p0[3]);
            float t1 = (p0[4] + p0[5]) + (p0[6] + p0[7]);
            float t2 = (p0[8] + p0[9]) + (p0[10] + p0[11]);
            float t3 = (p0[12] + p0[13]) + (p0[14] + p0[15]);
            ps = (t0 + t1) + (t2 + t3);
        }
        if (have1) {
#pragma unroll
            for (int r = 0; r < 16; ++r) p1[r] = __builtin_exp2f((p1[r] - mrun) * cs);
            float t0 = (p1[0] + p1[1]) + (p1[2] + p1[3]);
            float t1 = (p1[4] + p1[5]) + (p1[6] + p1[7]);
            float t2 = (p1[8] + p1[9]) + (p1[10] + p1[11]);
            float t3 = (p1[12] + p1[13]) + (p1[14] + p1[15]);
            ps += (t0 + t1) + (t2 + t3);
        }
        lrun += cross_sum(ps);
        // ---- pack to bf16 A-fragments via permlane32_swap ----
        union { uint32_t u[4]; s16x8 v; } f00, f01, f10, f11;
        {
            uint32_t w0 = cvtpk_bf16(p0[0], p0[1]),   w1 = cvtpk_bf16(p0[2], p0[3]);
            uint32_t w2 = cvtpk_bf16(p0[4], p0[5]),   w3 = cvtpk_bf16(p0[6], p0[7]);
            uint32_t w4 = cvtpk_bf16(p0[8], p0[9]),   w5 = cvtpk_bf16(p0[10], p0[11]);
            uint32_t w6 = cvtpk_bf16(p0[12], p0[13]), w7 = cvtpk_bf16(p0[14], p0[15]);
            u32x2 r02 = pl32swap(w0, w2); f00.u[0] = r02[0]; f00.u[2] = r02[1];
            u32x2 r13 = pl32swap(w1, w3); f00.u[1] = r13[0]; f00.u[3] = r13[1];
            u32x2 r46 = pl32swap(w4, w6); f01.u[0] = r46[0]; f01.u[2] = r46[1];
            u32x2 r57 = pl32swap(w5, w7); f01.u[1] = r57[0]; f01.u[3] = r57[1];
        }
        if (have1) {
            uint32_t w0 = cvtpk_bf16(p1[0], p1[1]),   w1 = cvtpk_bf16(p1[2], p1[3]);
            uint32_t w2 = cvtpk_bf16(p1[4], p1[5]),   w3 = cvtpk_bf16(p1[6], p1[7]);
            uint32_t w4 = cvtpk_bf16(p1[8], p1[9]),   w5 = cvtpk_bf16(p1[10], p1[11]);
            uint32_t w6 = cvtpk_bf16(p1[12], p1[13]), w7 = cvtpk_bf16(p1[14], p1[15]);
            u32x2 r02 = pl32swap(w0, w2); f10.u[0] = r02[0]; f10.u[2] = r02[1];
            u32x2 r13 = pl32swap(w1, w3); f10.u[1] = r13[0]; f10.u[3] = r13[1];
            u32x2 r46 = pl32swap(w4, w6); f11.u[0] = r46[0]; f11.u[2] = r46[1];
            u32x2 r57 = pl32swap(w5, w7); f11.u[1] = r57[0]; f11.u[3] = r57[1];
        }
        // ---- PV ----
        __builtin_amdgcn_s_setprio(1);
#pragma unroll
        for (int dc = 0; dc < 4; ++dc) {
            const int dd = dc * 32 + ql;
            const int sw = (dd & 7);
            s16x8 v0 = *(const s16x8*)&Vs[cur][dd * 64 + (((hi) ^ sw) << 3)];
            ov[dc] = mfma32(f00.v, v0, ov[dc]);
            s16x8 v1 = *(const s16x8*)&Vs[cur][dd * 64 + (((2 + hi) ^ sw) << 3)];
            ov[dc] = mfma32(f01.v, v1, ov[dc]);
            if (have1) {
                s16x8 v2 = *(const s16x8*)&Vs[cur][dd * 64 + (((4 + hi) ^ sw) << 3)];
                ov[dc] = mfma32(f10.v, v2, ov[dc]);
                s16x8 v3 = *(const s16x8*)&Vs[cur][dd * 64 + (((6 + hi) ^ sw) << 3)];
                ov[dc] = mfma32(f11.v, v3, ov[dc]);
            }
        }
        __builtin_amdgcn_s_setprio(0);
        asm volatile("s_waitcnt vmcnt(0)");
        __syncthreads();
        cur ^= 1;
    }
    const float gl = gate_logits[h];
    const float gate = 1.f / (1.f + __expf(-gl));
    const float linv = gate / lrun;
#pragma unroll
    for (int r = 0; r < 16; ++r) {
        int cr = (r & 3) + 8 * (r >> 2) + 4 * hi;
        float sc = __uint_as_float(
            (uint32_t)__builtin_amdgcn_ds_bpermute(cr << 2, (int)__float_as_uint(linv)));
        int qrow = q0 + cr;
        short* orow = attnb + ((size_t)(b * S) + qrow) * 2048 + h * 128 + ql;
#pragma unroll
        for (int dc = 0; dc < 4; ++dc)
            orow[dc * 32] = (short)f2bf(ov[dc][r] * sc);
    }
}

// ---------- launch ----------
extern "C" void kernel_launch(void* const* d_in, const int* in_sizes, int n_in,
                              void* d_out, int out_size, void* d_ws, size_t ws_size,
                              hipStream_t stream) {
    const float* x  = (const float*)d_in[0];
    const float* Wq = (const float*)d_in[1];
    const float* bq = (const float*)d_in[2];
    const float* Wk = (const float*)d_in[3];
    const float* bk = (const float*)d_in[4];
    const float* Wv = (const float*)d_in[5];
    const float* bv = (const float*)d_in[6];
    const float* Wo = (const float*)d_in[7];
    const float* bo = (const float*)d_in[8];
    const float* qn = (const float*)d_in[9];
    const float* kn = (const float*)d_in[10];
    const float* gl = (const float*)d_in[11];
    const int* sp   = (const int*)d_in[13];
    float* out = (float*)d_out;

    char* ws = (char*)d_ws;
    const size_t NEED = 96481280;
    if (ws_size < NEED) return;
    short* xb    = (short*)(ws + 0);            // 16 MiB, reused as Qb
    short* wqkvT = (short*)(ws + 16777216);     // 12 MiB
    short* woT   = (short*)(ws + 29360128);     // 8 MiB
    float* bqkv  = (float*)(ws + 37748736);     // 12 KiB
    float* Y     = (float*)(ws + 37761024);     // 48 MiB, head reused as attnb
    short* Kb    = (short*)(ws + 88092672);     // 4 MiB
    short* Vtb   = (short*)(ws + 92286976);     // 4 MiB
    short* Qb    = xb;
    short* attnb = (short*)Y;

    f32_to_bf16_k<<<4096, 256, 0, stream>>>(x, xb, 1048576);
    transpose_f32_bf16_k<<<dim3(32, 32, 1), 256, 0, stream>>>(Wq, 0, 2048, wqkvT, 0, 2048);
    transpose_f32_bf16_k<<<dim3(8, 32, 1), 256, 0, stream>>>(Wk, 0, 512, wqkvT + (size_t)2048 * 2048, 0, 2048);
    transpose_f32_bf16_k<<<dim3(8, 32, 1), 256, 0, stream>>>(Wv, 0, 512, wqkvT + (size_t)2560 * 2048, 0, 2048);
    transpose_f32_bf16_k<<<dim3(32, 32, 1), 256, 0, stream>>>(Wo, 0, 2048, woT, 0, 2048);
    concat_bias_k<<<12, 256, 0, stream>>>(bq, bk, bv, bqkv);
    gemm256_k<0><<<dim3(12, 16), 512, 0, stream>>>(xb, wqkvT, bqkv, Y, 4096, 3072, 2048);
    qkv_post_k<<<4096, 256, 0, stream>>>(Y, qn, kn, sp, Qb, Kb);
    transpose_f32_bf16_k<<<dim3(8, 32, 2), 256, 0, stream>>>(
        Y + 2560, (size_t)2048 * 3072, 3072, Vtb, (size_t)512 * 2048, 2048);
    attn_fwd_k<<<dim3(8, 64), 256, 0, stream>>>(Qb, Kb, Vtb, gl, attnb);
    gemm256_k<1><<<dim3(8, 16), 512, 0, stream>>>(attnb, woT, bo, out, 4096, 2048, 2048);
}

// Round 11
// 209.782 us; speedup vs baseline: 1.3983x; 1.1785x over previous
//
#include <hip/hip_runtime.h>
#include <hip/hip_bf16.h>
#include <stdint.h>

#define DEV __device__ __forceinline__

typedef short     s16x8  __attribute__((ext_vector_type(8)));
typedef __bf16    bf16v8 __attribute__((ext_vector_type(8)));
typedef float     f32x4  __attribute__((ext_vector_type(4)));
typedef float     f32x16 __attribute__((ext_vector_type(16)));
typedef unsigned int u32x2 __attribute__((ext_vector_type(2)));

// ---------- helpers ----------
DEV unsigned short f2bf(float x) {
    uint32_t u = __float_as_uint(x);
    uint32_t r = (u + 0x7FFFu + ((u >> 16) & 1u)) >> 16;
    return (unsigned short)r;
}
DEV float bf2f(uint32_t u) { return __uint_as_float(u << 16); }

DEV void gload_lds16(const void* g, void* l) {
    __builtin_amdgcn_global_load_lds((const __attribute__((address_space(1))) void*)g,
                                     (__attribute__((address_space(3))) void*)l,
                                     16, 0, 0);
}

DEV f32x4 mfma16(s16x8 a, s16x8 b, f32x4 c) {
    return __builtin_amdgcn_mfma_f32_16x16x32_bf16(
        __builtin_bit_cast(bf16v8, a), __builtin_bit_cast(bf16v8, b), c, 0, 0, 0);
}
DEV f32x16 mfma32(s16x8 a, s16x8 b, f32x16 c) {
    return __builtin_amdgcn_mfma_f32_32x32x16_bf16(
        __builtin_bit_cast(bf16v8, a), __builtin_bit_cast(bf16v8, b), c, 0, 0, 0);
}

DEV uint32_t cvtpk_bf16(float lo, float hi) {
    uint32_t r;
    asm volatile("v_cvt_pk_bf16_f32 %0, %1, %2" : "=v"(r) : "v"(lo), "v"(hi));
    return r;
}

DEV u32x2 pl32swap(uint32_t a, uint32_t b) {
    return __builtin_amdgcn_permlane32_swap(a, b, false, false);
}
DEV float cross_max(float x) {
    u32x2 r = pl32swap(__float_as_uint(x), __float_as_uint(x));
    return fmaxf(__uint_as_float(r[0]), __uint_as_float(r[1]));
}
DEV float cross_sum(float x) {
    u32x2 r = pl32swap(__float_as_uint(x), __float_as_uint(x));
    return __uint_as_float(r[0]) + __uint_as_float(r[1]);
}

DEV void barx() {
    asm volatile("" ::: "memory");
    __builtin_amdgcn_s_barrier();
    __builtin_amdgcn_sched_barrier(0);
    asm volatile("" ::: "memory");
}

// ---------- elementwise f32 -> bf16 ----------
__global__ void f32_to_bf16_k(const float* __restrict__ in, short* __restrict__ out, int n8) {
    int i = blockIdx.x * blockDim.x + threadIdx.x;
    if (i >= n8) return;
    const float4 a = *(const float4*)(in + (size_t)i * 8);
    const float4 b = *(const float4*)(in + (size_t)i * 8 + 4);
    uint4 w;
    w.x = (uint32_t)f2bf(a.x) | ((uint32_t)f2bf(a.y) << 16);
    w.y = (uint32_t)f2bf(a.z) | ((uint32_t)f2bf(a.w) << 16);
    w.z = (uint32_t)f2bf(b.x) | ((uint32_t)f2bf(b.y) << 16);
    w.w = (uint32_t)f2bf(b.z) | ((uint32_t)f2bf(b.w) << 16);
    *(uint4*)(out + (size_t)i * 8) = w;
}

// ---------- tiled transpose f32 (R x C) -> bf16 (C x R) ----------
__global__ __launch_bounds__(256) void transpose_f32_bf16_k(
    const float* __restrict__ in, size_t in_batch, int ld_in,
    short* __restrict__ out, size_t out_batch, int ld_out) {
    __shared__ float tile[64][65];
    const float* ip = in + (size_t)blockIdx.z * in_batch;
    short* op = out + (size_t)blockIdx.z * out_batch;
    const int c0 = blockIdx.x * 64, r0 = blockIdx.y * 64;
    const int t = threadIdx.x;
    const int cc4 = (t & 15) * 4;
    const int rr  = t >> 4;
#pragma unroll
    for (int p = 0; p < 4; ++p) {
        int r = rr + p * 16;
        float4 v = *(const float4*)(ip + (size_t)(r0 + r) * ld_in + c0 + cc4);
        tile[r][cc4 + 0] = v.x; tile[r][cc4 + 1] = v.y;
        tile[r][cc4 + 2] = v.z; tile[r][cc4 + 3] = v.w;
    }
    __syncthreads();
#pragma unroll
    for (int p = 0; p < 4; ++p) {
        int oc  = (t >> 4) + p * 16;
        int rr4 = (t & 15) * 4;
        ushort4 w;
        w.x = f2bf(tile[rr4 + 0][oc]);
        w.y = f2bf(tile[rr4 + 1][oc]);
        w.z = f2bf(tile[rr4 + 2][oc]);
        w.w = f2bf(tile[rr4 + 3][oc]);
        *(ushort4*)(op + (size_t)(c0 + oc) * ld_out + r0 + rr4) = w;
    }
}

// ---------- tiled transpose bf16 (R x C) -> bf16 (C x R) ----------
__global__ __launch_bounds__(256) void transpose_bf16_k(
    const short* __restrict__ in, size_t in_batch, int ld_in,
    short* __restrict__ out, size_t out_batch, int ld_out) {
    __shared__ short tile[64][72];
    const short* ip = in + (size_t)blockIdx.z * in_batch;
    short* op = out + (size_t)blockIdx.z * out_batch;
    const int c0 = blockIdx.x * 64, r0 = blockIdx.y * 64;
    const int t = threadIdx.x;
    const int cc = (t & 7) * 8;
    const int rr = t >> 3;
#pragma unroll
    for (int p = 0; p < 2; ++p) {
        int r = rr + p * 32;
        s16x8 v = *(const s16x8*)(ip + (size_t)(r0 + r) * ld_in + c0 + cc);
        *(s16x8*)&tile[r][cc] = v;
    }
    __syncthreads();
    const int oc = t >> 2;
    const int rb = (t & 3) * 16;
    s16x8 w0, w1;
#pragma unroll
    for (int j = 0; j < 8; ++j) w0[j] = tile[rb + j][oc];
#pragma unroll
    for (int j = 0; j < 8; ++j) w1[j] = tile[rb + 8 + j][oc];
    *(s16x8*)(op + (size_t)(c0 + oc) * ld_out + r0 + rb) = w0;
    *(s16x8*)(op + (size_t)(c0 + oc) * ld_out + r0 + rb + 8) = w1;
}

// ---------- bias concat ----------
__global__ void concat_bias_k(const float* __restrict__ bq, const float* __restrict__ bk,
                              const float* __restrict__ bv, float* __restrict__ o) {
    int i = blockIdx.x * 256 + threadIdx.x;
    if (i < 2048)       o[i] = bq[i];
    else if (i < 2560)  o[i] = bk[i - 2048];
    else if (i < 3072)  o[i] = bv[i - 2560];
}

// ---------- GEMM v5: 256 x (NF*64) tile, 2-phase counted-vmcnt ----------
// C[M,N] = A[M,K](bf16) * Bt[N,K]^T + bias. OUTBF: write bf16 else f32.
// 8 waves (2M x 4N), wave-out 128 x NF*16. A: 4 units of 64 rows; B: NF units.
// Phase0 (mh=0): read A units {0,2} frags + ALL B frags; stage(t+1) A0,A2,B*.
// Phase1 (mh=1): read A units {1,3} + B; stage(t+1) A1,A3.
// Ledger: end-ph0 vmcnt(NF+2) -> this tile's A1,A3 landed (issued prev ph1).
//         end-ph1 vmcnt(2)    -> next tile's A0,A2,B* landed. Tail drains.
template<int TAG, bool OUTBF, int NF>
__global__ __launch_bounds__(512, 2) void gemm256_k(
    const short* __restrict__ A, const short* __restrict__ Bt,
    const float* __restrict__ bias, void* __restrict__ Cv,
    int M, int N, int K) {
    __shared__ short As[2][16384];
    __shared__ short Bs[2][NF * 4096];
    const int tid = threadIdx.x;
    const int gx = gridDim.x;
    const int nwg = gx * gridDim.y;
    const int flat = blockIdx.y * gx + blockIdx.x;
    const int cpx = nwg >> 3;
    const int swz = (flat & 7) * cpx + (flat >> 3);
    const int m0 = (swz / gx) * 256, n0 = (swz % gx) * (NF * 64);
    const int lane = tid & 63, wid = tid >> 6;
    const int wm = wid >> 2, wn = wid & 3;
    const int lr = lane & 15, lg = lane >> 4;

    const int srow = tid >> 3;
    const int schunk = ((tid & 7) ^ (srow & 7)) << 3;
    const short* Ag = A  + (size_t)(m0 + srow) * K + schunk;
    const short* Bg = Bt + (size_t)(n0 + srow) * K + schunk;
    const int lwb = (tid & ~63) * 8;

    f32x4 acc[8][NF];
#pragma unroll
    for (int fr = 0; fr < 8; ++fr)
#pragma unroll
        for (int fc = 0; fc < NF; ++fc)
#pragma unroll
            for (int r = 0; r < 4; ++r) acc[fr][fc][r] = 0.f;

    const int nk = K >> 6;

#define SA(u, kt, dd) gload_lds16(Ag + (size_t)(u) * 64 * K + (kt) * 64, &As[dd][(u) * 4096 + lwb])
#define SB(u, kt, dd) gload_lds16(Bg + (size_t)(u) * 64 * K + (kt) * 64, &Bs[dd][(u) * 4096 + lwb])

    // prologue: tile 0 fully staged
    SA(0, 0, 0); SA(1, 0, 0); SA(2, 0, 0); SA(3, 0, 0);
#pragma unroll
    for (int u = 0; u < NF; ++u) SB(u, 0, 0);
    asm volatile("s_waitcnt vmcnt(0)" ::: "memory");
    barx();

    for (int t = 0; t < nk; ++t) {
        const int d = t & 1, e = d ^ 1;
        const bool more = (t + 1 < nk);
        // ---- phase 0 (mh=0) ----
        {
            s16x8 af[2][4], bf[2][NF];
#pragma unroll
            for (int ks = 0; ks < 2; ++ks) {
                const int csw = ((ks * 4 + lg) ^ (lr & 7)) * 8;
#pragma unroll
                for (int i = 0; i < 4; ++i)
                    af[ks][i] = *(const s16x8*)&As[d][(wm * 128 + i * 16 + lr) * 64 + csw];
#pragma unroll
                for (int j = 0; j < NF; ++j)
                    bf[ks][j] = *(const s16x8*)&Bs[d][(wn * (NF * 16) + j * 16 + lr) * 64 + csw];
            }
            if (more) {
                SA(0, t + 1, e); SA(2, t + 1, e);
#pragma unroll
                for (int u = 0; u < NF; ++u) SB(u, t + 1, e);
            }
            __builtin_amdgcn_s_setprio(1);
#pragma unroll
            for (int ks = 0; ks < 2; ++ks)
#pragma unroll
                for (int i = 0; i < 4; ++i)
#pragma unroll
                    for (int j = 0; j < NF; ++j)
                        acc[i][j] = mfma16(af[ks][i], bf[ks][j], acc[i][j]);
            __builtin_amdgcn_s_setprio(0);
            if (more) { asm volatile("s_waitcnt vmcnt(%0)" :: "i"(NF + 2) : "memory"); }
            else      { asm volatile("s_waitcnt vmcnt(0)" ::: "memory"); }
            barx();
        }
        // ---- phase 1 (mh=1) ----
        {
            s16x8 af[2][4], bf[2][NF];
#pragma unroll
            for (int ks = 0; ks < 2; ++ks) {
                const int csw = ((ks * 4 + lg) ^ (lr & 7)) * 8;
#pragma unroll
                for (int i = 0; i < 4; ++i)
                    af[ks][i] = *(const s16x8*)&As[d][(wm * 128 + 64 + i * 16 + lr) * 64 + csw];
#pragma unroll
                for (int j = 0; j < NF; ++j)
                    bf[ks][j] = *(const s16x8*)&Bs[d][(wn * (NF * 16) + j * 16 + lr) * 64 + csw];
            }
            if (more) { SA(1, t + 1, e); SA(3, t + 1, e); }
            __builtin_amdgcn_s_setprio(1);
#pragma unroll
            for (int ks = 0; ks < 2; ++ks)
#pragma unroll
                for (int i = 0; i < 4; ++i)
#pragma unroll
                    for (int j = 0; j < NF; ++j)
                        acc[4 + i][j] = mfma16(af[ks][i], bf[ks][j], acc[4 + i][j]);
            __builtin_amdgcn_s_setprio(0);
            if (more) {
                asm volatile("s_waitcnt vmcnt(2)" ::: "memory");
                barx();
            }
        }
    }
#undef SA
#undef SB

    // epilogue
#pragma unroll
    for (int fr = 0; fr < 8; ++fr) {
        const int row = m0 + wm * 128 + fr * 16 + lg * 4;
#pragma unroll
        for (int fc = 0; fc < NF; ++fc) {
            const int col = n0 + wn * (NF * 16) + fc * 16 + lr;
            const float bbv = bias[col];
            if constexpr (OUTBF) {
                short* Cs = (short*)Cv;
#pragma unroll
                for (int r = 0; r < 4; ++r)
                    Cs[(size_t)(row + r) * N + col] = (short)f2bf(acc[fr][fc][r] + bbv);
            } else {
                float* Cf = (float*)Cv;
#pragma unroll
                for (int r = 0; r < 4; ++r)
                    Cf[(size_t)(row + r) * N + col] = acc[fr][fc][r] + bbv;
            }
        }
    }
}

// ---------- rmsnorm + rope + head layout for Q,K (bf16 Y input) ----------
__global__ __launch_bounds__(256) void qkv_post_k(
    const short* __restrict__ Y, const float* __restrict__ qn_w,
    const float* __restrict__ kn_w, const int* __restrict__ start_pos,
    short* __restrict__ Qb, short* __restrict__ Kb) {
    const int m = blockIdx.x;
    const int b = m >> 11, s = m & 2047;
    const short* y = Y + (size_t)m * 3072;
    const int tid = threadIdx.x;

    s16x8 qv = *(const s16x8*)(y + tid * 8);
    float qn[8];
#pragma unroll
    for (int j = 0; j < 8; ++j) qn[j] = bf2f((uint32_t)(unsigned short)qv[j]);
    const uint32_t kvu = *(const uint32_t*)(y + 2048 + tid * 2);
    float k1 = bf2f(kvu & 0xffffu), k2 = bf2f(kvu >> 16);

    float ssq = qn[0]*qn[0] + qn[1]*qn[1] + qn[2]*qn[2] + qn[3]*qn[3]
              + qn[4]*qn[4] + qn[5]*qn[5] + qn[6]*qn[6] + qn[7]*qn[7];
    float ssk = k1 * k1 + k2 * k2;
#pragma unroll
    for (int off = 1; off < 64; off <<= 1) {
        ssq += __shfl_xor(ssq, off);
        ssk += __shfl_xor(ssk, off);
    }
    __shared__ float red[8];
    if ((tid & 63) == 0) { red[tid >> 6] = ssq; red[4 + (tid >> 6)] = ssk; }
    __syncthreads();
    const float tq = red[0] + red[1] + red[2] + red[3];
    const float tk = red[4] + red[5] + red[6] + red[7];
    const float rq = rsqrtf(tq * (1.f / 2048.f) + 1.1920929e-07f);
    const float rk = rsqrtf(tk * (1.f / 512.f) + 1.1920929e-07f);
    const int pos = start_pos[0] + s;

#pragma unroll
    for (int j = 0; j < 8; ++j) qn[j] *= rq * qn_w[tid * 8 + j];
    const int hq = tid >> 4;
    const int din = (tid * 8) & 127;
    unsigned short ob[8];
#pragma unroll
    for (int j = 0; j < 4; ++j) {
        int tt = (din >> 1) + j;
        float inv = __builtin_exp2f(-0.20762050f * (float)tt);
        float ang = (float)pos * inv;
        float sn, cn;
        __sincosf(ang, &sn, &cn);
        float x1 = qn[2 * j], x2 = qn[2 * j + 1];
        ob[2 * j]     = f2bf(x1 * cn - x2 * sn);
        ob[2 * j + 1] = f2bf(x1 * sn + x2 * cn);
    }
    short* qdst = Qb + (((size_t)(b * 16 + hq) * 2048 + s) * 128 + din);
    uint4 w;
    w.x = (uint32_t)ob[0] | ((uint32_t)ob[1] << 16);
    w.y = (uint32_t)ob[2] | ((uint32_t)ob[3] << 16);
    w.z = (uint32_t)ob[4] | ((uint32_t)ob[5] << 16);
    w.w = (uint32_t)ob[6] | ((uint32_t)ob[7] << 16);
    *(uint4*)qdst = w;

    const int colk = tid * 2;
    const int hk = colk >> 7, dk = colk & 127;
    float kk1 = k1 * rk * kn_w[colk], kk2 = k2 * rk * kn_w[colk + 1];
    {
        int tt = dk >> 1;
        float inv = __builtin_exp2f(-0.20762050f * (float)tt);
        float ang = (float)pos * inv;
        float sn, cn;
        __sincosf(ang, &sn, &cn);
        float r1 = kk1 * cn - kk2 * sn, r2 = kk1 * sn + kk2 * cn;
        short* kdst = Kb + (((size_t)(b * 4 + hk) * 2048 + s) * 128 + dk);
        *(uint32_t*)kdst = (uint32_t)f2bf(r1) | ((uint32_t)f2bf(r2) << 16);
    }
}

// ---------- flash attention v6: permlane cross-half (unchanged from r10) ----
__global__ __launch_bounds__(256, 2) void attn_fwd_k(
    const short* __restrict__ Qb, const short* __restrict__ Kb,
    const short* __restrict__ Vtb, const float* __restrict__ gate_logits,
    short* __restrict__ attnb) {
    const int S = 2048;
    __shared__ short Ks[2][64 * 128];
    __shared__ short Vs[2][128 * 64];
    const int tid = threadIdx.x, lane = tid & 63;
    const int wid = tid >> 6;
    const int y = blockIdx.y;
    const int qt = (y < 32) ? (63 - y) : (y - 32);
    const int bhk = blockIdx.x;
    const int b = bhk >> 2, hk = bhk & 3;
    const int h = hk * 4 + wid;
    const int q0 = qt * 32;
    const int ql = lane & 31, hi = lane >> 5;
    const int qg = q0 + ql;

    s16x8 qf[8];
    {
        const short* qrow = Qb + (((size_t)(b * 16 + h) * S + qg) * 128 + hi * 8);
#pragma unroll
        for (int kc = 0; kc < 8; ++kc) qf[kc] = *(const s16x8*)(qrow + kc * 16);
    }
    f32x16 ov[4];
#pragma unroll
    for (int dc = 0; dc < 4; ++dc)
#pragma unroll
        for (int r = 0; r < 16; ++r) ov[dc][r] = 0.f;
    float mrun = -3.0e38f, lrun = 0.f;
    const float cs = 0.12751745f;
    const float THR = 90.509668f;

    const short* kg[4]; const short* vg[4]; int lb[4];
#pragma unroll
    for (int i = 0; i < 4; ++i) {
        int oo = (i * 256 + tid) * 8;
        lb[i] = (i * 256 + (tid & ~63)) * 8;
        {
            int row = oo >> 7, col = oo & 127, ch = col >> 3;
            kg[i] = Kb + ((size_t)bhk * S + row) * 128 + ((ch ^ (row & 7)) << 3);
        }
        {
            int row = oo >> 6, col = oo & 63, ch = col >> 3;
            vg[i] = Vtb + ((size_t)bhk * 128 + row) * S + ((ch ^ (row & 7)) << 3);
        }
    }
    const int ntiles = ((q0 + 31) >> 6) + 1;
#pragma unroll
    for (int i = 0; i < 4; ++i) gload_lds16(kg[i], &Ks[0][lb[i]]);
#pragma unroll
    for (int i = 0; i < 4; ++i) gload_lds16(vg[i], &Vs[0][lb[i]]);
    asm volatile("s_waitcnt vmcnt(0)");
    __syncthreads();

    int cur = 0;
    for (int jt = 0; jt < ntiles; ++jt) {
        const int j0 = jt * 64;
        if (jt + 1 < ntiles) {
            const int jn = j0 + 64;
#pragma unroll
            for (int i = 0; i < 4; ++i) gload_lds16(kg[i] + (size_t)jn * 128, &Ks[cur ^ 1][lb[i]]);
#pragma unroll
            for (int i = 0; i < 4; ++i) gload_lds16(vg[i] + jn, &Vs[cur ^ 1][lb[i]]);
        }
        const bool have1 = (j0 + 32 <= q0 + 31);
        const bool fsub0 = (j0 + 31 <= q0);
        const bool fsub1 = (j0 + 63 <= q0);
        f32x16 s0, s1;
#pragma unroll
        for (int r = 0; r < 16; ++r) { s0[r] = 0.f; s1[r] = 0.f; }
        __builtin_amdgcn_s_setprio(1);
#pragma unroll
        for (int kc = 0; kc < 8; ++kc) {
            const int c = kc * 2 + hi;
            s16x8 kf0 = *(const s16x8*)&Ks[cur][ql * 128 + ((c ^ (ql & 7)) << 3)];
            s0 = mfma32(kf0, qf[kc], s0);
        }
        if (have1) {
#pragma unroll
            for (int kc = 0; kc < 8; ++kc) {
                const int c = kc * 2 + hi;
                const int kr = 32 + ql;
                s16x8 kf1 = *(const s16x8*)&Ks[cur][kr * 128 + ((c ^ (kr & 7)) << 3)];
                s1 = mfma32(kf1, qf[kc], s1);
            }
        }
        __builtin_amdgcn_s_setprio(0);
        float p0[16], p1[16];
        if (fsub0) {
#pragma unroll
            for (int r = 0; r < 16; ++r) p0[r] = s0[r];
        } else {
#pragma unroll
            for (int r = 0; r < 16; ++r) {
                int kvg = j0 + ((r & 3) + 8 * (r >> 2) + 4 * hi);
                p0[r] = (kvg <= qg) ? s0[r] : -3.0e38f;
            }
        }
        if (have1) {
            if (fsub1) {
#pragma unroll
                for (int r = 0; r < 16; ++r) p1[r] = s1[r];
            } else {
#pragma unroll
                for (int r = 0; r < 16; ++r) {
                    int kvg = j0 + 32 + ((r & 3) + 8 * (r >> 2) + 4 * hi);
                    p1[r] = (kvg <= qg) ? s1[r] : -3.0e38f;
                }
            }
        }
        float a0 = fmaxf(p0[0], p0[1]),  a1 = fmaxf(p0[2], p0[3]);
        float a2 = fmaxf(p0[4], p0[5]),  a3 = fmaxf(p0[6], p0[7]);
        float a4 = fmaxf(p0[8], p0[9]),  a5 = fmaxf(p0[10], p0[11]);
        float a6 = fmaxf(p0[12], p0[13]), a7 = fmaxf(p0[14], p0[15]);
        float pmax = fmaxf(fmaxf(fmaxf(a0, a1), fmaxf(a2, a3)),
                           fmaxf(fmaxf(a4, a5), fmaxf(a6, a7)));
        if (have1) {
            float b0 = fmaxf(p1[0], p1[1]),  b1 = fmaxf(p1[2], p1[3]);
            float b2 = fmaxf(p1[4], p1[5]),  b3 = fmaxf(p1[6], p1[7]);
            float b4 = fmaxf(p1[8], p1[9]),  b5 = fmaxf(p1[10], p1[11]);
            float b6 = fmaxf(p1[12], p1[13]), b7 = fmaxf(p1[14], p1[15]);
            pmax = fmaxf(pmax, fmaxf(fmaxf(fmaxf(b0, b1), fmaxf(b2, b3)),
                                     fmaxf(fmaxf(b4, b5), fmaxf(b6, b7))));
        }
        pmax = cross_max(pmax);
        if (__any(pmax - mrun > THR)) {
            float mnew = fmaxf(mrun, pmax);
            float alpha = __builtin_exp2f((mrun - mnew) * cs);
            lrun *= alpha;
#pragma unroll
            for (int r = 0; r < 16; ++r) {
                int cr = (r & 3) + 8 * (r >> 2) + 4 * hi;
                float ar = __uint_as_float(
                    (uint32_t)__builtin_amdgcn_ds_bpermute(cr << 2, (int)__float_as_uint(alpha)));
                ov[0][r] *= ar; ov[1][r] *= ar; ov[2][r] *= ar; ov[3][r] *= ar;
            }
            mrun = mnew;
        }
#pragma unroll
        for (int r = 0; r < 16; ++r) p0[r] = __builtin_exp2f((p0[r] - mrun) * cs);
        float ps;
        {
            float t0 = (p0[0] + p0[1]) + (p0[2] + p0[3]);
            float t1 = (p0[4] + p0[5]) + (p0[6] + p0[7]);
            float t2 = (p0[8] + p0[9]) + (p0[10] + p0[11]);
            float t3 = (p0[12] + p0[13]) + (p0[14] + p0[15]);
            ps = (t0 + t1) + (t2 + t3);
        }
        if (have1) {
#pragma unroll
            for (int r = 0; r < 16; ++r) p1[r] = __builtin_exp2f((p1[r] - mrun) * cs);
            float t0 = (p1[0] + p1[1]) + (p1[2] + p1[3]);
            float t1 = (p1[4] + p1[5]) + (p1[6] + p1[7]);
            float t2 = (p1[8] + p1[9]) + (p1[10] + p1[11]);
            float t3 = (p1[12] + p1[13]) + (p1[14] + p1[15]);
            ps += (t0 + t1) + (t2 + t3);
        }
        lrun += cross_sum(ps);
        union { uint32_t u[4]; s16x8 v; } f00, f01, f10, f11;
        {
            uint32_t w0 = cvtpk_bf16(p0[0], p0[1]),   w1 = cvtpk_bf16(p0[2], p0[3]);
            uint32_t w2 = cvtpk_bf16(p0[4], p0[5]),   w3 = cvtpk_bf16(p0[6], p0[7]);
            uint32_t w4 = cvtpk_bf16(p0[8], p0[9]),   w5 = cvtpk_bf16(p0[10], p0[11]);
            uint32_t w6 = cvtpk_bf16(p0[12], p0[13]), w7 = cvtpk_bf16(p0[14], p0[15]);
            u32x2 r02 = pl32swap(w0, w2); f00.u[0] = r02[0]; f00.u[2] = r02[1];
            u32x2 r13 = pl32swap(w1, w3); f00.u[1] = r13[0]; f00.u[3] = r13[1];
            u32x2 r46 = pl32swap(w4, w6); f01.u[0] = r46[0]; f01.u[2] = r46[1];
            u32x2 r57 = pl32swap(w5, w7); f01.u[1] = r57[0]; f01.u[3] = r57[1];
        }
        if (have1) {
            uint32_t w0 = cvtpk_bf16(p1[0], p1[1]),   w1 = cvtpk_bf16(p1[2], p1[3]);
            uint32_t w2 = cvtpk_bf16(p1[4], p1[5]),   w3 = cvtpk_bf16(p1[6], p1[7]);
            uint32_t w4 = cvtpk_bf16(p1[8], p1[9]),   w5 = cvtpk_bf16(p1[10], p1[11]);
            uint32_t w6 = cvtpk_bf16(p1[12], p1[13]), w7 = cvtpk_bf16(p1[14], p1[15]);
            u32x2 r02 = pl32swap(w0, w2); f10.u[0] = r02[0]; f10.u[2] = r02[1];
            u32x2 r13 = pl32swap(w1, w3); f10.u[1] = r13[0]; f10.u[3] = r13[1];
            u32x2 r46 = pl32swap(w4, w6); f11.u[0] = r46[0]; f11.u[2] = r46[1];
            u32x2 r57 = pl32swap(w5, w7); f11.u[1] = r57[0]; f11.u[3] = r57[1];
        }
        __builtin_amdgcn_s_setprio(1);
#pragma unroll
        for (int dc = 0; dc < 4; ++dc) {
            const int dd = dc * 32 + ql;
            const int sw = (dd & 7);
            s16x8 v0 = *(const s16x8*)&Vs[cur][dd * 64 + (((hi) ^ sw) << 3)];
            ov[dc] = mfma32(f00.v, v0, ov[dc]);
            s16x8 v1 = *(const s16x8*)&Vs[cur][dd * 64 + (((2 + hi) ^ sw) << 3)];
            ov[dc] = mfma32(f01.v, v1, ov[dc]);
            if (have1) {
                s16x8 v2 = *(const s16x8*)&Vs[cur][dd * 64 + (((4 + hi) ^ sw) << 3)];
                ov[dc] = mfma32(f10.v, v2, ov[dc]);
                s16x8 v3 = *(const s16x8*)&Vs[cur][dd * 64 + (((6 + hi) ^ sw) << 3)];
                ov[dc] = mfma32(f11.v, v3, ov[dc]);
            }
        }
        __builtin_amdgcn_s_setprio(0);
        asm volatile("s_waitcnt vmcnt(0)");
        __syncthreads();
        cur ^= 1;
    }
    const float gl = gate_logits[h];
    const float gate = 1.f / (1.f + __expf(-gl));
    const float linv = gate / lrun;
#pragma unroll
    for (int r = 0; r < 16; ++r) {
        int cr = (r & 3) + 8 * (r >> 2) + 4 * hi;
        float sc = __uint_as_float(
            (uint32_t)__builtin_amdgcn_ds_bpermute(cr << 2, (int)__float_as_uint(linv)));
        int qrow = q0 + cr;
        short* orow = attnb + ((size_t)(b * S) + qrow) * 2048 + h * 128 + ql;
#pragma unroll
        for (int dc = 0; dc < 4; ++dc)
            orow[dc * 32] = (short)f2bf(ov[dc][r] * sc);
    }
}

// ---------- launch ----------
extern "C" void kernel_launch(void* const* d_in, const int* in_sizes, int n_in,
                              void* d_out, int out_size, void* d_ws, size_t ws_size,
                              hipStream_t stream) {
    const float* x  = (const float*)d_in[0];
    const float* Wq = (const float*)d_in[1];
    const float* bq = (const float*)d_in[2];
    const float* Wk = (const float*)d_in[3];
    const float* bk = (const float*)d_in[4];
    const float* Wv = (const float*)d_in[5];
    const float* bv = (const float*)d_in[6];
    const float* Wo = (const float*)d_in[7];
    const float* bo = (const float*)d_in[8];
    const float* qn = (const float*)d_in[9];
    const float* kn = (const float*)d_in[10];
    const float* gl = (const float*)d_in[11];
    const int* sp   = (const int*)d_in[13];
    float* out = (float*)d_out;

    char* ws = (char*)d_ws;
    const size_t NEED = 96481280;
    if (ws_size < NEED) return;
    short* xb    = (short*)(ws + 0);            // 16 MiB, reused as Qb
    short* wqkvT = (short*)(ws + 16777216);     // 12 MiB
    short* woT   = (short*)(ws + 29360128);     // 8 MiB
    float* bqkv  = (float*)(ws + 37748736);     // 12 KiB
    short* Yb    = (short*)(ws + 37761024);     // 24 MiB bf16, head reused as attnb
    short* Kb    = (short*)(ws + 88092672);     // 4 MiB
    short* Vtb   = (short*)(ws + 92286976);     // 4 MiB
    short* Qb    = xb;
    short* attnb = Yb;

    f32_to_bf16_k<<<4096, 256, 0, stream>>>(x, xb, 1048576);
    transpose_f32_bf16_k<<<dim3(32, 32, 1), 256, 0, stream>>>(Wq, 0, 2048, wqkvT, 0, 2048);
    transpose_f32_bf16_k<<<dim3(8, 32, 1), 256, 0, stream>>>(Wk, 0, 512, wqkvT + (size_t)2048 * 2048, 0, 2048);
    transpose_f32_bf16_k<<<dim3(8, 32, 1), 256, 0, stream>>>(Wv, 0, 512, wqkvT + (size_t)2560 * 2048, 0, 2048);
    transpose_f32_bf16_k<<<dim3(32, 32, 1), 256, 0, stream>>>(Wo, 0, 2048, woT, 0, 2048);
    concat_bias_k<<<12, 256, 0, stream>>>(bq, bk, bv, bqkv);
    // QKV: 256x192 tiles -> grid 16x16 = 256 blocks (full chip, 1 round)
    gemm256_k<0, true, 3><<<dim3(16, 16), 512, 0, stream>>>(xb, wqkvT, bqkv, Yb, 4096, 3072, 2048);
    qkv_post_k<<<4096, 256, 0, stream>>>(Yb, qn, kn, sp, Qb, Kb);
    transpose_bf16_k<<<dim3(8, 32, 2), 256, 0, stream>>>(
        Yb + 2560, (size_t)2048 * 3072, 3072, Vtb, (size_t)512 * 2048, 2048);
    attn_fwd_k<<<dim3(8, 64), 256, 0, stream>>>(Qb, Kb, Vtb, gl, attnb);
    // OUT: 256x128 tiles -> grid 16x16 = 256 blocks (full chip, 1 round)
    gemm256_k<1, false, 2><<<dim3(16, 16), 512, 0, stream>>>(attnb, woT, bo, out, 4096, 2048, 2048);
}

// Round 12
// 194.637 us; speedup vs baseline: 1.5071x; 1.0778x over previous
//
#include <hip/hip_runtime.h>
#include <hip/hip_bf16.h>
#include <stdint.h>

#define DEV __device__ __forceinline__

typedef short     s16x8  __attribute__((ext_vector_type(8)));
typedef __bf16    bf16v8 __attribute__((ext_vector_type(8)));
typedef float     f32x4  __attribute__((ext_vector_type(4)));
typedef float     f32x16 __attribute__((ext_vector_type(16)));
typedef unsigned int u32x2 __attribute__((ext_vector_type(2)));

// ---------- helpers ----------
DEV unsigned short f2bf(float x) {
    uint32_t u = __float_as_uint(x);
    uint32_t r = (u + 0x7FFFu + ((u >> 16) & 1u)) >> 16;
    return (unsigned short)r;
}
DEV float bf2f(uint32_t u) { return __uint_as_float(u << 16); }

DEV void gload_lds16(const void* g, void* l) {
    __builtin_amdgcn_global_load_lds((const __attribute__((address_space(1))) void*)g,
                                     (__attribute__((address_space(3))) void*)l,
                                     16, 0, 0);
}

DEV f32x4 mfma16(s16x8 a, s16x8 b, f32x4 c) {
    return __builtin_amdgcn_mfma_f32_16x16x32_bf16(
        __builtin_bit_cast(bf16v8, a), __builtin_bit_cast(bf16v8, b), c, 0, 0, 0);
}
DEV f32x16 mfma32(s16x8 a, s16x8 b, f32x16 c) {
    return __builtin_amdgcn_mfma_f32_32x32x16_bf16(
        __builtin_bit_cast(bf16v8, a), __builtin_bit_cast(bf16v8, b), c, 0, 0, 0);
}

DEV uint32_t cvtpk_bf16(float lo, float hi) {
    uint32_t r;
    asm volatile("v_cvt_pk_bf16_f32 %0, %1, %2" : "=v"(r) : "v"(lo), "v"(hi));
    return r;
}

DEV u32x2 pl32swap(uint32_t a, uint32_t b) {
    return __builtin_amdgcn_permlane32_swap(a, b, false, false);
}
DEV float cross_max(float x) {
    u32x2 r = pl32swap(__float_as_uint(x), __float_as_uint(x));
    return fmaxf(__uint_as_float(r[0]), __uint_as_float(r[1]));
}
DEV float cross_sum(float x) {
    u32x2 r = pl32swap(__float_as_uint(x), __float_as_uint(x));
    return __uint_as_float(r[0]) + __uint_as_float(r[1]);
}

DEV void barx() {
    asm volatile("" ::: "memory");
    __builtin_amdgcn_s_barrier();
    __builtin_amdgcn_sched_barrier(0);
    asm volatile("" ::: "memory");
}

// ---------- elementwise f32 -> bf16 ----------
__global__ void f32_to_bf16_k(const float* __restrict__ in, short* __restrict__ out, int n8) {
    int i = blockIdx.x * blockDim.x + threadIdx.x;
    if (i >= n8) return;
    const float4 a = *(const float4*)(in + (size_t)i * 8);
    const float4 b = *(const float4*)(in + (size_t)i * 8 + 4);
    uint4 w;
    w.x = (uint32_t)f2bf(a.x) | ((uint32_t)f2bf(a.y) << 16);
    w.y = (uint32_t)f2bf(a.z) | ((uint32_t)f2bf(a.w) << 16);
    w.z = (uint32_t)f2bf(b.x) | ((uint32_t)f2bf(b.y) << 16);
    w.w = (uint32_t)f2bf(b.z) | ((uint32_t)f2bf(b.w) << 16);
    *(uint4*)(out + (size_t)i * 8) = w;
}

// ---------- tiled transpose f32 (R x C) -> bf16 (C x R) ----------
__global__ __launch_bounds__(256) void transpose_f32_bf16_k(
    const float* __restrict__ in, size_t in_batch, int ld_in,
    short* __restrict__ out, size_t out_batch, int ld_out) {
    __shared__ float tile[64][65];
    const float* ip = in + (size_t)blockIdx.z * in_batch;
    short* op = out + (size_t)blockIdx.z * out_batch;
    const int c0 = blockIdx.x * 64, r0 = blockIdx.y * 64;
    const int t = threadIdx.x;
    const int cc4 = (t & 15) * 4;
    const int rr  = t >> 4;
#pragma unroll
    for (int p = 0; p < 4; ++p) {
        int r = rr + p * 16;
        float4 v = *(const float4*)(ip + (size_t)(r0 + r) * ld_in + c0 + cc4);
        tile[r][cc4 + 0] = v.x; tile[r][cc4 + 1] = v.y;
        tile[r][cc4 + 2] = v.z; tile[r][cc4 + 3] = v.w;
    }
    __syncthreads();
#pragma unroll
    for (int p = 0; p < 4; ++p) {
        int oc  = (t >> 4) + p * 16;
        int rr4 = (t & 15) * 4;
        ushort4 w;
        w.x = f2bf(tile[rr4 + 0][oc]);
        w.y = f2bf(tile[rr4 + 1][oc]);
        w.z = f2bf(tile[rr4 + 2][oc]);
        w.w = f2bf(tile[rr4 + 3][oc]);
        *(ushort4*)(op + (size_t)(c0 + oc) * ld_out + r0 + rr4) = w;
    }
}

// ---------- tiled transpose bf16 (R x C) -> bf16 (C x R) ----------
__global__ __launch_bounds__(256) void transpose_bf16_k(
    const short* __restrict__ in, size_t in_batch, int ld_in,
    short* __restrict__ out, size_t out_batch, int ld_out) {
    __shared__ short tile[64][72];
    const short* ip = in + (size_t)blockIdx.z * in_batch;
    short* op = out + (size_t)blockIdx.z * out_batch;
    const int c0 = blockIdx.x * 64, r0 = blockIdx.y * 64;
    const int t = threadIdx.x;
    const int cc = (t & 7) * 8;
    const int rr = t >> 3;
#pragma unroll
    for (int p = 0; p < 2; ++p) {
        int r = rr + p * 32;
        s16x8 v = *(const s16x8*)(ip + (size_t)(r0 + r) * ld_in + c0 + cc);
        *(s16x8*)&tile[r][cc] = v;
    }
    __syncthreads();
    const int oc = t >> 2;
    const int rb = (t & 3) * 16;
    s16x8 w0, w1;
#pragma unroll
    for (int j = 0; j < 8; ++j) w0[j] = tile[rb + j][oc];
#pragma unroll
    for (int j = 0; j < 8; ++j) w1[j] = tile[rb + 8 + j][oc];
    *(s16x8*)(op + (size_t)(c0 + oc) * ld_out + r0 + rb) = w0;
    *(s16x8*)(op + (size_t)(c0 + oc) * ld_out + r0 + rb + 8) = w1;
}

// ---------- bias concat ----------
__global__ void concat_bias_k(const float* __restrict__ bq, const float* __restrict__ bk,
                              const float* __restrict__ bv, float* __restrict__ o) {
    int i = blockIdx.x * 256 + threadIdx.x;
    if (i < 2048)       o[i] = bq[i];
    else if (i < 2560)  o[i] = bk[i - 2048];
    else if (i < 3072)  o[i] = bv[i - 2560];
}

// ---------- GEMM v5: 256 x (NF*64) tile, 2-phase counted-vmcnt ----------
template<int TAG, bool OUTBF, int NF>
__global__ __launch_bounds__(512, 2) void gemm256_k(
    const short* __restrict__ A, const short* __restrict__ Bt,
    const float* __restrict__ bias, void* __restrict__ Cv,
    int M, int N, int K) {
    __shared__ short As[2][16384];
    __shared__ short Bs[2][NF * 4096];
    const int tid = threadIdx.x;
    const int gx = gridDim.x;
    const int nwg = gx * gridDim.y;
    const int flat = blockIdx.y * gx + blockIdx.x;
    const int cpx = nwg >> 3;
    const int swz = (flat & 7) * cpx + (flat >> 3);
    const int m0 = (swz / gx) * 256, n0 = (swz % gx) * (NF * 64);
    const int lane = tid & 63, wid = tid >> 6;
    const int wm = wid >> 2, wn = wid & 3;
    const int lr = lane & 15, lg = lane >> 4;

    const int srow = tid >> 3;
    const int schunk = ((tid & 7) ^ (srow & 7)) << 3;
    const short* Ag = A  + (size_t)(m0 + srow) * K + schunk;
    const short* Bg = Bt + (size_t)(n0 + srow) * K + schunk;
    const int lwb = (tid & ~63) * 8;

    f32x4 acc[8][NF];
#pragma unroll
    for (int fr = 0; fr < 8; ++fr)
#pragma unroll
        for (int fc = 0; fc < NF; ++fc)
#pragma unroll
            for (int r = 0; r < 4; ++r) acc[fr][fc][r] = 0.f;

    const int nk = K >> 6;

#define SA(u, kt, dd) gload_lds16(Ag + (size_t)(u) * 64 * K + (kt) * 64, &As[dd][(u) * 4096 + lwb])
#define SB(u, kt, dd) gload_lds16(Bg + (size_t)(u) * 64 * K + (kt) * 64, &Bs[dd][(u) * 4096 + lwb])

    SA(0, 0, 0); SA(1, 0, 0); SA(2, 0, 0); SA(3, 0, 0);
#pragma unroll
    for (int u = 0; u < NF; ++u) SB(u, 0, 0);
    asm volatile("s_waitcnt vmcnt(0)" ::: "memory");
    barx();

    for (int t = 0; t < nk; ++t) {
        const int d = t & 1, e = d ^ 1;
        const bool more = (t + 1 < nk);
        // ---- phase 0 (mh=0) ----
        {
            s16x8 af[2][4], bf[2][NF];
#pragma unroll
            for (int ks = 0; ks < 2; ++ks) {
                const int csw = ((ks * 4 + lg) ^ (lr & 7)) * 8;
#pragma unroll
                for (int i = 0; i < 4; ++i)
                    af[ks][i] = *(const s16x8*)&As[d][(wm * 128 + i * 16 + lr) * 64 + csw];
#pragma unroll
                for (int j = 0; j < NF; ++j)
                    bf[ks][j] = *(const s16x8*)&Bs[d][(wn * (NF * 16) + j * 16 + lr) * 64 + csw];
            }
            if (more) {
                SA(0, t + 1, e); SA(2, t + 1, e);
#pragma unroll
                for (int u = 0; u < NF; ++u) SB(u, t + 1, e);
            }
            __builtin_amdgcn_s_setprio(1);
#pragma unroll
            for (int ks = 0; ks < 2; ++ks)
#pragma unroll
                for (int i = 0; i < 4; ++i)
#pragma unroll
                    for (int j = 0; j < NF; ++j)
                        acc[i][j] = mfma16(af[ks][i], bf[ks][j], acc[i][j]);
            __builtin_amdgcn_s_setprio(0);
            if (more) { asm volatile("s_waitcnt vmcnt(%0)" :: "i"(NF + 2) : "memory"); }
            else      { asm volatile("s_waitcnt vmcnt(0)" ::: "memory"); }
            barx();
        }
        // ---- phase 1 (mh=1) ----
        {
            s16x8 af[2][4], bf[2][NF];
#pragma unroll
            for (int ks = 0; ks < 2; ++ks) {
                const int csw = ((ks * 4 + lg) ^ (lr & 7)) * 8;
#pragma unroll
                for (int i = 0; i < 4; ++i)
                    af[ks][i] = *(const s16x8*)&As[d][(wm * 128 + 64 + i * 16 + lr) * 64 + csw];
#pragma unroll
                for (int j = 0; j < NF; ++j)
                    bf[ks][j] = *(const s16x8*)&Bs[d][(wn * (NF * 16) + j * 16 + lr) * 64 + csw];
            }
            if (more) { SA(1, t + 1, e); SA(3, t + 1, e); }
            __builtin_amdgcn_s_setprio(1);
#pragma unroll
            for (int ks = 0; ks < 2; ++ks)
#pragma unroll
                for (int i = 0; i < 4; ++i)
#pragma unroll
                    for (int j = 0; j < NF; ++j)
                        acc[4 + i][j] = mfma16(af[ks][i], bf[ks][j], acc[4 + i][j]);
            __builtin_amdgcn_s_setprio(0);
            if (more) {
                asm volatile("s_waitcnt vmcnt(2)" ::: "memory");
                barx();
            }
        }
    }
#undef SA
#undef SB

#pragma unroll
    for (int fr = 0; fr < 8; ++fr) {
        const int row = m0 + wm * 128 + fr * 16 + lg * 4;
#pragma unroll
        for (int fc = 0; fc < NF; ++fc) {
            const int col = n0 + wn * (NF * 16) + fc * 16 + lr;
            const float bbv = bias[col];
            if constexpr (OUTBF) {
                short* Cs = (short*)Cv;
#pragma unroll
                for (int r = 0; r < 4; ++r)
                    Cs[(size_t)(row + r) * N + col] = (short)f2bf(acc[fr][fc][r] + bbv);
            } else {
                float* Cf = (float*)Cv;
#pragma unroll
                for (int r = 0; r < 4; ++r)
                    Cf[(size_t)(row + r) * N + col] = acc[fr][fc][r] + bbv;
            }
        }
    }
}

// ---------- rmsnorm + rope + head layout for Q,K (bf16 Y input) ----------
__global__ __launch_bounds__(256) void qkv_post_k(
    const short* __restrict__ Y, const float* __restrict__ qn_w,
    const float* __restrict__ kn_w, const int* __restrict__ start_pos,
    short* __restrict__ Qb, short* __restrict__ Kb) {
    const int m = blockIdx.x;
    const int b = m >> 11, s = m & 2047;
    const short* y = Y + (size_t)m * 3072;
    const int tid = threadIdx.x;

    s16x8 qv = *(const s16x8*)(y + tid * 8);
    float qn[8];
#pragma unroll
    for (int j = 0; j < 8; ++j) qn[j] = bf2f((uint32_t)(unsigned short)qv[j] << 0);
    const uint32_t kvu = *(const uint32_t*)(y + 2048 + tid * 2);
    float k1 = bf2f(kvu & 0xffffu), k2 = bf2f(kvu >> 16);

    float ssq = qn[0]*qn[0] + qn[1]*qn[1] + qn[2]*qn[2] + qn[3]*qn[3]
              + qn[4]*qn[4] + qn[5]*qn[5] + qn[6]*qn[6] + qn[7]*qn[7];
    float ssk = k1 * k1 + k2 * k2;
#pragma unroll
    for (int off = 1; off < 64; off <<= 1) {
        ssq += __shfl_xor(ssq, off);
        ssk += __shfl_xor(ssk, off);
    }
    __shared__ float red[8];
    if ((tid & 63) == 0) { red[tid >> 6] = ssq; red[4 + (tid >> 6)] = ssk; }
    __syncthreads();
    const float tq = red[0] + red[1] + red[2] + red[3];
    const float tk = red[4] + red[5] + red[6] + red[7];
    const float rq = rsqrtf(tq * (1.f / 2048.f) + 1.1920929e-07f);
    const float rk = rsqrtf(tk * (1.f / 512.f) + 1.1920929e-07f);
    const int pos = start_pos[0] + s;

#pragma unroll
    for (int j = 0; j < 8; ++j) qn[j] *= rq * qn_w[tid * 8 + j];
    const int hq = tid >> 4;
    const int din = (tid * 8) & 127;
    unsigned short ob[8];
#pragma unroll
    for (int j = 0; j < 4; ++j) {
        int tt = (din >> 1) + j;
        float inv = __builtin_exp2f(-0.20762050f * (float)tt);
        float ang = (float)pos * inv;
        float sn, cn;
        __sincosf(ang, &sn, &cn);
        float x1 = qn[2 * j], x2 = qn[2 * j + 1];
        ob[2 * j]     = f2bf(x1 * cn - x2 * sn);
        ob[2 * j + 1] = f2bf(x1 * sn + x2 * cn);
    }
    short* qdst = Qb + (((size_t)(b * 16 + hq) * 2048 + s) * 128 + din);
    uint4 w;
    w.x = (uint32_t)ob[0] | ((uint32_t)ob[1] << 16);
    w.y = (uint32_t)ob[2] | ((uint32_t)ob[3] << 16);
    w.z = (uint32_t)ob[4] | ((uint32_t)ob[5] << 16);
    w.w = (uint32_t)ob[6] | ((uint32_t)ob[7] << 16);
    *(uint4*)qdst = w;

    const int colk = tid * 2;
    const int hk = colk >> 7, dk = colk & 127;
    float kk1 = k1 * rk * kn_w[colk], kk2 = k2 * rk * kn_w[colk + 1];
    {
        int tt = dk >> 1;
        float inv = __builtin_exp2f(-0.20762050f * (float)tt);
        float ang = (float)pos * inv;
        float sn, cn;
        __sincosf(ang, &sn, &cn);
        float r1 = kk1 * cn - kk2 * sn, r2 = kk1 * sn + kk2 * cn;
        short* kdst = Kb + (((size_t)(b * 4 + hk) * 2048 + s) * 128 + dk);
        *(uint32_t*)kdst = (uint32_t)f2bf(r1) | ((uint32_t)f2bf(r2) << 16);
    }
}

// ---------- flash attention v7: equal-work pair blocks + in-block kv-split ----
// grid (8 bhk, 32 y), 512 thr = 2 groups x 4 heads. Block = q-tile pair
// {qtA=63-y, qtB=y}; nA+nB = 33 64-kv tiles for EVERY block (perfect balance).
// group0: A-tiles [0,17). group1: B-tiles [0,nB) then A-tiles [17,nA)
// (count = 16 identically); at switch it writes B's output and resets state.
// End: group1 parks A-partial (O,m,l) in dead LDS; group0 merges and writes A.
__global__ __launch_bounds__(512, 1) void attn_fwd_k(
    const short* __restrict__ Qb, const short* __restrict__ Kb,
    const short* __restrict__ Vtb, const float* __restrict__ gate_logits,
    short* __restrict__ attnb) {
    const int S = 2048;
    __shared__ short KV[2][2][16384];   // [group][buf][ K:0..8192 | V:8192.. ]
    const int tid = threadIdx.x, lane = tid & 63;
    const int wid = tid >> 6;
    const int g = wid >> 2;             // kv-split group
    const int hw = wid & 3;             // head within GQA group
    const int y = blockIdx.y;           // 0..31
    const int bhk = blockIdx.x;
    const int b = bhk >> 2, hk = bhk & 3;
    const int h = hk * 4 + hw;
    const int qtA = 63 - y, qtB = y;
    const int nA = (qtA + 2) >> 1, nB = (qtB + 2) >> 1;   // nA+nB == 33
    const int ql = lane & 31, hi = lane >> 5;
    const float cs = 0.12751745f;       // (1/sqrt(128)) * log2(e)
    const float THR = 90.509668f;       // 8*sqrt(128)
    const float gl = gate_logits[h];
    const float gate = 1.f / (1.f + __expf(-gl));

    int q0 = (g == 0 ? qtA : qtB) * 32;
    int qg = q0 + ql;

    s16x8 qf[8];
#pragma unroll
    for (int kc = 0; kc < 8; ++kc)
        qf[kc] = *(const s16x8*)(Qb + (((size_t)(b * 16 + h) * S + qg) * 128 + hi * 8) + kc * 16);

    f32x16 ov[4];
#pragma unroll
    for (int dc = 0; dc < 4; ++dc)
#pragma unroll
        for (int r = 0; r < 16; ++r) ov[dc][r] = 0.f;
    float mrun = -3.0e38f, lrun = 0.f;

    // group-local staging pointers
    const int g256 = tid & 255;
    const short* kg[4]; const short* vg[4]; int lb[4];
#pragma unroll
    for (int i = 0; i < 4; ++i) {
        int oo = (i * 256 + g256) * 8;
        lb[i] = (i * 256 + (g256 & ~63)) * 8;
        {
            int row = oo >> 7, col = oo & 127, ch = col >> 3;
            kg[i] = Kb + ((size_t)bhk * S + row) * 128 + ((ch ^ (row & 7)) << 3);
        }
        {
            int row = oo >> 6, col = oo & 63, ch = col >> 3;
            vg[i] = Vtb + ((size_t)bhk * 128 + row) * S + ((ch ^ (row & 7)) << 3);
        }
    }

#define TILE_IDX(it_) ((g == 0) ? (it_) : ((it_) < nB ? (it_) : 17 + (it_) - nB))
#define STAGE_TILE(jj, bb) do {                                                  \
        const int base_ = (jj) * 64;                                             \
        _Pragma("unroll")                                                        \
        for (int i_ = 0; i_ < 4; ++i_)                                           \
            gload_lds16(kg[i_] + (size_t)base_ * 128, &KV[g][bb][lb[i_]]);       \
        _Pragma("unroll")                                                        \
        for (int i_ = 0; i_ < 4; ++i_)                                           \
            gload_lds16(vg[i_] + base_, &KV[g][bb][8192 + lb[i_]]);              \
    } while (0)

#define WRITE_OUT(Q0_) do {                                                      \
        const float linv_ = gate / lrun;                                         \
        _Pragma("unroll")                                                        \
        for (int r_ = 0; r_ < 16; ++r_) {                                        \
            int cr_ = (r_ & 3) + 8 * (r_ >> 2) + 4 * hi;                         \
            float sc_ = __uint_as_float(                                         \
                (uint32_t)__builtin_amdgcn_ds_bpermute(cr_ << 2,                 \
                    (int)__float_as_uint(linv_)));                               \
            int qrow_ = (Q0_) + cr_;                                             \
            short* orow_ = attnb + ((size_t)(b * S) + qrow_) * 2048 + h * 128 + ql; \
            _Pragma("unroll")                                                    \
            for (int dc_ = 0; dc_ < 4; ++dc_)                                    \
                orow_[dc_ * 32] = (short)f2bf(ov[dc_][r_] * sc_);                \
        }                                                                        \
    } while (0)

    // prologue: both groups stage their tile 0 (= kv tile 0)
    STAGE_TILE(0, 0);
    asm volatile("s_waitcnt vmcnt(0)");
    __syncthreads();

    int cur = 0;
    for (int it = 0; it < 17; ++it) {
        // group1 switch: B done -> write B output, move to A suffix
        if (g == 1 && it == nB) {
            WRITE_OUT(q0);
            q0 = qtA * 32; qg = q0 + ql;
#pragma unroll
            for (int kc = 0; kc < 8; ++kc)
                qf[kc] = *(const s16x8*)(Qb + (((size_t)(b * 16 + h) * S + qg) * 128 + hi * 8) + kc * 16);
            mrun = -3.0e38f; lrun = 0.f;
#pragma unroll
            for (int dc = 0; dc < 4; ++dc)
#pragma unroll
                for (int r = 0; r < 16; ++r) ov[dc][r] = 0.f;
        }
        const int j = TILE_IDX(it);
        const bool active = (g == 0) ? true : (it < 16);
        // prefetch next tile
        {
            const int itn = it + 1;
            const bool nok = (itn < 17) && ((g == 0) ? true : (itn < 16));
            if (nok) { const int jn = TILE_IDX(itn); STAGE_TILE(jn, cur ^ 1); }
        }
        if (active) {
            const int j0 = j * 64;
            const short* Ks = &KV[g][cur][0];
            const short* Vs = &KV[g][cur][8192];
            const bool have1 = (j0 + 32 <= q0 + 31);
            const bool fsub0 = (j0 + 31 <= q0);
            const bool fsub1 = (j0 + 63 <= q0);
            f32x16 s0, s1;
#pragma unroll
            for (int r = 0; r < 16; ++r) { s0[r] = 0.f; s1[r] = 0.f; }
            __builtin_amdgcn_s_setprio(1);
#pragma unroll
            for (int kc = 0; kc < 8; ++kc) {
                const int c = kc * 2 + hi;
                s16x8 kf0 = *(const s16x8*)&Ks[ql * 128 + ((c ^ (ql & 7)) << 3)];
                s0 = mfma32(kf0, qf[kc], s0);
            }
            if (have1) {
#pragma unroll
                for (int kc = 0; kc < 8; ++kc) {
                    const int c = kc * 2 + hi;
                    const int kr = 32 + ql;
                    s16x8 kf1 = *(const s16x8*)&Ks[kr * 128 + ((c ^ (kr & 7)) << 3)];
                    s1 = mfma32(kf1, qf[kc], s1);
                }
            }
            __builtin_amdgcn_s_setprio(0);
            float p0[16], p1[16];
            if (fsub0) {
#pragma unroll
                for (int r = 0; r < 16; ++r) p0[r] = s0[r];
            } else {
#pragma unroll
                for (int r = 0; r < 16; ++r) {
                    int kvg = j0 + ((r & 3) + 8 * (r >> 2) + 4 * hi);
                    p0[r] = (kvg <= qg) ? s0[r] : -3.0e38f;
                }
            }
            if (have1) {
                if (fsub1) {
#pragma unroll
                    for (int r = 0; r < 16; ++r) p1[r] = s1[r];
                } else {
#pragma unroll
                    for (int r = 0; r < 16; ++r) {
                        int kvg = j0 + 32 + ((r & 3) + 8 * (r >> 2) + 4 * hi);
                        p1[r] = (kvg <= qg) ? s1[r] : -3.0e38f;
                    }
                }
            }
            float a0 = fmaxf(p0[0], p0[1]),  a1 = fmaxf(p0[2], p0[3]);
            float a2 = fmaxf(p0[4], p0[5]),  a3 = fmaxf(p0[6], p0[7]);
            float a4 = fmaxf(p0[8], p0[9]),  a5 = fmaxf(p0[10], p0[11]);
            float a6 = fmaxf(p0[12], p0[13]), a7 = fmaxf(p0[14], p0[15]);
            float pmax = fmaxf(fmaxf(fmaxf(a0, a1), fmaxf(a2, a3)),
                               fmaxf(fmaxf(a4, a5), fmaxf(a6, a7)));
            if (have1) {
                float b0 = fmaxf(p1[0], p1[1]),  b1 = fmaxf(p1[2], p1[3]);
                float b2 = fmaxf(p1[4], p1[5]),  b3 = fmaxf(p1[6], p1[7]);
                float b4 = fmaxf(p1[8], p1[9]),  b5 = fmaxf(p1[10], p1[11]);
                float b6 = fmaxf(p1[12], p1[13]), b7 = fmaxf(p1[14], p1[15]);
                pmax = fmaxf(pmax, fmaxf(fmaxf(fmaxf(b0, b1), fmaxf(b2, b3)),
                                         fmaxf(fmaxf(b4, b5), fmaxf(b6, b7))));
            }
            pmax = cross_max(pmax);
            if (__any(pmax - mrun > THR)) {
                float mnew = fmaxf(mrun, pmax);
                float alpha = __builtin_exp2f((mrun - mnew) * cs);
                lrun *= alpha;
#pragma unroll
                for (int r = 0; r < 16; ++r) {
                    int cr = (r & 3) + 8 * (r >> 2) + 4 * hi;
                    float ar = __uint_as_float(
                        (uint32_t)__builtin_amdgcn_ds_bpermute(cr << 2, (int)__float_as_uint(alpha)));
                    ov[0][r] *= ar; ov[1][r] *= ar; ov[2][r] *= ar; ov[3][r] *= ar;
                }
                mrun = mnew;
            }
#pragma unroll
            for (int r = 0; r < 16; ++r) p0[r] = __builtin_exp2f((p0[r] - mrun) * cs);
            float ps;
            {
                float t0 = (p0[0] + p0[1]) + (p0[2] + p0[3]);
                float t1 = (p0[4] + p0[5]) + (p0[6] + p0[7]);
                float t2 = (p0[8] + p0[9]) + (p0[10] + p0[11]);
                float t3 = (p0[12] + p0[13]) + (p0[14] + p0[15]);
                ps = (t0 + t1) + (t2 + t3);
            }
            if (have1) {
#pragma unroll
                for (int r = 0; r < 16; ++r) p1[r] = __builtin_exp2f((p1[r] - mrun) * cs);
                float t0 = (p1[0] + p1[1]) + (p1[2] + p1[3]);
                float t1 = (p1[4] + p1[5]) + (p1[6] + p1[7]);
                float t2 = (p1[8] + p1[9]) + (p1[10] + p1[11]);
                float t3 = (p1[12] + p1[13]) + (p1[14] + p1[15]);
                ps += (t0 + t1) + (t2 + t3);
            }
            lrun += cross_sum(ps);
            union { uint32_t u[4]; s16x8 v; } f00, f01, f10, f11;
            {
                uint32_t w0 = cvtpk_bf16(p0[0], p0[1]),   w1 = cvtpk_bf16(p0[2], p0[3]);
                uint32_t w2 = cvtpk_bf16(p0[4], p0[5]),   w3 = cvtpk_bf16(p0[6], p0[7]);
                uint32_t w4 = cvtpk_bf16(p0[8], p0[9]),   w5 = cvtpk_bf16(p0[10], p0[11]);
                uint32_t w6 = cvtpk_bf16(p0[12], p0[13]), w7 = cvtpk_bf16(p0[14], p0[15]);
                u32x2 r02 = pl32swap(w0, w2); f00.u[0] = r02[0]; f00.u[2] = r02[1];
                u32x2 r13 = pl32swap(w1, w3); f00.u[1] = r13[0]; f00.u[3] = r13[1];
                u32x2 r46 = pl32swap(w4, w6); f01.u[0] = r46[0]; f01.u[2] = r46[1];
                u32x2 r57 = pl32swap(w5, w7); f01.u[1] = r57[0]; f01.u[3] = r57[1];
            }
            if (have1) {
                uint32_t w0 = cvtpk_bf16(p1[0], p1[1]),   w1 = cvtpk_bf16(p1[2], p1[3]);
                uint32_t w2 = cvtpk_bf16(p1[4], p1[5]),   w3 = cvtpk_bf16(p1[6], p1[7]);
                uint32_t w4 = cvtpk_bf16(p1[8], p1[9]),   w5 = cvtpk_bf16(p1[10], p1[11]);
                uint32_t w6 = cvtpk_bf16(p1[12], p1[13]), w7 = cvtpk_bf16(p1[14], p1[15]);
                u32x2 r02 = pl32swap(w0, w2); f10.u[0] = r02[0]; f10.u[2] = r02[1];
                u32x2 r13 = pl32swap(w1, w3); f10.u[1] = r13[0]; f10.u[3] = r13[1];
                u32x2 r46 = pl32swap(w4, w6); f11.u[0] = r46[0]; f11.u[2] = r46[1];
                u32x2 r57 = pl32swap(w5, w7); f11.u[1] = r57[0]; f11.u[3] = r57[1];
            }
            __builtin_amdgcn_s_setprio(1);
#pragma unroll
            for (int dc = 0; dc < 4; ++dc) {
                const int dd = dc * 32 + ql;
                const int sw = (dd & 7);
                s16x8 v0 = *(const s16x8*)&Vs[dd * 64 + (((hi) ^ sw) << 3)];
                ov[dc] = mfma32(f00.v, v0, ov[dc]);
                s16x8 v1 = *(const s16x8*)&Vs[dd * 64 + (((2 + hi) ^ sw) << 3)];
                ov[dc] = mfma32(f01.v, v1, ov[dc]);
                if (have1) {
                    s16x8 v2 = *(const s16x8*)&Vs[dd * 64 + (((4 + hi) ^ sw) << 3)];
                    ov[dc] = mfma32(f10.v, v2, ov[dc]);
                    s16x8 v3 = *(const s16x8*)&Vs[dd * 64 + (((6 + hi) ^ sw) << 3)];
                    ov[dc] = mfma32(f11.v, v3, ov[dc]);
                }
            }
            __builtin_amdgcn_s_setprio(0);
        }
        asm volatile("s_waitcnt vmcnt(0)");
        __syncthreads();
        cur ^= 1;
    }

    // ---- merge: group1's A-partial -> group0, via (dead) KV LDS ----
    float* mb = (float*)&KV[0][0][0];
    if (g == 1) {
#pragma unroll
        for (int dc = 0; dc < 4; ++dc)
#pragma unroll
            for (int r = 0; r < 16; ++r)
                mb[hw * 4096 + lane * 64 + dc * 16 + r] = ov[dc][r];
        mb[16384 + hw * 64 + lane] = mrun;
        mb[16640 + hw * 64 + lane] = lrun;
    }
    __syncthreads();
    if (g == 0) {
        const float m1 = mb[16384 + hw * 64 + lane];
        const float l1 = mb[16640 + hw * 64 + lane];
        const float mm = fmaxf(mrun, m1);
        const float al0 = __builtin_exp2f((mrun - mm) * cs);
        const float al1 = __builtin_exp2f((m1 - mm) * cs);
        lrun = lrun * al0 + l1 * al1;
#pragma unroll
        for (int r = 0; r < 16; ++r) {
            int cr = (r & 3) + 8 * (r >> 2) + 4 * hi;
            float a0r = __uint_as_float(
                (uint32_t)__builtin_amdgcn_ds_bpermute(cr << 2, (int)__float_as_uint(al0)));
            float a1r = __uint_as_float(
                (uint32_t)__builtin_amdgcn_ds_bpermute(cr << 2, (int)__float_as_uint(al1)));
#pragma unroll
            for (int dc = 0; dc < 4; ++dc)
                ov[dc][r] = ov[dc][r] * a0r + mb[hw * 4096 + lane * 64 + dc * 16 + r] * a1r;
        }
        WRITE_OUT(q0);
    }
#undef TILE_IDX
#undef STAGE_TILE
#undef WRITE_OUT
}

// ---------- launch ----------
extern "C" void kernel_launch(void* const* d_in, const int* in_sizes, int n_in,
                              void* d_out, int out_size, void* d_ws, size_t ws_size,
                              hipStream_t stream) {
    const float* x  = (const float*)d_in[0];
    const float* Wq = (const float*)d_in[1];
    const float* bq = (const float*)d_in[2];
    const float* Wk = (const float*)d_in[3];
    const float* bk = (const float*)d_in[4];
    const float* Wv = (const float*)d_in[5];
    const float* bv = (const float*)d_in[6];
    const float* Wo = (const float*)d_in[7];
    const float* bo = (const float*)d_in[8];
    const float* qn = (const float*)d_in[9];
    const float* kn = (const float*)d_in[10];
    const float* gl = (const float*)d_in[11];
    const int* sp   = (const int*)d_in[13];
    float* out = (float*)d_out;

    char* ws = (char*)d_ws;
    const size_t NEED = 96481280;
    if (ws_size < NEED) return;
    short* xb    = (short*)(ws + 0);            // 16 MiB, reused as Qb
    short* wqkvT = (short*)(ws + 16777216);     // 12 MiB
    short* woT   = (short*)(ws + 29360128);     // 8 MiB
    float* bqkv  = (float*)(ws + 37748736);     // 12 KiB
    short* Yb    = (short*)(ws + 37761024);     // 24 MiB bf16, head reused as attnb
    short* Kb    = (short*)(ws + 88092672);     // 4 MiB
    short* Vtb   = (short*)(ws + 92286976);     // 4 MiB
    short* Qb    = xb;
    short* attnb = Yb;

    f32_to_bf16_k<<<4096, 256, 0, stream>>>(x, xb, 1048576);
    transpose_f32_bf16_k<<<dim3(32, 32, 1), 256, 0, stream>>>(Wq, 0, 2048, wqkvT, 0, 2048);
    transpose_f32_bf16_k<<<dim3(8, 32, 1), 256, 0, stream>>>(Wk, 0, 512, wqkvT + (size_t)2048 * 2048, 0, 2048);
    transpose_f32_bf16_k<<<dim3(8, 32, 1), 256, 0, stream>>>(Wv, 0, 512, wqkvT + (size_t)2560 * 2048, 0, 2048);
    transpose_f32_bf16_k<<<dim3(32, 32, 1), 256, 0, stream>>>(Wo, 0, 2048, woT, 0, 2048);
    concat_bias_k<<<12, 256, 0, stream>>>(bq, bk, bv, bqkv);
    gemm256_k<0, true, 3><<<dim3(16, 16), 512, 0, stream>>>(xb, wqkvT, bqkv, Yb, 4096, 3072, 2048);
    qkv_post_k<<<4096, 256, 0, stream>>>(Yb, qn, kn, sp, Qb, Kb);
    transpose_bf16_k<<<dim3(8, 32, 2), 256, 0, stream>>>(
        Yb + 2560, (size_t)2048 * 3072, 3072, Vtb, (size_t)512 * 2048, 2048);
    attn_fwd_k<<<dim3(8, 32), 512, 0, stream>>>(Qb, Kb, Vtb, gl, attnb);
    gemm256_k<1, false, 2><<<dim3(16, 16), 512, 0, stream>>>(attnb, woT, bo, out, 4096, 2048, 2048);
}